// Round 1
// 2068.720 us; speedup vs baseline: 1.5197x; 1.5197x over previous
//
#include <hip/hip_runtime.h>
#include <stdint.h>

// ---- problem constants ----
constexpr int Bb = 4, Ss = 2048, Dd = 1024;
constexpr int Hh = 16, KVh = 4, HDd = 64;
constexpr int Ee = 8, Ff = 1024;
constexpr int Tt = Bb * Ss;           // 8192 tokens
constexpr float EPSf = 1e-6f;

typedef unsigned short u16;
typedef __attribute__((ext_vector_type(8))) short short8;       // 8 bf16 (4 VGPRs)
typedef __attribute__((ext_vector_type(4))) float f32x4;        // 4 fp32 acc
typedef __attribute__((ext_vector_type(8))) _Float16 h16x8;     // 8 f16 (4 VGPRs)
typedef __attribute__((ext_vector_type(4))) _Float16 h16x4;     // 4 f16 (8B)

__device__ __forceinline__ float bf2f(u16 u) {
  union { unsigned int i; float f; } x; x.i = ((unsigned int)u) << 16; return x.f;
}
__device__ __forceinline__ u16 f2bf(float f) {
  union { float f; unsigned int i; } x; x.f = f;
  unsigned int r = x.i + 0x7fffu + ((x.i >> 16) & 1u);
  return (u16)(r >> 16);
}
__device__ __forceinline__ void storef(float* p, float v) { *p = v; }
__device__ __forceinline__ void storef(u16* p, float v) { *p = f2bf(v); }

// ---------------- fp32 [1024][N] -> bf16 [N][1024] transpose-convert ----------------
__global__ __launch_bounds__(256) void transpose_kernel(const float* __restrict__ W,
                                                        u16* __restrict__ WT, int N) {
  __shared__ float tile[64][65];
  int n0 = blockIdx.x * 64, k0 = blockIdx.y * 64;
  int tid = threadIdx.x, r = tid >> 6, c = tid & 63;
#pragma unroll
  for (int p = 0; p < 16; ++p)
    tile[p * 4 + r][c] = W[(size_t)(k0 + p * 4 + r) * N + n0 + c];
  __syncthreads();
#pragma unroll
  for (int p = 0; p < 16; ++p)
    WT[(size_t)(n0 + p * 4 + r) * 1024 + k0 + c] = f2bf(tile[c][p * 4 + r]);
}

// ---------------- RMSNorm: fp32 in -> fp32 or bf16 out ----------------
template <typename TOUT>
__global__ __launch_bounds__(256) void rmsnorm_kernel(const float* __restrict__ x,
                                                      const float* __restrict__ w,
                                                      TOUT* __restrict__ out) {
  int t = blockIdx.x, tid = threadIdx.x;
  __shared__ float red[4];
  const float* xr = x + (size_t)t * Dd;
  float v[4]; float ss = 0.f;
#pragma unroll
  for (int i = 0; i < 4; ++i) { v[i] = xr[tid + 256 * i]; ss += v[i] * v[i]; }
#pragma unroll
  for (int off = 32; off; off >>= 1) ss += __shfl_down(ss, off, 64);
  if ((tid & 63) == 0) red[tid >> 6] = ss;
  __syncthreads();
  float tot = red[0] + red[1] + red[2] + red[3];
  float sc = rsqrtf(tot * (1.f / Dd) + EPSf);
  TOUT* orow = out + (size_t)t * Dd;
#pragma unroll
  for (int i = 0; i < 4; ++i) storef(orow + tid + 256 * i, v[i] * sc * w[tid + 256 * i]);
}

// ---------------- fp32 128x128 tiled GEMM (attention path), 8x8 microtile ----------------
// MODE 0: C = A@B        MODE 1: C = A@B + resid
template <int MODE>
__global__ __launch_bounds__(256) void gemm128(const float* __restrict__ A,
                                               const float* __restrict__ Bw,
                                               float* __restrict__ C,
                                               const float* __restrict__ resid,
                                               int N, int K) {
  __shared__ float As[16][128];   // [k][m]
  __shared__ float Bs[16][128];   // [k][n]
  int tid = threadIdx.x;
  int tx = tid & 15, ty = tid >> 4;
  int m0 = blockIdx.y * 128, n0 = blockIdx.x * 128;
  float acc[8][8] = {};
  int arow = tid >> 1, akc = (tid & 1) * 8;     // A loader: 128 rows, 8 k each
  int bkr = tid >> 4, bnc = (tid & 15) * 8;     // B loader: 16 k-rows, 8 n each
  const float* Ald = A + (size_t)(m0 + arow) * K + akc;
  const float* Bld = Bw + (size_t)bkr * N + n0 + bnc;
  for (int kt = 0; kt < K; kt += 16) {
    float4 a0 = *(const float4*)(Ald + kt);
    float4 a1 = *(const float4*)(Ald + kt + 4);
    float4 b0 = *(const float4*)(Bld + (size_t)kt * N);
    float4 b1 = *(const float4*)(Bld + (size_t)kt * N + 4);
    __syncthreads();
    As[akc + 0][arow] = a0.x; As[akc + 1][arow] = a0.y;
    As[akc + 2][arow] = a0.z; As[akc + 3][arow] = a0.w;
    As[akc + 4][arow] = a1.x; As[akc + 5][arow] = a1.y;
    As[akc + 6][arow] = a1.z; As[akc + 7][arow] = a1.w;
    *(float4*)&Bs[bkr][bnc] = b0;
    *(float4*)&Bs[bkr][bnc + 4] = b1;
    __syncthreads();
#pragma unroll
    for (int kk = 0; kk < 16; ++kk) {
      float4 af0 = *(const float4*)&As[kk][ty * 8];
      float4 af1 = *(const float4*)&As[kk][ty * 8 + 4];
      float4 bf0 = *(const float4*)&Bs[kk][tx * 8];
      float4 bf1 = *(const float4*)&Bs[kk][tx * 8 + 4];
      float aa[8] = {af0.x, af0.y, af0.z, af0.w, af1.x, af1.y, af1.z, af1.w};
      float bb[8] = {bf0.x, bf0.y, bf0.z, bf0.w, bf1.x, bf1.y, bf1.z, bf1.w};
#pragma unroll
      for (int i = 0; i < 8; ++i)
#pragma unroll
        for (int j = 0; j < 8; ++j) acc[i][j] += aa[i] * bb[j];
    }
  }
#pragma unroll
  for (int i = 0; i < 8; ++i) {
    int m = m0 + ty * 8 + i;
    size_t rowoff = (size_t)m * N + n0 + tx * 8;
    float* crow = C + rowoff;
#pragma unroll
    for (int j = 0; j < 8; ++j) {
      float vv = acc[i][j];
      if (MODE == 1) vv += resid[rowoff + j];
      crow[j] = vv;
    }
  }
}

// ---------------- MFMA bf16 GEMM (MoE path): C[M,N] = A[M,K]bf16 @ BT[N,K]bf16 ----------------
// MODE 2: Cb = bf16(C)    MODE 3: Cf += gate[m]*C
template <int MODE>
__global__ __launch_bounds__(256) void mfma_gemm(const u16* __restrict__ A,
                                                 const u16* __restrict__ BT,
                                                 float* __restrict__ Cf,
                                                 u16* __restrict__ Cb,
                                                 const float* __restrict__ gates, int e,
                                                 int N, int K) {
  constexpr int LS = 40;                 // u16 row stride (32 + 8 pad)
  __shared__ u16 As[128 * LS];
  __shared__ u16 Bs[128 * LS];
  int tid = threadIdx.x;
  int m0 = blockIdx.y * 128, n0 = blockIdx.x * 128;
  int lane = tid & 63, w = tid >> 6;
  int wm = (w & 1) * 64, wn = (w >> 1) * 64;
  f32x4 acc[4][4];
#pragma unroll
  for (int i = 0; i < 4; ++i)
#pragma unroll
    for (int j = 0; j < 4; ++j) acc[i][j] = (f32x4){0.f, 0.f, 0.f, 0.f};

  int row = tid >> 2, col8 = (tid & 3) * 8;
  int row1 = row + 64;
  const u16* gA0 = A + (size_t)(m0 + row) * K + col8;
  const u16* gA1 = A + (size_t)(m0 + row1) * K + col8;
  const u16* gB0 = BT + (size_t)(n0 + row) * K + col8;
  const u16* gB1 = BT + (size_t)(n0 + row1) * K + col8;
  int lo0 = row * LS + col8, lo1 = row1 * LS + col8;
  int afo[4], bfo[4];
#pragma unroll
  for (int i = 0; i < 4; ++i) {
    afo[i] = (wm + i * 16 + (lane & 15)) * LS + (lane >> 4) * 8;
    bfo[i] = (wn + i * 16 + (lane & 15)) * LS + (lane >> 4) * 8;
  }

  for (int kt = 0; kt < K; kt += 32) {
    short8 va0 = *(const short8*)(gA0 + kt);
    short8 va1 = *(const short8*)(gA1 + kt);
    short8 vb0 = *(const short8*)(gB0 + kt);
    short8 vb1 = *(const short8*)(gB1 + kt);
    __syncthreads();
    *(short8*)&As[lo0] = va0;
    *(short8*)&As[lo1] = va1;
    *(short8*)&Bs[lo0] = vb0;
    *(short8*)&Bs[lo1] = vb1;
    __syncthreads();
    short8 af[4], bfr[4];
#pragma unroll
    for (int i = 0; i < 4; ++i) af[i] = *(const short8*)&As[afo[i]];
#pragma unroll
    for (int j = 0; j < 4; ++j) bfr[j] = *(const short8*)&Bs[bfo[j]];
#pragma unroll
    for (int i = 0; i < 4; ++i)
#pragma unroll
      for (int j = 0; j < 4; ++j)
        acc[i][j] = __builtin_amdgcn_mfma_f32_16x16x32_bf16(af[i], bfr[j], acc[i][j], 0, 0, 0);
  }

  int r0 = (lane >> 4) * 4, cc = lane & 15;   // C/D: row=(lane>>4)*4+reg, col=lane&15
#pragma unroll
  for (int i = 0; i < 4; ++i) {
#pragma unroll
    for (int r = 0; r < 4; ++r) {
      int m = m0 + wm + i * 16 + r0 + r;
      float g = 0.f;
      if (MODE == 3) g = gates[(size_t)m * Ee + e];
#pragma unroll
      for (int j = 0; j < 4; ++j) {
        int n = n0 + wn + j * 16 + cc;
        size_t off = (size_t)m * N + n;
        float v = acc[i][j][r];
        if (MODE == 2) Cb[off] = f2bf(v);
        else if (MODE == 3) Cf[off] += g * v;
      }
    }
  }
}

// ---------------- RoPE on q (fp32, in place, stride H*HD) ----------------
__global__ __launch_bounds__(256) void rope_q_kernel(float* __restrict__ q,
                                                     const float* __restrict__ cosb,
                                                     const float* __restrict__ sinb) {
  int idx = blockIdx.x * 256 + threadIdx.x;  // Tt*H*32
  int d = idx & 31;
  int hh = (idx >> 5) & (Hh - 1);
  int t = idx >> 9;
  int s = t & (Ss - 1);
  float c = cosb[s * HDd + d], sn = sinb[s * HDd + d];
  float* qp = q + (size_t)t * (Hh * HDd) + hh * HDd;
  float a = qp[d], b = qp[d + 32];
  qp[d] = a * c - b * sn;
  qp[d + 32] = b * c + a * sn;
}

// ---------------- RoPE on k (in place) + emit fp32 k,v outputs ----------------
__global__ __launch_bounds__(256) void ropek_kv_kernel(float* __restrict__ kf,
                                                       const float* __restrict__ vf,
                                                       const float* __restrict__ cosb,
                                                       const float* __restrict__ sinb,
                                                       float* __restrict__ outk,
                                                       float* __restrict__ outv) {
  int idx = blockIdx.x * 256 + threadIdx.x;  // Tt*KV*32
  int d = idx & 31;
  int kv = (idx >> 5) & (KVh - 1);
  int t = idx >> 7;
  int s = t & (Ss - 1);
  float c = cosb[s * HDd + d], sn = sinb[s * HDd + d];
  size_t base = (size_t)t * (KVh * HDd) + kv * HDd;
  float a = kf[base + d], b = kf[base + d + 32];
  float r1 = a * c - b * sn, r2 = b * c + a * sn;
  kf[base + d] = r1; kf[base + d + 32] = r2;
  outk[base + d] = r1; outk[base + d + 32] = r2;
  outv[base + d] = vf[base + d]; outv[base + d + 32] = vf[base + d + 32];
}

// ---------------- MFMA f16 flash attention ----------------
// Block = 128 q-rows of one (b,h), 4 waves x 32 q-rows. K-tile = 64 keys.
// Q held in registers as pre-scaled f16 A-frags. K staged [key][72] f16,
// V staged transposed Vt[d][key] (+72 stride). P re-laid-out via per-wave LDS.
// Fragment conventions identical to mfma_gemm above (verified):
//   A-frag elem j = X[row=lane&15][k=(lane>>4)*8+j]
//   B-frag elem j = Y[n=lane&15][k=(lane>>4)*8+j]   (Y row-major [n][k])
//   C: row=(lane>>4)*4+reg, col=lane&15
__global__ __launch_bounds__(256) void flash_mfma(const float* __restrict__ q,
                                                  const float* __restrict__ kf,
                                                  const float* __restrict__ vf,
                                                  float* __restrict__ o) {
  constexpr int LS = 72;  // halves per row: 144B, 16B aligned, padded vs 128B
  __shared__ __align__(16) _Float16 Kt[64 * LS];
  __shared__ __align__(16) _Float16 Vt[64 * LS];       // Vt[d][key]
  __shared__ __align__(16) _Float16 Pl[4][32 * LS];    // per-wave P[q][key]
  int tid = threadIdx.x;
  int qt = 15 - (blockIdx.x & 15);      // heavy q-tiles first
  int bh = blockIdx.x >> 4;
  int b = bh >> 4, hh = bh & 15;
  int w = tid >> 6, lane = tid & 63;
  int c = lane & 15, g = lane >> 4;
  int kvh = hh >> 2;                    // H/KV = 4
  const float* Kbase = kf + (size_t)b * Ss * (KVh * HDd) + kvh * HDd;
  const float* Vbase = vf + (size_t)b * Ss * (KVh * HDd) + kvh * HDd;
  int qrow0 = qt * 128 + w * 32;

  // Q fragments (A operand), pre-scaled by 1/sqrt(64)
  h16x8 qa[2][2];
#pragma unroll
  for (int i = 0; i < 2; ++i) {
#pragma unroll
    for (int kk = 0; kk < 2; ++kk) {
      const float* qp = q + ((size_t)(b * Ss) + qrow0 + i * 16 + c) * (Hh * HDd) +
                        hh * HDd + kk * 32 + g * 8;
      float4 v0 = *(const float4*)qp;
      float4 v1 = *(const float4*)(qp + 4);
      h16x8 hv;
      hv[0] = (_Float16)(v0.x * 0.125f); hv[1] = (_Float16)(v0.y * 0.125f);
      hv[2] = (_Float16)(v0.z * 0.125f); hv[3] = (_Float16)(v0.w * 0.125f);
      hv[4] = (_Float16)(v1.x * 0.125f); hv[5] = (_Float16)(v1.y * 0.125f);
      hv[6] = (_Float16)(v1.z * 0.125f); hv[7] = (_Float16)(v1.w * 0.125f);
      qa[i][kk] = hv;
    }
  }

  f32x4 occ[2][4];                      // O acc: [q-tile i][d-tile dt]
#pragma unroll
  for (int i = 0; i < 2; ++i)
#pragma unroll
    for (int dt = 0; dt < 4; ++dt) occ[i][dt] = (f32x4){0.f, 0.f, 0.f, 0.f};
  float mrow[2][4], lrow[2][4];         // per-row running max / PARTIAL sum (per lane-column)
#pragma unroll
  for (int i = 0; i < 2; ++i)
#pragma unroll
    for (int r = 0; r < 4; ++r) { mrow[i][r] = -1e30f; lrow[i][r] = 0.f; }

  int kmax = qt * 128 + 128;
  int lr = tid >> 2, lc4 = (tid & 3) * 16;   // K stager: key lr, dims lc4..+15
  int vk = tid >> 4, vc = (tid & 15) * 4;    // V stager: key vk(+16u), dims vc..+3

  for (int j0 = 0; j0 < kmax; j0 += 64) {
    __syncthreads();
    // ---- stage K [key][d] f16 ----
    const float* krow = Kbase + (size_t)(j0 + lr) * (KVh * HDd) + lc4;
#pragma unroll
    for (int u = 0; u < 4; ++u) {
      float4 kv = *(const float4*)(krow + u * 4);
      h16x4 h;
      h[0] = (_Float16)kv.x; h[1] = (_Float16)kv.y;
      h[2] = (_Float16)kv.z; h[3] = (_Float16)kv.w;
      *(h16x4*)&Kt[lr * LS + lc4 + u * 4] = h;
    }
    // ---- stage V transposed: Vt[d][key] ----
#pragma unroll
    for (int u = 0; u < 4; ++u) {
      const float* vrow = Vbase + (size_t)(j0 + vk + u * 16) * (KVh * HDd) + vc;
      float4 vv = *(const float4*)vrow;
      Vt[(vc + 0) * LS + vk + u * 16] = (_Float16)vv.x;
      Vt[(vc + 1) * LS + vk + u * 16] = (_Float16)vv.y;
      Vt[(vc + 2) * LS + vk + u * 16] = (_Float16)vv.z;
      Vt[(vc + 3) * LS + vk + u * 16] = (_Float16)vv.w;
    }
    __syncthreads();
    // ---- S = Q K^T : per wave 32 q x 64 keys ----
    f32x4 sacc[2][4];
#pragma unroll
    for (int i = 0; i < 2; ++i)
#pragma unroll
      for (int jt = 0; jt < 4; ++jt) sacc[i][jt] = (f32x4){0.f, 0.f, 0.f, 0.f};
#pragma unroll
    for (int kk = 0; kk < 2; ++kk) {
#pragma unroll
      for (int jt = 0; jt < 4; ++jt) {
        h16x8 bf = *(const h16x8*)&Kt[(jt * 16 + c) * LS + kk * 32 + g * 8];
        sacc[0][jt] = __builtin_amdgcn_mfma_f32_16x16x32_f16(qa[0][kk], bf, sacc[0][jt], 0, 0, 0);
        sacc[1][jt] = __builtin_amdgcn_mfma_f32_16x16x32_f16(qa[1][kk], bf, sacc[1][jt], 0, 0, 0);
      }
    }
    // ---- online softmax (fp32) + emit P (f16) to per-wave LDS ----
#pragma unroll
    for (int i = 0; i < 2; ++i) {
#pragma unroll
      for (int r = 0; r < 4; ++r) {
        int iq = qrow0 + i * 16 + g * 4 + r;
        float sv[4];
#pragma unroll
        for (int jt = 0; jt < 4; ++jt) {
          int jk = j0 + jt * 16 + c;
          sv[jt] = (jk <= iq) ? sacc[i][jt][r] : -1e30f;
        }
        float rm = fmaxf(fmaxf(sv[0], sv[1]), fmaxf(sv[2], sv[3]));
#pragma unroll
        for (int off = 1; off < 16; off <<= 1) rm = fmaxf(rm, __shfl_xor(rm, off, 64));
        float mn = fmaxf(mrow[i][r], rm);
        float alpha = __expf(mrow[i][r] - mn);
        mrow[i][r] = mn;
        float ps = 0.f;
        _Float16 ph[4];
#pragma unroll
        for (int jt = 0; jt < 4; ++jt) {
          float p = __expf(sv[jt] - mn);
          ps += p;
          ph[jt] = (_Float16)p;
        }
        // l stays a per-lane partial over this lane's 4 key-columns (alpha is
        // row-uniform after the max reduce) — reduced once in the epilogue.
        lrow[i][r] = lrow[i][r] * alpha + ps;
#pragma unroll
        for (int dt = 0; dt < 4; ++dt) occ[i][dt][r] *= alpha;
#pragma unroll
        for (int jt = 0; jt < 4; ++jt)
          Pl[w][(i * 16 + g * 4 + r) * LS + jt * 16 + c] = ph[jt];
      }
    }
    __syncthreads();  // P write -> P frag read visibility (cross-lane)
    // ---- O += P V : A-frags from Pl, B-frags from Vt ----
#pragma unroll
    for (int kkey = 0; kkey < 2; ++kkey) {
      h16x8 pa0 = *(const h16x8*)&Pl[w][(0 * 16 + c) * LS + kkey * 32 + g * 8];
      h16x8 pa1 = *(const h16x8*)&Pl[w][(1 * 16 + c) * LS + kkey * 32 + g * 8];
#pragma unroll
      for (int dt = 0; dt < 4; ++dt) {
        h16x8 bv = *(const h16x8*)&Vt[(dt * 16 + c) * LS + kkey * 32 + g * 8];
        occ[0][dt] = __builtin_amdgcn_mfma_f32_16x16x32_f16(pa0, bv, occ[0][dt], 0, 0, 0);
        occ[1][dt] = __builtin_amdgcn_mfma_f32_16x16x32_f16(pa1, bv, occ[1][dt], 0, 0, 0);
      }
    }
  }
  // ---- epilogue: finish l reduction across the 16-lane column group, store O ----
#pragma unroll
  for (int i = 0; i < 2; ++i) {
#pragma unroll
    for (int r = 0; r < 4; ++r) {
      float ls = lrow[i][r];
#pragma unroll
      for (int off = 1; off < 16; off <<= 1) ls += __shfl_xor(ls, off, 64);
      float inv = 1.f / ls;
      float* op = o + ((size_t)(b * Ss) + qrow0 + i * 16 + g * 4 + r) * (Hh * HDd) +
                  hh * HDd + c;
#pragma unroll
      for (int dt = 0; dt < 4; ++dt) op[dt * 16] = occ[i][dt][r] * inv;
    }
  }
}

// ---------------- Fused router: rmsnorm(h) fp32 -> logits -> top-2 softmax gates ----------------
__global__ __launch_bounds__(64) void router_kernel(const float* __restrict__ h,
                                                    const float* __restrict__ wm,
                                                    const float* __restrict__ rw,
                                                    float* __restrict__ gates) {
  int t = blockIdx.x, lane = threadIdx.x;
  const float* hr = h + (size_t)t * Dd;
  float v[16]; float ss = 0.f;
#pragma unroll
  for (int j = 0; j < 16; ++j) { v[j] = hr[lane + j * 64]; ss += v[j] * v[j]; }
#pragma unroll
  for (int off = 32; off; off >>= 1) ss += __shfl_down(ss, off, 64);
  ss = __shfl(ss, 0, 64);
  float sc = rsqrtf(ss * (1.f / Dd) + EPSf);
  float acc[8] = {};
#pragma unroll
  for (int j = 0; j < 16; ++j) {
    int i = lane + j * 64;
    float yv = v[j] * sc * wm[i];
    float4 w0 = *(const float4*)(rw + (size_t)i * 8);
    float4 w1 = *(const float4*)(rw + (size_t)i * 8 + 4);
    acc[0] += yv * w0.x; acc[1] += yv * w0.y;
    acc[2] += yv * w0.z; acc[3] += yv * w0.w;
    acc[4] += yv * w1.x; acc[5] += yv * w1.y;
    acc[6] += yv * w1.z; acc[7] += yv * w1.w;
  }
#pragma unroll
  for (int off = 32; off; off >>= 1)
#pragma unroll
    for (int e = 0; e < 8; ++e) acc[e] += __shfl_down(acc[e], off, 64);
  if (lane == 0) {
    int i0 = 0; float v0 = acc[0];
#pragma unroll
    for (int e = 1; e < 8; ++e) if (acc[e] > v0) { v0 = acc[e]; i0 = e; }
    int i1 = -1; float v1 = -3.4e38f;
#pragma unroll
    for (int e = 0; e < 8; ++e) if (e != i0 && acc[e] > v1) { v1 = acc[e]; i1 = e; }
    float e1 = __expf(v1 - v0);
    float inv = 1.f / (1.f + e1);
    float* gr = gates + (size_t)t * 8;
#pragma unroll
    for (int e = 0; e < 8; ++e) gr[e] = (e == i0) ? inv : ((e == i1) ? e1 * inv : 0.f);
  }
}

// ---------------- silu(g)*u from fused gu [M][2048] bf16 -> he [M][1024] bf16 ----------------
__global__ __launch_bounds__(256) void silu_mul_kernel(const u16* __restrict__ gu,
                                                       u16* __restrict__ he) {
  size_t idx4 = ((size_t)blockIdx.x * 256 + threadIdx.x) * 4;
  size_t m = idx4 >> 10, f = idx4 & 1023;
  const u16* gp = gu + m * 2048 + f;
  ushort4 gv = *(const ushort4*)gp;
  ushort4 uv = *(const ushort4*)(gp + 1024);
  float g[4] = {bf2f(gv.x), bf2f(gv.y), bf2f(gv.z), bf2f(gv.w)};
  float u[4] = {bf2f(uv.x), bf2f(uv.y), bf2f(uv.z), bf2f(uv.w)};
  ushort4 o;
  o.x = f2bf(g[0] / (1.f + __expf(-g[0])) * u[0]);
  o.y = f2bf(g[1] / (1.f + __expf(-g[1])) * u[1]);
  o.z = f2bf(g[2] / (1.f + __expf(-g[2])) * u[2]);
  o.w = f2bf(g[3] / (1.f + __expf(-g[3])) * u[3]);
  *(ushort4*)(he + m * 1024 + f) = o;
}

extern "C" void kernel_launch(void* const* d_in, const int* in_sizes, int n_in,
                              void* d_out, int out_size, void* d_ws, size_t ws_size,
                              hipStream_t stream) {
  const float* x      = (const float*)d_in[0];
  const float* cosb   = (const float*)d_in[1];
  const float* sinb   = (const float*)d_in[2];
  // d_in[3] = mask — causal, hard-coded in flash
  const float* w_attn = (const float*)d_in[4];
  const float* w_moe  = (const float*)d_in[5];
  const float* Wq = (const float*)d_in[6];
  const float* Wk = (const float*)d_in[7];
  const float* Wv = (const float*)d_in[8];
  const float* Wo = (const float*)d_in[9];
  const float* Wr = (const float*)d_in[10];
  const float* Wg = (const float*)d_in[11];
  const float* Wu = (const float*)d_in[12];
  const float* Wd = (const float*)d_in[13];
  float* out  = (float*)d_out;
  float* outk = out + (size_t)Tt * Dd;
  float* outv = outk + (size_t)Tt * KVh * HDd;

  char* ws8 = (char*)d_ws;                       // 112 MB budget
  float* xn    = (float*)(ws8);                  // 32 MB : xn -> o -> {y, gates, wbuf}
  float* q     = (float*)(ws8 + 33554432);       // 32 MB : q fp32 -> gu bf16 [T][2048]
  float* kf    = (float*)(ws8 + 67108864);       //  8 MB : kf -> he (he spans kf+vf)
  float* vf    = (float*)(ws8 + 75497472);       //  8 MB
  float* h     = (float*)(ws8 + 83886080);       // 32 MB
  float* o_    = xn;
  u16*   y     = (u16*)(ws8);                    // 16 MB (o dead after Wo gemm)
  float* gates = (float*)(ws8 + 16777216);       // 256 KB
  u16*   wbuf  = (u16*)(ws8 + 17825792);         // 6 MB : WguT [2048][1024] + WdT [1024][1024]
  u16*   WguT  = wbuf;
  u16*   WdT   = wbuf + (size_t)2048 * 1024;
  u16*   gu    = (u16*)q;                        // q dead after flash
  u16*   he    = (u16*)kf;                       // kf/vf dead after flash

  // 1. xn = rmsnorm(x, w_attn)  (fp32 — attention path stays fp32 for router precision)
  rmsnorm_kernel<float><<<Tt, 256, 0, stream>>>(x, w_attn, xn);
  // 2. q/k/v projections (fp32, 128x128 tile)
  gemm128<0><<<dim3(8, 64), 256, 0, stream>>>(xn, Wq, q, nullptr, 1024, 1024);
  gemm128<0><<<dim3(2, 64), 256, 0, stream>>>(xn, Wk, kf, nullptr, 256, 1024);
  gemm128<0><<<dim3(2, 64), 256, 0, stream>>>(xn, Wv, vf, nullptr, 256, 1024);
  // 3. RoPE; emit fp32 k,v outputs
  rope_q_kernel<<<(Tt * Hh * 32) / 256, 256, 0, stream>>>(q, cosb, sinb);
  ropek_kv_kernel<<<(Tt * KVh * 32) / 256, 256, 0, stream>>>(kf, vf, cosb, sinb, outk, outv);
  // 4. causal GQA flash attention (MFMA f16) -> o (xn region)
  flash_mfma<<<Bb * Hh * (Ss / 128), 256, 0, stream>>>(q, kf, vf, o_);
  // 5. h = o @ Wo + x (fp32)
  gemm128<1><<<dim3(8, 64), 256, 0, stream>>>(o_, Wo, h, x, 1024, 1024);
  // 6. y = rmsnorm(h) -> bf16 (MoE input); fused fp32 router -> gates
  rmsnorm_kernel<u16><<<Tt, 256, 0, stream>>>(h, w_moe, y);
  router_kernel<<<Tt, 64, 0, stream>>>(h, w_moe, Wr, gates);
  // 7. out = h, then MoE accumulates
  hipMemcpyAsync(out, h, (size_t)Tt * Dd * sizeof(float), hipMemcpyDeviceToDevice, stream);
  // 8. dense MoE, bf16 MFMA (gates are 0 for unrouted tokens)
  for (int e = 0; e < Ee; ++e) {
    transpose_kernel<<<dim3(16, 16), 256, 0, stream>>>(Wg + (size_t)e * Dd * Ff, WguT, 1024);
    transpose_kernel<<<dim3(16, 16), 256, 0, stream>>>(Wu + (size_t)e * Dd * Ff, WguT + (size_t)1024 * 1024, 1024);
    transpose_kernel<<<dim3(16, 16), 256, 0, stream>>>(Wd + (size_t)e * Ff * Dd, WdT, 1024);
    mfma_gemm<2><<<dim3(16, 64), 256, 0, stream>>>(y, WguT, nullptr, gu, nullptr, 0, 2048, 1024);
    silu_mul_kernel<<<(Tt * 1024) / 1024, 256, 0, stream>>>(gu, he);
    mfma_gemm<3><<<dim3(8, 64), 256, 0, stream>>>(he, WdT, out, nullptr, gates, e, 1024, 1024);
  }
}

// Round 2
// 1540.691 us; speedup vs baseline: 2.0405x; 1.3427x over previous
//
#include <hip/hip_runtime.h>
#include <stdint.h>

// ---- problem constants ----
constexpr int Bb = 4, Ss = 2048, Dd = 1024;
constexpr int Hh = 16, KVh = 4, HDd = 64;
constexpr int Ee = 8, Ff = 1024;
constexpr int Tt = Bb * Ss;           // 8192 tokens
constexpr float EPSf = 1e-6f;

typedef unsigned short u16;
typedef __attribute__((ext_vector_type(8))) short short8;       // 8 bf16/f16 (4 VGPRs)
typedef __attribute__((ext_vector_type(4))) float f32x4;        // 4 fp32 acc
typedef __attribute__((ext_vector_type(8))) _Float16 h16x8;     // 8 f16 (4 VGPRs)
typedef __attribute__((ext_vector_type(4))) _Float16 h16x4;     // 4 f16 (8B)

__device__ __forceinline__ float bf2f(u16 u) {
  union { unsigned int i; float f; } x; x.i = ((unsigned int)u) << 16; return x.f;
}
__device__ __forceinline__ u16 f2bf(float f) {
  union { float f; unsigned int i; } x; x.f = f;
  unsigned int r = x.i + 0x7fffu + ((x.i >> 16) & 1u);
  return (u16)(r >> 16);
}
__device__ __forceinline__ u16 f2h(float f) {
  union { _Float16 h; u16 u; } x; x.h = (_Float16)f; return x.u;
}
__device__ __forceinline__ h16x8 as_h(short8 v) {
  union { short8 s; h16x8 h; } u; u.s = v; return u.h;
}

// ---------------- fp32 [1024][N] -> 16-bit [N][1024] transpose-convert ----------------
// F16H=false: bf16 out (MoE weights)   F16H=true: f16 out (attention weights)
template <bool F16H>
__global__ __launch_bounds__(256) void transpose_kernel(const float* __restrict__ W,
                                                        u16* __restrict__ WT, int N) {
  __shared__ float tile[64][65];
  int n0 = blockIdx.x * 64, k0 = blockIdx.y * 64;
  int tid = threadIdx.x, r = tid >> 6, c = tid & 63;
#pragma unroll
  for (int p = 0; p < 16; ++p)
    tile[p * 4 + r][c] = W[(size_t)(k0 + p * 4 + r) * N + n0 + c];
  __syncthreads();
#pragma unroll
  for (int p = 0; p < 16; ++p) {
    float v = tile[c][p * 4 + r];
    WT[(size_t)(n0 + p * 4 + r) * 1024 + k0 + c] = F16H ? f2h(v) : f2bf(v);
  }
}

// ---------------- RMSNorm: fp32 in -> FMT out (0=f32, 1=bf16, 2=f16) ----------------
template <int FMT>
__global__ __launch_bounds__(256) void rmsnorm_kernel(const float* __restrict__ x,
                                                      const float* __restrict__ w,
                                                      void* __restrict__ outp) {
  int t = blockIdx.x, tid = threadIdx.x;
  __shared__ float red[4];
  const float* xr = x + (size_t)t * Dd;
  float v[4]; float ss = 0.f;
#pragma unroll
  for (int i = 0; i < 4; ++i) { v[i] = xr[tid + 256 * i]; ss += v[i] * v[i]; }
#pragma unroll
  for (int off = 32; off; off >>= 1) ss += __shfl_down(ss, off, 64);
  if ((tid & 63) == 0) red[tid >> 6] = ss;
  __syncthreads();
  float tot = red[0] + red[1] + red[2] + red[3];
  float sc = rsqrtf(tot * (1.f / Dd) + EPSf);
#pragma unroll
  for (int i = 0; i < 4; ++i) {
    size_t idx = (size_t)t * Dd + tid + 256 * i;
    float val = v[i] * sc * w[tid + 256 * i];
    if constexpr (FMT == 0) ((float*)outp)[idx] = val;
    else if constexpr (FMT == 1) ((u16*)outp)[idx] = f2bf(val);
    else ((u16*)outp)[idx] = f2h(val);
  }
}

// ---------------- MFMA 16-bit GEMM: C[M,N] = A[M,K] @ BT[N,K] ----------------
// F16H selects f16 vs bf16 MFMA. Modes:
//   0: Cf = C          1: Cf = C + resid       2: Cb = bf16(C)      3: Cf += gate[m]*C
template <int MODE, bool F16H>
__global__ __launch_bounds__(256) void mfma_gemm(const u16* __restrict__ A,
                                                 const u16* __restrict__ BT,
                                                 float* __restrict__ Cf,
                                                 u16* __restrict__ Cb,
                                                 const float* __restrict__ resid,
                                                 const float* __restrict__ gates, int e,
                                                 int N, int K) {
  constexpr int LS = 40;                 // u16 row stride (32 + 8 pad)
  __shared__ u16 As[128 * LS];
  __shared__ u16 Bs[128 * LS];
  int tid = threadIdx.x;
  int m0 = blockIdx.y * 128, n0 = blockIdx.x * 128;
  int lane = tid & 63, w = tid >> 6;
  int wm = (w & 1) * 64, wn = (w >> 1) * 64;
  f32x4 acc[4][4];
#pragma unroll
  for (int i = 0; i < 4; ++i)
#pragma unroll
    for (int j = 0; j < 4; ++j) acc[i][j] = (f32x4){0.f, 0.f, 0.f, 0.f};

  int row = tid >> 2, col8 = (tid & 3) * 8;
  int row1 = row + 64;
  const u16* gA0 = A + (size_t)(m0 + row) * K + col8;
  const u16* gA1 = A + (size_t)(m0 + row1) * K + col8;
  const u16* gB0 = BT + (size_t)(n0 + row) * K + col8;
  const u16* gB1 = BT + (size_t)(n0 + row1) * K + col8;
  int lo0 = row * LS + col8, lo1 = row1 * LS + col8;
  int afo[4], bfo[4];
#pragma unroll
  for (int i = 0; i < 4; ++i) {
    afo[i] = (wm + i * 16 + (lane & 15)) * LS + (lane >> 4) * 8;
    bfo[i] = (wn + i * 16 + (lane & 15)) * LS + (lane >> 4) * 8;
  }

  for (int kt = 0; kt < K; kt += 32) {
    short8 va0 = *(const short8*)(gA0 + kt);
    short8 va1 = *(const short8*)(gA1 + kt);
    short8 vb0 = *(const short8*)(gB0 + kt);
    short8 vb1 = *(const short8*)(gB1 + kt);
    __syncthreads();
    *(short8*)&As[lo0] = va0;
    *(short8*)&As[lo1] = va1;
    *(short8*)&Bs[lo0] = vb0;
    *(short8*)&Bs[lo1] = vb1;
    __syncthreads();
    short8 af[4], bfr[4];
#pragma unroll
    for (int i = 0; i < 4; ++i) af[i] = *(const short8*)&As[afo[i]];
#pragma unroll
    for (int j = 0; j < 4; ++j) bfr[j] = *(const short8*)&Bs[bfo[j]];
#pragma unroll
    for (int i = 0; i < 4; ++i)
#pragma unroll
      for (int j = 0; j < 4; ++j) {
        if constexpr (F16H)
          acc[i][j] = __builtin_amdgcn_mfma_f32_16x16x32_f16(as_h(af[i]), as_h(bfr[j]),
                                                             acc[i][j], 0, 0, 0);
        else
          acc[i][j] = __builtin_amdgcn_mfma_f32_16x16x32_bf16(af[i], bfr[j],
                                                              acc[i][j], 0, 0, 0);
      }
  }

  int r0 = (lane >> 4) * 4, cc = lane & 15;   // C/D: row=(lane>>4)*4+reg, col=lane&15
#pragma unroll
  for (int i = 0; i < 4; ++i) {
#pragma unroll
    for (int r = 0; r < 4; ++r) {
      int m = m0 + wm + i * 16 + r0 + r;
      float g = 0.f;
      if (MODE == 3) g = gates[(size_t)m * Ee + e];
#pragma unroll
      for (int j = 0; j < 4; ++j) {
        int n = n0 + wn + j * 16 + cc;
        size_t off = (size_t)m * N + n;
        float v = acc[i][j][r];
        if constexpr (MODE == 0) Cf[off] = v;
        else if constexpr (MODE == 1) Cf[off] = v + resid[off];
        else if constexpr (MODE == 2) Cb[off] = f2bf(v);
        else Cf[off] += g * v;
      }
    }
  }
}

// ---------------- RoPE on q (fp32, in place, stride H*HD) ----------------
__global__ __launch_bounds__(256) void rope_q_kernel(float* __restrict__ q,
                                                     const float* __restrict__ cosb,
                                                     const float* __restrict__ sinb) {
  int idx = blockIdx.x * 256 + threadIdx.x;  // Tt*H*32
  int d = idx & 31;
  int hh = (idx >> 5) & (Hh - 1);
  int t = idx >> 9;
  int s = t & (Ss - 1);
  float c = cosb[s * HDd + d], sn = sinb[s * HDd + d];
  float* qp = q + (size_t)t * (Hh * HDd) + hh * HDd;
  float a = qp[d], b = qp[d + 32];
  qp[d] = a * c - b * sn;
  qp[d + 32] = b * c + a * sn;
}

// ---------------- RoPE on k (in place) + emit fp32 k,v outputs ----------------
__global__ __launch_bounds__(256) void ropek_kv_kernel(float* __restrict__ kf,
                                                       const float* __restrict__ vf,
                                                       const float* __restrict__ cosb,
                                                       const float* __restrict__ sinb,
                                                       float* __restrict__ outk,
                                                       float* __restrict__ outv) {
  int idx = blockIdx.x * 256 + threadIdx.x;  // Tt*KV*32
  int d = idx & 31;
  int kv = (idx >> 5) & (KVh - 1);
  int t = idx >> 7;
  int s = t & (Ss - 1);
  float c = cosb[s * HDd + d], sn = sinb[s * HDd + d];
  size_t base = (size_t)t * (KVh * HDd) + kv * HDd;
  float a = kf[base + d], b = kf[base + d + 32];
  float r1 = a * c - b * sn, r2 = b * c + a * sn;
  kf[base + d] = r1; kf[base + d + 32] = r2;
  outk[base + d] = r1; outk[base + d + 32] = r2;
  outv[base + d] = vf[base + d]; outv[base + d + 32] = vf[base + d + 32];
}

// ---------------- MFMA f16 flash attention ----------------
// Block = 128 q-rows of one (b,h), 4 waves x 32 q-rows. K-tile = 64 keys.
// Q held in registers as pre-scaled f16 A-frags. K staged [key][72] f16,
// V staged transposed Vt[d][key] (+72 stride). P re-laid-out via per-wave LDS.
// O written as f16 (u16) — feeds the Wo MFMA gemm directly.
__global__ __launch_bounds__(256) void flash_mfma(const float* __restrict__ q,
                                                  const float* __restrict__ kf,
                                                  const float* __restrict__ vf,
                                                  u16* __restrict__ ob) {
  constexpr int LS = 72;  // halves per row: 144B, 16B aligned, padded vs 128B
  __shared__ __align__(16) _Float16 Kt[64 * LS];
  __shared__ __align__(16) _Float16 Vt[64 * LS];       // Vt[d][key]
  __shared__ __align__(16) _Float16 Pl[4][32 * LS];    // per-wave P[q][key]
  int tid = threadIdx.x;
  int qt = 15 - (blockIdx.x & 15);      // heavy q-tiles first
  int bh = blockIdx.x >> 4;
  int b = bh >> 4, hh = bh & 15;
  int w = tid >> 6, lane = tid & 63;
  int c = lane & 15, g = lane >> 4;
  int kvh = hh >> 2;                    // H/KV = 4
  const float* Kbase = kf + (size_t)b * Ss * (KVh * HDd) + kvh * HDd;
  const float* Vbase = vf + (size_t)b * Ss * (KVh * HDd) + kvh * HDd;
  int qrow0 = qt * 128 + w * 32;

  // Q fragments (A operand), pre-scaled by 1/sqrt(64)
  h16x8 qa[2][2];
#pragma unroll
  for (int i = 0; i < 2; ++i) {
#pragma unroll
    for (int kk = 0; kk < 2; ++kk) {
      const float* qp = q + ((size_t)(b * Ss) + qrow0 + i * 16 + c) * (Hh * HDd) +
                        hh * HDd + kk * 32 + g * 8;
      float4 v0 = *(const float4*)qp;
      float4 v1 = *(const float4*)(qp + 4);
      h16x8 hv;
      hv[0] = (_Float16)(v0.x * 0.125f); hv[1] = (_Float16)(v0.y * 0.125f);
      hv[2] = (_Float16)(v0.z * 0.125f); hv[3] = (_Float16)(v0.w * 0.125f);
      hv[4] = (_Float16)(v1.x * 0.125f); hv[5] = (_Float16)(v1.y * 0.125f);
      hv[6] = (_Float16)(v1.z * 0.125f); hv[7] = (_Float16)(v1.w * 0.125f);
      qa[i][kk] = hv;
    }
  }

  f32x4 occ[2][4];                      // O acc: [q-tile i][d-tile dt]
#pragma unroll
  for (int i = 0; i < 2; ++i)
#pragma unroll
    for (int dt = 0; dt < 4; ++dt) occ[i][dt] = (f32x4){0.f, 0.f, 0.f, 0.f};
  float mrow[2][4], lrow[2][4];         // per-row running max / PARTIAL sum (per lane-column)
#pragma unroll
  for (int i = 0; i < 2; ++i)
#pragma unroll
    for (int r = 0; r < 4; ++r) { mrow[i][r] = -1e30f; lrow[i][r] = 0.f; }

  int kmax = qt * 128 + 128;
  int lr = tid >> 2, lc4 = (tid & 3) * 16;   // K stager: key lr, dims lc4..+15
  int vk = tid >> 4, vc = (tid & 15) * 4;    // V stager: key vk(+16u), dims vc..+3

  for (int j0 = 0; j0 < kmax; j0 += 64) {
    __syncthreads();
    // ---- stage K [key][d] f16 ----
    const float* krow = Kbase + (size_t)(j0 + lr) * (KVh * HDd) + lc4;
#pragma unroll
    for (int u = 0; u < 4; ++u) {
      float4 kv = *(const float4*)(krow + u * 4);
      h16x4 h;
      h[0] = (_Float16)kv.x; h[1] = (_Float16)kv.y;
      h[2] = (_Float16)kv.z; h[3] = (_Float16)kv.w;
      *(h16x4*)&Kt[lr * LS + lc4 + u * 4] = h;
    }
    // ---- stage V transposed: Vt[d][key] ----
#pragma unroll
    for (int u = 0; u < 4; ++u) {
      const float* vrow = Vbase + (size_t)(j0 + vk + u * 16) * (KVh * HDd) + vc;
      float4 vv = *(const float4*)vrow;
      Vt[(vc + 0) * LS + vk + u * 16] = (_Float16)vv.x;
      Vt[(vc + 1) * LS + vk + u * 16] = (_Float16)vv.y;
      Vt[(vc + 2) * LS + vk + u * 16] = (_Float16)vv.z;
      Vt[(vc + 3) * LS + vk + u * 16] = (_Float16)vv.w;
    }
    __syncthreads();
    // ---- S = Q K^T : per wave 32 q x 64 keys ----
    f32x4 sacc[2][4];
#pragma unroll
    for (int i = 0; i < 2; ++i)
#pragma unroll
      for (int jt = 0; jt < 4; ++jt) sacc[i][jt] = (f32x4){0.f, 0.f, 0.f, 0.f};
#pragma unroll
    for (int kk = 0; kk < 2; ++kk) {
#pragma unroll
      for (int jt = 0; jt < 4; ++jt) {
        h16x8 bf = *(const h16x8*)&Kt[(jt * 16 + c) * LS + kk * 32 + g * 8];
        sacc[0][jt] = __builtin_amdgcn_mfma_f32_16x16x32_f16(qa[0][kk], bf, sacc[0][jt], 0, 0, 0);
        sacc[1][jt] = __builtin_amdgcn_mfma_f32_16x16x32_f16(qa[1][kk], bf, sacc[1][jt], 0, 0, 0);
      }
    }
    // ---- online softmax (fp32) + emit P (f16) to per-wave LDS ----
#pragma unroll
    for (int i = 0; i < 2; ++i) {
#pragma unroll
      for (int r = 0; r < 4; ++r) {
        int iq = qrow0 + i * 16 + g * 4 + r;
        float sv[4];
#pragma unroll
        for (int jt = 0; jt < 4; ++jt) {
          int jk = j0 + jt * 16 + c;
          sv[jt] = (jk <= iq) ? sacc[i][jt][r] : -1e30f;
        }
        float rm = fmaxf(fmaxf(sv[0], sv[1]), fmaxf(sv[2], sv[3]));
#pragma unroll
        for (int off = 1; off < 16; off <<= 1) rm = fmaxf(rm, __shfl_xor(rm, off, 64));
        float mn = fmaxf(mrow[i][r], rm);
        float alpha = __expf(mrow[i][r] - mn);
        mrow[i][r] = mn;
        float ps = 0.f;
        _Float16 ph[4];
#pragma unroll
        for (int jt = 0; jt < 4; ++jt) {
          float p = __expf(sv[jt] - mn);
          ps += p;
          ph[jt] = (_Float16)p;
        }
        // l stays a per-lane partial over this lane's 4 key-columns (alpha is
        // row-uniform after the max reduce) — reduced once in the epilogue.
        lrow[i][r] = lrow[i][r] * alpha + ps;
#pragma unroll
        for (int dt = 0; dt < 4; ++dt) occ[i][dt][r] *= alpha;
#pragma unroll
        for (int jt = 0; jt < 4; ++jt)
          Pl[w][(i * 16 + g * 4 + r) * LS + jt * 16 + c] = ph[jt];
      }
    }
    __syncthreads();  // P write -> P frag read visibility (cross-lane)
    // ---- O += P V : A-frags from Pl, B-frags from Vt ----
#pragma unroll
    for (int kkey = 0; kkey < 2; ++kkey) {
      h16x8 pa0 = *(const h16x8*)&Pl[w][(0 * 16 + c) * LS + kkey * 32 + g * 8];
      h16x8 pa1 = *(const h16x8*)&Pl[w][(1 * 16 + c) * LS + kkey * 32 + g * 8];
#pragma unroll
      for (int dt = 0; dt < 4; ++dt) {
        h16x8 bv = *(const h16x8*)&Vt[(dt * 16 + c) * LS + kkey * 32 + g * 8];
        occ[0][dt] = __builtin_amdgcn_mfma_f32_16x16x32_f16(pa0, bv, occ[0][dt], 0, 0, 0);
        occ[1][dt] = __builtin_amdgcn_mfma_f32_16x16x32_f16(pa1, bv, occ[1][dt], 0, 0, 0);
      }
    }
  }
  // ---- epilogue: finish l reduction across the 16-lane column group, store O f16 ----
#pragma unroll
  for (int i = 0; i < 2; ++i) {
#pragma unroll
    for (int r = 0; r < 4; ++r) {
      float ls = lrow[i][r];
#pragma unroll
      for (int off = 1; off < 16; off <<= 1) ls += __shfl_xor(ls, off, 64);
      float inv = 1.f / ls;
      u16* op = ob + ((size_t)(b * Ss) + qrow0 + i * 16 + g * 4 + r) * (Hh * HDd) +
                hh * HDd + c;
#pragma unroll
      for (int dt = 0; dt < 4; ++dt) op[dt * 16] = f2h(occ[i][dt][r] * inv);
    }
  }
}

// ---------------- Fused router: rmsnorm(h) fp32 -> logits -> top-2 softmax gates ----------------
__global__ __launch_bounds__(64) void router_kernel(const float* __restrict__ h,
                                                    const float* __restrict__ wm,
                                                    const float* __restrict__ rw,
                                                    float* __restrict__ gates) {
  int t = blockIdx.x, lane = threadIdx.x;
  const float* hr = h + (size_t)t * Dd;
  float v[16]; float ss = 0.f;
#pragma unroll
  for (int j = 0; j < 16; ++j) { v[j] = hr[lane + j * 64]; ss += v[j] * v[j]; }
#pragma unroll
  for (int off = 32; off; off >>= 1) ss += __shfl_down(ss, off, 64);
  ss = __shfl(ss, 0, 64);
  float sc = rsqrtf(ss * (1.f / Dd) + EPSf);
  float acc[8] = {};
#pragma unroll
  for (int j = 0; j < 16; ++j) {
    int i = lane + j * 64;
    float yv = v[j] * sc * wm[i];
    float4 w0 = *(const float4*)(rw + (size_t)i * 8);
    float4 w1 = *(const float4*)(rw + (size_t)i * 8 + 4);
    acc[0] += yv * w0.x; acc[1] += yv * w0.y;
    acc[2] += yv * w0.z; acc[3] += yv * w0.w;
    acc[4] += yv * w1.x; acc[5] += yv * w1.y;
    acc[6] += yv * w1.z; acc[7] += yv * w1.w;
  }
#pragma unroll
  for (int off = 32; off; off >>= 1)
#pragma unroll
    for (int e = 0; e < 8; ++e) acc[e] += __shfl_down(acc[e], off, 64);
  if (lane == 0) {
    int i0 = 0; float v0 = acc[0];
#pragma unroll
    for (int e = 1; e < 8; ++e) if (acc[e] > v0) { v0 = acc[e]; i0 = e; }
    int i1 = -1; float v1 = -3.4e38f;
#pragma unroll
    for (int e = 0; e < 8; ++e) if (e != i0 && acc[e] > v1) { v1 = acc[e]; i1 = e; }
    float e1 = __expf(v1 - v0);
    float inv = 1.f / (1.f + e1);
    float* gr = gates + (size_t)t * 8;
#pragma unroll
    for (int e = 0; e < 8; ++e) gr[e] = (e == i0) ? inv : ((e == i1) ? e1 * inv : 0.f);
  }
}

// ---------------- silu(g)*u from fused gu [M][2048] bf16 -> he [M][1024] bf16 ----------------
__global__ __launch_bounds__(256) void silu_mul_kernel(const u16* __restrict__ gu,
                                                       u16* __restrict__ he) {
  size_t idx4 = ((size_t)blockIdx.x * 256 + threadIdx.x) * 4;
  size_t m = idx4 >> 10, f = idx4 & 1023;
  const u16* gp = gu + m * 2048 + f;
  ushort4 gv = *(const ushort4*)gp;
  ushort4 uv = *(const ushort4*)(gp + 1024);
  float g[4] = {bf2f(gv.x), bf2f(gv.y), bf2f(gv.z), bf2f(gv.w)};
  float u[4] = {bf2f(uv.x), bf2f(uv.y), bf2f(uv.z), bf2f(uv.w)};
  ushort4 o;
  o.x = f2bf(g[0] / (1.f + __expf(-g[0])) * u[0]);
  o.y = f2bf(g[1] / (1.f + __expf(-g[1])) * u[1]);
  o.z = f2bf(g[2] / (1.f + __expf(-g[2])) * u[2]);
  o.w = f2bf(g[3] / (1.f + __expf(-g[3])) * u[3]);
  *(ushort4*)(he + m * 1024 + f) = o;
}

extern "C" void kernel_launch(void* const* d_in, const int* in_sizes, int n_in,
                              void* d_out, int out_size, void* d_ws, size_t ws_size,
                              hipStream_t stream) {
  const float* x      = (const float*)d_in[0];
  const float* cosb   = (const float*)d_in[1];
  const float* sinb   = (const float*)d_in[2];
  // d_in[3] = mask — causal, hard-coded in flash
  const float* w_attn = (const float*)d_in[4];
  const float* w_moe  = (const float*)d_in[5];
  const float* Wq = (const float*)d_in[6];
  const float* Wk = (const float*)d_in[7];
  const float* Wv = (const float*)d_in[8];
  const float* Wo = (const float*)d_in[9];
  const float* Wr = (const float*)d_in[10];
  const float* Wg = (const float*)d_in[11];
  const float* Wu = (const float*)d_in[12];
  const float* Wd = (const float*)d_in[13];
  float* out  = (float*)d_out;
  float* outk = out + (size_t)Tt * Dd;
  float* outv = outk + (size_t)Tt * KVh * HDd;

  // ---- workspace layout (112 MB budget) ----
  char* ws8 = (char*)d_ws;
  u16*   xnb   = (u16*)(ws8);                    // 16 MB f16 : xnb -> ob -> y
  u16*   ob    = (u16*)(ws8);                    //   (o f16, after xnb dead)
  u16*   y     = (u16*)(ws8);                    //   (bf16 MoE input, after ob dead)
  float* gates = (float*)(ws8 + 16777216);       // 256 KB
  u16*   wbuf  = (u16*)(ws8 + 17825792);         // 6 MB shared weight region
  u16*   WqT   = wbuf;                           // f16 [1024][1024] 2 MB
  u16*   WkT   = wbuf + (size_t)1024 * 1024;     // f16 [256][1024]  0.5 MB
  u16*   WvT   = WkT + (size_t)256 * 1024;       // f16 [256][1024]  0.5 MB
  u16*   WoT   = WvT + (size_t)256 * 1024;       // f16 [1024][1024] 2 MB
  u16*   WguT  = wbuf;                           // bf16 [2048][1024] 4 MB (MoE reuse)
  u16*   WdT   = wbuf + (size_t)2048 * 1024;     // bf16 [1024][1024] 2 MB
  float* q     = (float*)(ws8 + 33554432);       // 32 MB fp32 -> gu bf16 [T][2048]
  u16*   gu    = (u16*)q;
  float* kf    = (float*)(ws8 + 67108864);       //  8 MB
  float* vf    = (float*)(ws8 + 75497472);       //  8 MB
  u16*   he    = (u16*)kf;                       // 16 MB (spans kf+vf, after flash)
  float* h     = (float*)(ws8 + 83886080);       // 32 MB

  // 1. xnb = rmsnorm(x, w_attn) -> f16
  rmsnorm_kernel<2><<<Tt, 256, 0, stream>>>(x, w_attn, xnb);
  // 2. transpose attention weights -> f16 [N][K]
  transpose_kernel<true><<<dim3(16, 16), 256, 0, stream>>>(Wq, WqT, 1024);
  transpose_kernel<true><<<dim3(4, 16), 256, 0, stream>>>(Wk, WkT, 256);
  transpose_kernel<true><<<dim3(4, 16), 256, 0, stream>>>(Wv, WvT, 256);
  transpose_kernel<true><<<dim3(16, 16), 256, 0, stream>>>(Wo, WoT, 1024);
  // 3. q/k/v projections (f16 MFMA, fp32 out)
  mfma_gemm<0, true><<<dim3(8, 64), 256, 0, stream>>>(xnb, WqT, q, nullptr, nullptr, nullptr, 0, 1024, 1024);
  mfma_gemm<0, true><<<dim3(2, 64), 256, 0, stream>>>(xnb, WkT, kf, nullptr, nullptr, nullptr, 0, 256, 1024);
  mfma_gemm<0, true><<<dim3(2, 64), 256, 0, stream>>>(xnb, WvT, vf, nullptr, nullptr, nullptr, 0, 256, 1024);
  // 4. RoPE; emit fp32 k,v outputs
  rope_q_kernel<<<(Tt * Hh * 32) / 256, 256, 0, stream>>>(q, cosb, sinb);
  ropek_kv_kernel<<<(Tt * KVh * 32) / 256, 256, 0, stream>>>(kf, vf, cosb, sinb, outk, outv);
  // 5. causal GQA flash attention (MFMA f16) -> ob (f16)
  flash_mfma<<<Bb * Hh * (Ss / 128), 256, 0, stream>>>(q, kf, vf, ob);
  // 6. h = ob @ WoT + x (f16 MFMA, fp32 out + resid)
  mfma_gemm<1, true><<<dim3(8, 64), 256, 0, stream>>>(ob, WoT, h, nullptr, x, nullptr, 0, 1024, 1024);
  // 7. y = rmsnorm(h) -> bf16 (MoE input); fused fp32 router -> gates
  rmsnorm_kernel<1><<<Tt, 256, 0, stream>>>(h, w_moe, y);
  router_kernel<<<Tt, 64, 0, stream>>>(h, w_moe, Wr, gates);
  // 8. out = h, then MoE accumulates
  hipMemcpyAsync(out, h, (size_t)Tt * Dd * sizeof(float), hipMemcpyDeviceToDevice, stream);
  // 9. dense MoE, bf16 MFMA (gates are 0 for unrouted tokens)
  for (int e = 0; e < Ee; ++e) {
    transpose_kernel<false><<<dim3(16, 16), 256, 0, stream>>>(Wg + (size_t)e * Dd * Ff, WguT, 1024);
    transpose_kernel<false><<<dim3(16, 16), 256, 0, stream>>>(Wu + (size_t)e * Dd * Ff, WguT + (size_t)1024 * 1024, 1024);
    transpose_kernel<false><<<dim3(16, 16), 256, 0, stream>>>(Wd + (size_t)e * Ff * Dd, WdT, 1024);
    mfma_gemm<2, false><<<dim3(16, 64), 256, 0, stream>>>(y, WguT, nullptr, gu, nullptr, nullptr, 0, 2048, 1024);
    silu_mul_kernel<<<(Tt * 1024) / 1024, 256, 0, stream>>>(gu, he);
    mfma_gemm<3, false><<<dim3(8, 64), 256, 0, stream>>>(he, WdT, out, nullptr, nullptr, gates, e, 1024, 1024);
  }
}

// Round 3
// 1333.399 us; speedup vs baseline: 2.3577x; 1.1555x over previous
//
#include <hip/hip_runtime.h>
#include <stdint.h>

// ---- problem constants ----
constexpr int Bb = 4, Ss = 2048, Dd = 1024;
constexpr int Hh = 16, KVh = 4, HDd = 64;
constexpr int Ee = 8, Ff = 1024;
constexpr int Tt = Bb * Ss;           // 8192 tokens
constexpr float EPSf = 1e-6f;

typedef unsigned short u16;
typedef __attribute__((ext_vector_type(8))) short short8;       // 8 bf16/f16 (4 VGPRs)
typedef __attribute__((ext_vector_type(4))) float f32x4;        // 4 fp32 acc
typedef __attribute__((ext_vector_type(8))) _Float16 h16x8;     // 8 f16 (4 VGPRs)
typedef __attribute__((ext_vector_type(4))) _Float16 h16x4;     // 4 f16 (8B)

__device__ __forceinline__ float bf2f(u16 u) {
  union { unsigned int i; float f; } x; x.i = ((unsigned int)u) << 16; return x.f;
}
__device__ __forceinline__ u16 f2bf(float f) {
  union { float f; unsigned int i; } x; x.f = f;
  unsigned int r = x.i + 0x7fffu + ((x.i >> 16) & 1u);
  return (u16)(r >> 16);
}
__device__ __forceinline__ u16 f2h(float f) {
  union { _Float16 h; u16 u; } x; x.h = (_Float16)f; return x.u;
}
__device__ __forceinline__ h16x8 as_h(short8 v) {
  union { short8 s; h16x8 h; } u; u.s = v; return u.h;
}

// ---------------- fp32 [1024][N] -> 16-bit [N][1024] transpose-convert ----------------
// F16H=false: bf16 out (MoE weights)   F16H=true: f16 out (attention weights)
// blockIdx.z batches experts: W += z*wes, WT += z*tes.
template <bool F16H>
__global__ __launch_bounds__(256) void transpose_kernel(const float* __restrict__ W,
                                                        u16* __restrict__ WT, int N,
                                                        size_t wes, size_t tes) {
  W += (size_t)blockIdx.z * wes;
  WT += (size_t)blockIdx.z * tes;
  __shared__ float tile[64][65];
  int n0 = blockIdx.x * 64, k0 = blockIdx.y * 64;
  int tid = threadIdx.x, r = tid >> 6, c = tid & 63;
#pragma unroll
  for (int p = 0; p < 16; ++p)
    tile[p * 4 + r][c] = W[(size_t)(k0 + p * 4 + r) * N + n0 + c];
  __syncthreads();
#pragma unroll
  for (int p = 0; p < 16; ++p) {
    float v = tile[c][p * 4 + r];
    WT[(size_t)(n0 + p * 4 + r) * 1024 + k0 + c] = F16H ? f2h(v) : f2bf(v);
  }
}

// ---------------- RMSNorm: fp32 in -> FMT out (0=f32, 1=bf16, 2=f16) ----------------
template <int FMT>
__global__ __launch_bounds__(256) void rmsnorm_kernel(const float* __restrict__ x,
                                                      const float* __restrict__ w,
                                                      void* __restrict__ outp) {
  int t = blockIdx.x, tid = threadIdx.x;
  __shared__ float red[4];
  const float* xr = x + (size_t)t * Dd;
  float v[4]; float ss = 0.f;
#pragma unroll
  for (int i = 0; i < 4; ++i) { v[i] = xr[tid + 256 * i]; ss += v[i] * v[i]; }
#pragma unroll
  for (int off = 32; off; off >>= 1) ss += __shfl_down(ss, off, 64);
  if ((tid & 63) == 0) red[tid >> 6] = ss;
  __syncthreads();
  float tot = red[0] + red[1] + red[2] + red[3];
  float sc = rsqrtf(tot * (1.f / Dd) + EPSf);
#pragma unroll
  for (int i = 0; i < 4; ++i) {
    size_t idx = (size_t)t * Dd + tid + 256 * i;
    float val = v[i] * sc * w[tid + 256 * i];
    if constexpr (FMT == 0) ((float*)outp)[idx] = val;
    else if constexpr (FMT == 1) ((u16*)outp)[idx] = f2bf(val);
    else ((u16*)outp)[idx] = f2h(val);
  }
}

// ---------------- MFMA 16-bit GEMM (attention path): C[M,N] = A[M,K] @ BT[N,K] ----------------
// MODE 0: Cf = C     MODE 1: Cf = C + resid
template <int MODE, bool F16H>
__global__ __launch_bounds__(256) void mfma_gemm(const u16* __restrict__ A,
                                                 const u16* __restrict__ BT,
                                                 float* __restrict__ Cf,
                                                 const float* __restrict__ resid,
                                                 int N, int K) {
  constexpr int LS = 40;                 // u16 row stride (32 + 8 pad)
  __shared__ u16 As[128 * LS];
  __shared__ u16 Bs[128 * LS];
  int tid = threadIdx.x;
  int m0 = blockIdx.y * 128, n0 = blockIdx.x * 128;
  int lane = tid & 63, w = tid >> 6;
  int wm = (w & 1) * 64, wn = (w >> 1) * 64;
  f32x4 acc[4][4];
#pragma unroll
  for (int i = 0; i < 4; ++i)
#pragma unroll
    for (int j = 0; j < 4; ++j) acc[i][j] = (f32x4){0.f, 0.f, 0.f, 0.f};

  int row = tid >> 2, col8 = (tid & 3) * 8;
  int row1 = row + 64;
  const u16* gA0 = A + (size_t)(m0 + row) * K + col8;
  const u16* gA1 = A + (size_t)(m0 + row1) * K + col8;
  const u16* gB0 = BT + (size_t)(n0 + row) * K + col8;
  const u16* gB1 = BT + (size_t)(n0 + row1) * K + col8;
  int lo0 = row * LS + col8, lo1 = row1 * LS + col8;
  int afo[4], bfo[4];
#pragma unroll
  for (int i = 0; i < 4; ++i) {
    afo[i] = (wm + i * 16 + (lane & 15)) * LS + (lane >> 4) * 8;
    bfo[i] = (wn + i * 16 + (lane & 15)) * LS + (lane >> 4) * 8;
  }

  for (int kt = 0; kt < K; kt += 32) {
    short8 va0 = *(const short8*)(gA0 + kt);
    short8 va1 = *(const short8*)(gA1 + kt);
    short8 vb0 = *(const short8*)(gB0 + kt);
    short8 vb1 = *(const short8*)(gB1 + kt);
    __syncthreads();
    *(short8*)&As[lo0] = va0;
    *(short8*)&As[lo1] = va1;
    *(short8*)&Bs[lo0] = vb0;
    *(short8*)&Bs[lo1] = vb1;
    __syncthreads();
    short8 af[4], bfr[4];
#pragma unroll
    for (int i = 0; i < 4; ++i) af[i] = *(const short8*)&As[afo[i]];
#pragma unroll
    for (int j = 0; j < 4; ++j) bfr[j] = *(const short8*)&Bs[bfo[j]];
#pragma unroll
    for (int i = 0; i < 4; ++i)
#pragma unroll
      for (int j = 0; j < 4; ++j) {
        if constexpr (F16H)
          acc[i][j] = __builtin_amdgcn_mfma_f32_16x16x32_f16(as_h(af[i]), as_h(bfr[j]),
                                                             acc[i][j], 0, 0, 0);
        else
          acc[i][j] = __builtin_amdgcn_mfma_f32_16x16x32_bf16(af[i], bfr[j],
                                                              acc[i][j], 0, 0, 0);
      }
  }

  int r0 = (lane >> 4) * 4, cc = lane & 15;   // C/D: row=(lane>>4)*4+reg, col=lane&15
#pragma unroll
  for (int i = 0; i < 4; ++i) {
#pragma unroll
    for (int r = 0; r < 4; ++r) {
      int m = m0 + wm + i * 16 + r0 + r;
#pragma unroll
      for (int j = 0; j < 4; ++j) {
        int n = n0 + wn + j * 16 + cc;
        size_t off = (size_t)m * N + n;
        float v = acc[i][j][r];
        if constexpr (MODE == 0) Cf[off] = v;
        else Cf[off] = v + resid[off];
      }
    }
  }
}

// ---------------- Routed MoE up-GEMM: gu[m] = y[elist[m]] @ WguT  (bf16, 128x128) ----------------
__global__ __launch_bounds__(256) void moe_gemm_up(const u16* __restrict__ A,
                                                   const u16* __restrict__ BT,
                                                   u16* __restrict__ Cb,
                                                   const int* __restrict__ elist_e,
                                                   const int* __restrict__ cnt_e,
                                                   int N, int K) {
  int count = *cnt_e;
  int m0 = blockIdx.y * 128;
  if (m0 >= count) return;                 // uniform early-exit (before any barrier)
  constexpr int LS = 40;
  __shared__ u16 As[128 * LS];
  __shared__ u16 Bs[128 * LS];
  int tid = threadIdx.x;
  int n0 = blockIdx.x * 128;
  int lane = tid & 63, w = tid >> 6;
  int wm = (w & 1) * 64, wn = (w >> 1) * 64;
  f32x4 acc[4][4];
#pragma unroll
  for (int i = 0; i < 4; ++i)
#pragma unroll
    for (int j = 0; j < 4; ++j) acc[i][j] = (f32x4){0.f, 0.f, 0.f, 0.f};

  int row = tid >> 2, col8 = (tid & 3) * 8;
  int mr0 = m0 + row, mr1 = mr0 + 64;
  int t0 = (mr0 < count) ? elist_e[mr0] : 0;   // padded rows compute garbage, never consumed
  int t1 = (mr1 < count) ? elist_e[mr1] : 0;
  const u16* gA0 = A + (size_t)t0 * K + col8;
  const u16* gA1 = A + (size_t)t1 * K + col8;
  const u16* gB0 = BT + (size_t)(n0 + row) * K + col8;
  const u16* gB1 = BT + (size_t)(n0 + row + 64) * K + col8;
  int lo0 = row * LS + col8, lo1 = (row + 64) * LS + col8;
  int afo[4], bfo[4];
#pragma unroll
  for (int i = 0; i < 4; ++i) {
    afo[i] = (wm + i * 16 + (lane & 15)) * LS + (lane >> 4) * 8;
    bfo[i] = (wn + i * 16 + (lane & 15)) * LS + (lane >> 4) * 8;
  }

  for (int kt = 0; kt < K; kt += 32) {
    short8 va0 = *(const short8*)(gA0 + kt);
    short8 va1 = *(const short8*)(gA1 + kt);
    short8 vb0 = *(const short8*)(gB0 + kt);
    short8 vb1 = *(const short8*)(gB1 + kt);
    __syncthreads();
    *(short8*)&As[lo0] = va0;
    *(short8*)&As[lo1] = va1;
    *(short8*)&Bs[lo0] = vb0;
    *(short8*)&Bs[lo1] = vb1;
    __syncthreads();
    short8 af[4], bfr[4];
#pragma unroll
    for (int i = 0; i < 4; ++i) af[i] = *(const short8*)&As[afo[i]];
#pragma unroll
    for (int j = 0; j < 4; ++j) bfr[j] = *(const short8*)&Bs[bfo[j]];
#pragma unroll
    for (int i = 0; i < 4; ++i)
#pragma unroll
      for (int j = 0; j < 4; ++j)
        acc[i][j] = __builtin_amdgcn_mfma_f32_16x16x32_bf16(af[i], bfr[j], acc[i][j], 0, 0, 0);
  }

  int r0 = (lane >> 4) * 4, cc = lane & 15;
#pragma unroll
  for (int i = 0; i < 4; ++i)
#pragma unroll
    for (int r = 0; r < 4; ++r) {
      int m = m0 + wm + i * 16 + r0 + r;
      u16* crow = Cb + (size_t)m * N;
#pragma unroll
      for (int j = 0; j < 4; ++j) crow[n0 + wn + j * 16 + cc] = f2bf(acc[i][j][r]);
    }
}

// ---------------- Routed MoE down-GEMM: out[elist[m]] += gate * (he[m] @ WdT)  (64x128) ----------------
__global__ __launch_bounds__(256) void moe_gemm_down(const u16* __restrict__ A,
                                                     const u16* __restrict__ BT,
                                                     float* __restrict__ Cf,
                                                     const float* __restrict__ gates, int e,
                                                     const int* __restrict__ elist_e,
                                                     const int* __restrict__ cnt_e,
                                                     int N, int K) {
  int count = *cnt_e;
  int m0 = blockIdx.y * 64;
  if (m0 >= count) return;
  constexpr int LS = 40;
  __shared__ u16 As[64 * LS];
  __shared__ u16 Bs[128 * LS];
  int tid = threadIdx.x;
  int n0 = blockIdx.x * 128;
  int lane = tid & 63, w = tid >> 6;
  int wm = (w & 1) * 32, wn = (w >> 1) * 64;
  int c = lane & 15, g = lane >> 4;
  f32x4 acc[2][4];
#pragma unroll
  for (int i = 0; i < 2; ++i)
#pragma unroll
    for (int j = 0; j < 4; ++j) acc[i][j] = (f32x4){0.f, 0.f, 0.f, 0.f};

  int row = tid >> 2, col8 = (tid & 3) * 8;
  // A rows: compact he; rows >= count read stale in-buffer data, results discarded.
  const u16* gA0 = A + (size_t)(m0 + row) * K + col8;
  const u16* gB0 = BT + (size_t)(n0 + row) * K + col8;
  const u16* gB1 = BT + (size_t)(n0 + row + 64) * K + col8;
  int loA = row * LS + col8;
  int loB0 = row * LS + col8, loB1 = (row + 64) * LS + col8;
  int afo[2], bfo[4];
#pragma unroll
  for (int i = 0; i < 2; ++i) afo[i] = (wm + i * 16 + c) * LS + g * 8;
#pragma unroll
  for (int j = 0; j < 4; ++j) bfo[j] = (wn + j * 16 + c) * LS + g * 8;

  for (int kt = 0; kt < K; kt += 32) {
    short8 va = *(const short8*)(gA0 + kt);
    short8 vb0 = *(const short8*)(gB0 + kt);
    short8 vb1 = *(const short8*)(gB1 + kt);
    __syncthreads();
    *(short8*)&As[loA] = va;
    *(short8*)&Bs[loB0] = vb0;
    *(short8*)&Bs[loB1] = vb1;
    __syncthreads();
    short8 af[2], bfr[4];
#pragma unroll
    for (int i = 0; i < 2; ++i) af[i] = *(const short8*)&As[afo[i]];
#pragma unroll
    for (int j = 0; j < 4; ++j) bfr[j] = *(const short8*)&Bs[bfo[j]];
#pragma unroll
    for (int i = 0; i < 2; ++i)
#pragma unroll
      for (int j = 0; j < 4; ++j)
        acc[i][j] = __builtin_amdgcn_mfma_f32_16x16x32_bf16(af[i], bfr[j], acc[i][j], 0, 0, 0);
  }

  int r0 = g * 4;
#pragma unroll
  for (int i = 0; i < 2; ++i)
#pragma unroll
    for (int r = 0; r < 4; ++r) {
      int m = m0 + wm + i * 16 + r0 + r;
      if (m < count) {
        int tok = elist_e[m];
        float gt = gates[(size_t)tok * Ee + e];
        float* orow = Cf + (size_t)tok * N;
#pragma unroll
        for (int j = 0; j < 4; ++j) {
          int n = n0 + wn + j * 16 + c;
          orow[n] += gt * acc[i][j][r];
        }
      }
    }
}

// ---------------- RoPE on q (fp32, in place); also zeroes expert counters ----------------
__global__ __launch_bounds__(256) void rope_q_kernel(float* __restrict__ q,
                                                     const float* __restrict__ cosb,
                                                     const float* __restrict__ sinb,
                                                     int* __restrict__ cnt) {
  if (blockIdx.x == 0 && threadIdx.x < Ee) cnt[threadIdx.x] = 0;
  int idx = blockIdx.x * 256 + threadIdx.x;  // Tt*H*32
  int d = idx & 31;
  int hh = (idx >> 5) & (Hh - 1);
  int t = idx >> 9;
  int s = t & (Ss - 1);
  float c = cosb[s * HDd + d], sn = sinb[s * HDd + d];
  float* qp = q + (size_t)t * (Hh * HDd) + hh * HDd;
  float a = qp[d], b = qp[d + 32];
  qp[d] = a * c - b * sn;
  qp[d + 32] = b * c + a * sn;
}

// ---------------- RoPE on k (in place) + emit fp32 k,v outputs ----------------
__global__ __launch_bounds__(256) void ropek_kv_kernel(float* __restrict__ kf,
                                                       const float* __restrict__ vf,
                                                       const float* __restrict__ cosb,
                                                       const float* __restrict__ sinb,
                                                       float* __restrict__ outk,
                                                       float* __restrict__ outv) {
  int idx = blockIdx.x * 256 + threadIdx.x;  // Tt*KV*32
  int d = idx & 31;
  int kv = (idx >> 5) & (KVh - 1);
  int t = idx >> 7;
  int s = t & (Ss - 1);
  float c = cosb[s * HDd + d], sn = sinb[s * HDd + d];
  size_t base = (size_t)t * (KVh * HDd) + kv * HDd;
  float a = kf[base + d], b = kf[base + d + 32];
  float r1 = a * c - b * sn, r2 = b * c + a * sn;
  kf[base + d] = r1; kf[base + d + 32] = r2;
  outk[base + d] = r1; outk[base + d + 32] = r2;
  outv[base + d] = vf[base + d]; outv[base + d + 32] = vf[base + d + 32];
}

// ---------------- MFMA f16 flash attention ----------------
// Block = 128 q-rows of one (b,h), 4 waves x 32 q-rows. K-tile = 64 keys.
__global__ __launch_bounds__(256) void flash_mfma(const float* __restrict__ q,
                                                  const float* __restrict__ kf,
                                                  const float* __restrict__ vf,
                                                  u16* __restrict__ ob) {
  constexpr int LS = 72;  // halves per row: 144B, 16B aligned, padded vs 128B
  __shared__ __align__(16) _Float16 Kt[64 * LS];
  __shared__ __align__(16) _Float16 Vt[64 * LS];       // Vt[d][key]
  __shared__ __align__(16) _Float16 Pl[4][32 * LS];    // per-wave P[q][key]
  int tid = threadIdx.x;
  int qt = 15 - (blockIdx.x & 15);      // heavy q-tiles first
  int bh = blockIdx.x >> 4;
  int b = bh >> 4, hh = bh & 15;
  int w = tid >> 6, lane = tid & 63;
  int c = lane & 15, g = lane >> 4;
  int kvh = hh >> 2;                    // H/KV = 4
  const float* Kbase = kf + (size_t)b * Ss * (KVh * HDd) + kvh * HDd;
  const float* Vbase = vf + (size_t)b * Ss * (KVh * HDd) + kvh * HDd;
  int qrow0 = qt * 128 + w * 32;

  h16x8 qa[2][2];
#pragma unroll
  for (int i = 0; i < 2; ++i) {
#pragma unroll
    for (int kk = 0; kk < 2; ++kk) {
      const float* qp = q + ((size_t)(b * Ss) + qrow0 + i * 16 + c) * (Hh * HDd) +
                        hh * HDd + kk * 32 + g * 8;
      float4 v0 = *(const float4*)qp;
      float4 v1 = *(const float4*)(qp + 4);
      h16x8 hv;
      hv[0] = (_Float16)(v0.x * 0.125f); hv[1] = (_Float16)(v0.y * 0.125f);
      hv[2] = (_Float16)(v0.z * 0.125f); hv[3] = (_Float16)(v0.w * 0.125f);
      hv[4] = (_Float16)(v1.x * 0.125f); hv[5] = (_Float16)(v1.y * 0.125f);
      hv[6] = (_Float16)(v1.z * 0.125f); hv[7] = (_Float16)(v1.w * 0.125f);
      qa[i][kk] = hv;
    }
  }

  f32x4 occ[2][4];
#pragma unroll
  for (int i = 0; i < 2; ++i)
#pragma unroll
    for (int dt = 0; dt < 4; ++dt) occ[i][dt] = (f32x4){0.f, 0.f, 0.f, 0.f};
  float mrow[2][4], lrow[2][4];
#pragma unroll
  for (int i = 0; i < 2; ++i)
#pragma unroll
    for (int r = 0; r < 4; ++r) { mrow[i][r] = -1e30f; lrow[i][r] = 0.f; }

  int kmax = qt * 128 + 128;
  int lr = tid >> 2, lc4 = (tid & 3) * 16;
  int vk = tid >> 4, vc = (tid & 15) * 4;

  for (int j0 = 0; j0 < kmax; j0 += 64) {
    __syncthreads();
    const float* krow = Kbase + (size_t)(j0 + lr) * (KVh * HDd) + lc4;
#pragma unroll
    for (int u = 0; u < 4; ++u) {
      float4 kv = *(const float4*)(krow + u * 4);
      h16x4 h;
      h[0] = (_Float16)kv.x; h[1] = (_Float16)kv.y;
      h[2] = (_Float16)kv.z; h[3] = (_Float16)kv.w;
      *(h16x4*)&Kt[lr * LS + lc4 + u * 4] = h;
    }
#pragma unroll
    for (int u = 0; u < 4; ++u) {
      const float* vrow = Vbase + (size_t)(j0 + vk + u * 16) * (KVh * HDd) + vc;
      float4 vv = *(const float4*)vrow;
      Vt[(vc + 0) * LS + vk + u * 16] = (_Float16)vv.x;
      Vt[(vc + 1) * LS + vk + u * 16] = (_Float16)vv.y;
      Vt[(vc + 2) * LS + vk + u * 16] = (_Float16)vv.z;
      Vt[(vc + 3) * LS + vk + u * 16] = (_Float16)vv.w;
    }
    __syncthreads();
    f32x4 sacc[2][4];
#pragma unroll
    for (int i = 0; i < 2; ++i)
#pragma unroll
      for (int jt = 0; jt < 4; ++jt) sacc[i][jt] = (f32x4){0.f, 0.f, 0.f, 0.f};
#pragma unroll
    for (int kk = 0; kk < 2; ++kk) {
#pragma unroll
      for (int jt = 0; jt < 4; ++jt) {
        h16x8 bf = *(const h16x8*)&Kt[(jt * 16 + c) * LS + kk * 32 + g * 8];
        sacc[0][jt] = __builtin_amdgcn_mfma_f32_16x16x32_f16(qa[0][kk], bf, sacc[0][jt], 0, 0, 0);
        sacc[1][jt] = __builtin_amdgcn_mfma_f32_16x16x32_f16(qa[1][kk], bf, sacc[1][jt], 0, 0, 0);
      }
    }
#pragma unroll
    for (int i = 0; i < 2; ++i) {
#pragma unroll
      for (int r = 0; r < 4; ++r) {
        int iq = qrow0 + i * 16 + g * 4 + r;
        float sv[4];
#pragma unroll
        for (int jt = 0; jt < 4; ++jt) {
          int jk = j0 + jt * 16 + c;
          sv[jt] = (jk <= iq) ? sacc[i][jt][r] : -1e30f;
        }
        float rm = fmaxf(fmaxf(sv[0], sv[1]), fmaxf(sv[2], sv[3]));
#pragma unroll
        for (int off = 1; off < 16; off <<= 1) rm = fmaxf(rm, __shfl_xor(rm, off, 64));
        float mn = fmaxf(mrow[i][r], rm);
        float alpha = __expf(mrow[i][r] - mn);
        mrow[i][r] = mn;
        float ps = 0.f;
        _Float16 ph[4];
#pragma unroll
        for (int jt = 0; jt < 4; ++jt) {
          float p = __expf(sv[jt] - mn);
          ps += p;
          ph[jt] = (_Float16)p;
        }
        lrow[i][r] = lrow[i][r] * alpha + ps;
#pragma unroll
        for (int dt = 0; dt < 4; ++dt) occ[i][dt][r] *= alpha;
#pragma unroll
        for (int jt = 0; jt < 4; ++jt)
          Pl[w][(i * 16 + g * 4 + r) * LS + jt * 16 + c] = ph[jt];
      }
    }
    __syncthreads();
#pragma unroll
    for (int kkey = 0; kkey < 2; ++kkey) {
      h16x8 pa0 = *(const h16x8*)&Pl[w][(0 * 16 + c) * LS + kkey * 32 + g * 8];
      h16x8 pa1 = *(const h16x8*)&Pl[w][(1 * 16 + c) * LS + kkey * 32 + g * 8];
#pragma unroll
      for (int dt = 0; dt < 4; ++dt) {
        h16x8 bv = *(const h16x8*)&Vt[(dt * 16 + c) * LS + kkey * 32 + g * 8];
        occ[0][dt] = __builtin_amdgcn_mfma_f32_16x16x32_f16(pa0, bv, occ[0][dt], 0, 0, 0);
        occ[1][dt] = __builtin_amdgcn_mfma_f32_16x16x32_f16(pa1, bv, occ[1][dt], 0, 0, 0);
      }
    }
  }
#pragma unroll
  for (int i = 0; i < 2; ++i) {
#pragma unroll
    for (int r = 0; r < 4; ++r) {
      float ls = lrow[i][r];
#pragma unroll
      for (int off = 1; off < 16; off <<= 1) ls += __shfl_xor(ls, off, 64);
      float inv = 1.f / ls;
      u16* op = ob + ((size_t)(b * Ss) + qrow0 + i * 16 + g * 4 + r) * (Hh * HDd) +
                hh * HDd + c;
#pragma unroll
      for (int dt = 0; dt < 4; ++dt) op[dt * 16] = f2h(occ[i][dt][r] * inv);
    }
  }
}

// ---------------- Fused router: rmsnorm(h) -> logits -> top-2 gates + expert lists ----------------
__global__ __launch_bounds__(64) void router_kernel(const float* __restrict__ h,
                                                    const float* __restrict__ wm,
                                                    const float* __restrict__ rw,
                                                    float* __restrict__ gates,
                                                    int* __restrict__ cnt,
                                                    int* __restrict__ elist) {
  int t = blockIdx.x, lane = threadIdx.x;
  const float* hr = h + (size_t)t * Dd;
  float v[16]; float ss = 0.f;
#pragma unroll
  for (int j = 0; j < 16; ++j) { v[j] = hr[lane + j * 64]; ss += v[j] * v[j]; }
#pragma unroll
  for (int off = 32; off; off >>= 1) ss += __shfl_down(ss, off, 64);
  ss = __shfl(ss, 0, 64);
  float sc = rsqrtf(ss * (1.f / Dd) + EPSf);
  float acc[8] = {};
#pragma unroll
  for (int j = 0; j < 16; ++j) {
    int i = lane + j * 64;
    float yv = v[j] * sc * wm[i];
    float4 w0 = *(const float4*)(rw + (size_t)i * 8);
    float4 w1 = *(const float4*)(rw + (size_t)i * 8 + 4);
    acc[0] += yv * w0.x; acc[1] += yv * w0.y;
    acc[2] += yv * w0.z; acc[3] += yv * w0.w;
    acc[4] += yv * w1.x; acc[5] += yv * w1.y;
    acc[6] += yv * w1.z; acc[7] += yv * w1.w;
  }
#pragma unroll
  for (int off = 32; off; off >>= 1)
#pragma unroll
    for (int e = 0; e < 8; ++e) acc[e] += __shfl_down(acc[e], off, 64);
  if (lane == 0) {
    int i0 = 0; float v0 = acc[0];
#pragma unroll
    for (int e = 1; e < 8; ++e) if (acc[e] > v0) { v0 = acc[e]; i0 = e; }
    int i1 = -1; float v1 = -3.4e38f;
#pragma unroll
    for (int e = 0; e < 8; ++e) if (e != i0 && acc[e] > v1) { v1 = acc[e]; i1 = e; }
    float e1 = __expf(v1 - v0);
    float inv = 1.f / (1.f + e1);
    float* gr = gates + (size_t)t * 8;
#pragma unroll
    for (int e = 0; e < 8; ++e) gr[e] = (e == i0) ? inv : ((e == i1) ? e1 * inv : 0.f);
    int p0 = atomicAdd(&cnt[i0], 1); elist[(size_t)i0 * Tt + p0] = t;
    int p1 = atomicAdd(&cnt[i1], 1); elist[(size_t)i1 * Tt + p1] = t;
  }
}

// ---------------- silu(g)*u from fused gu [m][2048] bf16 -> he [m][1024] bf16 (routed) ----------------
__global__ __launch_bounds__(256) void silu_mul_kernel(const u16* __restrict__ gu,
                                                       u16* __restrict__ he,
                                                       const int* __restrict__ cnt_e) {
  if ((int)blockIdx.x >= *cnt_e) return;   // block <-> compact row m
  size_t idx4 = ((size_t)blockIdx.x * 256 + threadIdx.x) * 4;
  size_t m = idx4 >> 10, f = idx4 & 1023;
  const u16* gp = gu + m * 2048 + f;
  ushort4 gv = *(const ushort4*)gp;
  ushort4 uv = *(const ushort4*)(gp + 1024);
  float g[4] = {bf2f(gv.x), bf2f(gv.y), bf2f(gv.z), bf2f(gv.w)};
  float u[4] = {bf2f(uv.x), bf2f(uv.y), bf2f(uv.z), bf2f(uv.w)};
  ushort4 o;
  o.x = f2bf(g[0] / (1.f + __expf(-g[0])) * u[0]);
  o.y = f2bf(g[1] / (1.f + __expf(-g[1])) * u[1]);
  o.z = f2bf(g[2] / (1.f + __expf(-g[2])) * u[2]);
  o.w = f2bf(g[3] / (1.f + __expf(-g[3])) * u[3]);
  *(ushort4*)(he + m * 1024 + f) = o;
}

extern "C" void kernel_launch(void* const* d_in, const int* in_sizes, int n_in,
                              void* d_out, int out_size, void* d_ws, size_t ws_size,
                              hipStream_t stream) {
  const float* x      = (const float*)d_in[0];
  const float* cosb   = (const float*)d_in[1];
  const float* sinb   = (const float*)d_in[2];
  // d_in[3] = mask — causal, hard-coded in flash
  const float* w_attn = (const float*)d_in[4];
  const float* w_moe  = (const float*)d_in[5];
  const float* Wq = (const float*)d_in[6];
  const float* Wk = (const float*)d_in[7];
  const float* Wv = (const float*)d_in[8];
  const float* Wo = (const float*)d_in[9];
  const float* Wr = (const float*)d_in[10];
  const float* Wg = (const float*)d_in[11];
  const float* Wu = (const float*)d_in[12];
  const float* Wd = (const float*)d_in[13];
  float* out  = (float*)d_out;
  float* outk = out + (size_t)Tt * Dd;
  float* outv = outk + (size_t)Tt * KVh * HDd;

  // ---- workspace layout (112 MB budget) ----
  char* ws8 = (char*)d_ws;
  u16*   xnb   = (u16*)(ws8);                    // 16 MB f16 : xnb -> ob -> y
  u16*   ob    = (u16*)(ws8);
  u16*   y     = (u16*)(ws8);
  float* gates = (float*)(ws8 + 16777216);       // 256 KB
  int*   cnt   = (int*)(ws8 + 17039360);         // 32 B expert counters
  int*   elist = (int*)(ws8 + 17040384);         // 256 KB expert token lists [8][8192]
  u16*   wbuf  = (u16*)(ws8 + 17825792);         // 6 MB shared weight region
  u16*   WqT   = wbuf;                           // f16 [1024][1024] 2 MB
  u16*   WkT   = wbuf + (size_t)1024 * 1024;     // f16 [256][1024]  0.5 MB
  u16*   WvT   = WkT + (size_t)256 * 1024;       // f16 [256][1024]  0.5 MB
  u16*   WoT   = WvT + (size_t)256 * 1024;       // f16 [1024][1024] 2 MB
  u16*   WdT   = wbuf;                           // bf16 [1024][1024] 2 MB (per-expert, loop)
  float* q     = (float*)(ws8 + 33554432);       // 32 MB fp32 -> gu bf16 (compact, worst 8192 rows)
  u16*   gu    = (u16*)q;
  float* kf    = (float*)(ws8 + 67108864);       //  8 MB
  float* vf    = (float*)(ws8 + 75497472);       //  8 MB
  u16*   he    = (u16*)kf;                       // 16 MB compact (spans kf+vf, after flash)
  float* h     = (float*)(ws8 + 83886080);       // 32 MB -> WguT_all after h dead
  u16*   WguT_all = (u16*)(ws8 + 83886080);      // bf16 [8][2048][1024] 32 MB

  // 1. xnb = rmsnorm(x, w_attn) -> f16
  rmsnorm_kernel<2><<<Tt, 256, 0, stream>>>(x, w_attn, xnb);
  // 2. transpose attention weights -> f16 [N][K]
  transpose_kernel<true><<<dim3(16, 16), 256, 0, stream>>>(Wq, WqT, 1024, 0, 0);
  transpose_kernel<true><<<dim3(4, 16), 256, 0, stream>>>(Wk, WkT, 256, 0, 0);
  transpose_kernel<true><<<dim3(4, 16), 256, 0, stream>>>(Wv, WvT, 256, 0, 0);
  transpose_kernel<true><<<dim3(16, 16), 256, 0, stream>>>(Wo, WoT, 1024, 0, 0);
  // 3. q/k/v projections (f16 MFMA, fp32 out)
  mfma_gemm<0, true><<<dim3(8, 64), 256, 0, stream>>>(xnb, WqT, q, nullptr, 1024, 1024);
  mfma_gemm<0, true><<<dim3(2, 64), 256, 0, stream>>>(xnb, WkT, kf, nullptr, 256, 1024);
  mfma_gemm<0, true><<<dim3(2, 64), 256, 0, stream>>>(xnb, WvT, vf, nullptr, 256, 1024);
  // 4. RoPE (also zeroes expert counters); emit fp32 k,v outputs
  rope_q_kernel<<<(Tt * Hh * 32) / 256, 256, 0, stream>>>(q, cosb, sinb, cnt);
  ropek_kv_kernel<<<(Tt * KVh * 32) / 256, 256, 0, stream>>>(kf, vf, cosb, sinb, outk, outv);
  // 5. causal GQA flash attention (MFMA f16) -> ob (f16)
  flash_mfma<<<Bb * Hh * (Ss / 128), 256, 0, stream>>>(q, kf, vf, ob);
  // 6. h = ob @ WoT + x (f16 MFMA, fp32 out + resid)
  mfma_gemm<1, true><<<dim3(8, 64), 256, 0, stream>>>(ob, WoT, h, x, 1024, 1024);
  // 7. y = rmsnorm(h) -> bf16; fused fp32 router -> gates + expert lists
  rmsnorm_kernel<1><<<Tt, 256, 0, stream>>>(h, w_moe, y);
  router_kernel<<<Tt, 64, 0, stream>>>(h, w_moe, Wr, gates, cnt, elist);
  // 8. out = h (h dead afterwards -> region becomes WguT_all)
  hipMemcpyAsync(out, h, (size_t)Tt * Dd * sizeof(float), hipMemcpyDeviceToDevice, stream);
  // 9. batched all-expert Wg/Wu transposes -> bf16 [e][2048][1024]
  transpose_kernel<false><<<dim3(16, 16, 8), 256, 0, stream>>>(
      Wg, WguT_all, 1024, (size_t)Dd * Ff, (size_t)2048 * 1024);
  transpose_kernel<false><<<dim3(16, 16, 8), 256, 0, stream>>>(
      Wu, WguT_all + (size_t)1024 * 1024, 1024, (size_t)Dd * Ff, (size_t)2048 * 1024);
  // 10. routed MoE: only tokens whose top-2 includes e (fixed worst-case grids, early-exit)
  for (int e = 0; e < Ee; ++e) {
    transpose_kernel<false><<<dim3(16, 16), 256, 0, stream>>>(Wd + (size_t)e * Ff * Dd, WdT, 1024, 0, 0);
    moe_gemm_up<<<dim3(16, 64), 256, 0, stream>>>(y, WguT_all + (size_t)e * 2048 * 1024, gu,
                                                  elist + (size_t)e * Tt, cnt + e, 2048, 1024);
    silu_mul_kernel<<<Tt, 256, 0, stream>>>(gu, he, cnt + e);
    moe_gemm_down<<<dim3(8, 128), 256, 0, stream>>>(he, WdT, out, gates, e,
                                                    elist + (size_t)e * Tt, cnt + e, 1024, 1024);
  }
}

// Round 4
// 1149.917 us; speedup vs baseline: 2.7339x; 1.1596x over previous
//
#include <hip/hip_runtime.h>
#include <stdint.h>

// ---- problem constants ----
constexpr int Bb = 4, Ss = 2048, Dd = 1024;
constexpr int Hh = 16, KVh = 4, HDd = 64;
constexpr int Ee = 8, Ff = 1024;
constexpr int Tt = Bb * Ss;           // 8192 tokens
constexpr float EPSf = 1e-6f;

typedef unsigned short u16;
typedef __attribute__((ext_vector_type(8))) short short8;       // 8 bf16/f16 (4 VGPRs)
typedef __attribute__((ext_vector_type(4))) float f32x4;        // 4 fp32 acc
typedef __attribute__((ext_vector_type(8))) _Float16 h16x8;     // 8 f16 (4 VGPRs)
typedef __attribute__((ext_vector_type(4))) _Float16 h16x4;     // 4 f16 (8B)

__device__ __forceinline__ float bf2f(u16 u) {
  union { unsigned int i; float f; } x; x.i = ((unsigned int)u) << 16; return x.f;
}
__device__ __forceinline__ u16 f2bf(float f) {
  union { float f; unsigned int i; } x; x.f = f;
  unsigned int r = x.i + 0x7fffu + ((x.i >> 16) & 1u);
  return (u16)(r >> 16);
}
__device__ __forceinline__ u16 f2h(float f) {
  union { _Float16 h; u16 u; } x; x.h = (_Float16)f; return x.u;
}
__device__ __forceinline__ h16x8 as_h(short8 v) {
  union { short8 s; h16x8 h; } u; u.s = v; return u.h;
}

// ---------------- fp32 [1024][N] -> 16-bit [N][1024] transpose-convert ----------------
template <bool F16H>
__global__ __launch_bounds__(256) void transpose_kernel(const float* __restrict__ W,
                                                        u16* __restrict__ WT, int N,
                                                        size_t wes, size_t tes) {
  W += (size_t)blockIdx.z * wes;
  WT += (size_t)blockIdx.z * tes;
  __shared__ float tile[64][65];
  int n0 = blockIdx.x * 64, k0 = blockIdx.y * 64;
  int tid = threadIdx.x, r = tid >> 6, c = tid & 63;
#pragma unroll
  for (int p = 0; p < 16; ++p)
    tile[p * 4 + r][c] = W[(size_t)(k0 + p * 4 + r) * N + n0 + c];
  __syncthreads();
#pragma unroll
  for (int p = 0; p < 16; ++p) {
    float v = tile[c][p * 4 + r];
    WT[(size_t)(n0 + p * 4 + r) * 1024 + k0 + c] = F16H ? f2h(v) : f2bf(v);
  }
}

// ---------------- RMSNorm: fp32 in -> FMT out (0=f32, 1=bf16, 2=f16) ----------------
template <int FMT>
__global__ __launch_bounds__(256) void rmsnorm_kernel(const float* __restrict__ x,
                                                      const float* __restrict__ w,
                                                      void* __restrict__ outp) {
  int t = blockIdx.x, tid = threadIdx.x;
  __shared__ float red[4];
  const float* xr = x + (size_t)t * Dd;
  float v[4]; float ss = 0.f;
#pragma unroll
  for (int i = 0; i < 4; ++i) { v[i] = xr[tid + 256 * i]; ss += v[i] * v[i]; }
#pragma unroll
  for (int off = 32; off; off >>= 1) ss += __shfl_down(ss, off, 64);
  if ((tid & 63) == 0) red[tid >> 6] = ss;
  __syncthreads();
  float tot = red[0] + red[1] + red[2] + red[3];
  float sc = rsqrtf(tot * (1.f / Dd) + EPSf);
#pragma unroll
  for (int i = 0; i < 4; ++i) {
    size_t idx = (size_t)t * Dd + tid + 256 * i;
    float val = v[i] * sc * w[tid + 256 * i];
    if constexpr (FMT == 0) ((float*)outp)[idx] = val;
    else if constexpr (FMT == 1) ((u16*)outp)[idx] = f2bf(val);
    else ((u16*)outp)[idx] = f2h(val);
  }
}

// ---------------- MFMA 16-bit GEMM (attention path): C[M,N] = A[M,K] @ BT[N,K] ----------------
// MODE 0: Cf = C     MODE 1: Cf = C + resid
template <int MODE, bool F16H>
__global__ __launch_bounds__(256) void mfma_gemm(const u16* __restrict__ A,
                                                 const u16* __restrict__ BT,
                                                 float* __restrict__ Cf,
                                                 const float* __restrict__ resid,
                                                 int N, int K) {
  constexpr int LS = 40;                 // u16 row stride (32 + 8 pad)
  __shared__ u16 As[128 * LS];
  __shared__ u16 Bs[128 * LS];
  int tid = threadIdx.x;
  int m0 = blockIdx.y * 128, n0 = blockIdx.x * 128;
  int lane = tid & 63, w = tid >> 6;
  int wm = (w & 1) * 64, wn = (w >> 1) * 64;
  f32x4 acc[4][4];
#pragma unroll
  for (int i = 0; i < 4; ++i)
#pragma unroll
    for (int j = 0; j < 4; ++j) acc[i][j] = (f32x4){0.f, 0.f, 0.f, 0.f};

  int row = tid >> 2, col8 = (tid & 3) * 8;
  int row1 = row + 64;
  const u16* gA0 = A + (size_t)(m0 + row) * K + col8;
  const u16* gA1 = A + (size_t)(m0 + row1) * K + col8;
  const u16* gB0 = BT + (size_t)(n0 + row) * K + col8;
  const u16* gB1 = BT + (size_t)(n0 + row1) * K + col8;
  int lo0 = row * LS + col8, lo1 = row1 * LS + col8;
  int afo[4], bfo[4];
#pragma unroll
  for (int i = 0; i < 4; ++i) {
    afo[i] = (wm + i * 16 + (lane & 15)) * LS + (lane >> 4) * 8;
    bfo[i] = (wn + i * 16 + (lane & 15)) * LS + (lane >> 4) * 8;
  }

  for (int kt = 0; kt < K; kt += 32) {
    short8 va0 = *(const short8*)(gA0 + kt);
    short8 va1 = *(const short8*)(gA1 + kt);
    short8 vb0 = *(const short8*)(gB0 + kt);
    short8 vb1 = *(const short8*)(gB1 + kt);
    __syncthreads();
    *(short8*)&As[lo0] = va0;
    *(short8*)&As[lo1] = va1;
    *(short8*)&Bs[lo0] = vb0;
    *(short8*)&Bs[lo1] = vb1;
    __syncthreads();
    short8 af[4], bfr[4];
#pragma unroll
    for (int i = 0; i < 4; ++i) af[i] = *(const short8*)&As[afo[i]];
#pragma unroll
    for (int j = 0; j < 4; ++j) bfr[j] = *(const short8*)&Bs[bfo[j]];
#pragma unroll
    for (int i = 0; i < 4; ++i)
#pragma unroll
      for (int j = 0; j < 4; ++j) {
        if constexpr (F16H)
          acc[i][j] = __builtin_amdgcn_mfma_f32_16x16x32_f16(as_h(af[i]), as_h(bfr[j]),
                                                             acc[i][j], 0, 0, 0);
        else
          acc[i][j] = __builtin_amdgcn_mfma_f32_16x16x32_bf16(af[i], bfr[j],
                                                              acc[i][j], 0, 0, 0);
      }
  }

  int r0 = (lane >> 4) * 4, cc = lane & 15;   // C/D: row=(lane>>4)*4+reg, col=lane&15
#pragma unroll
  for (int i = 0; i < 4; ++i) {
#pragma unroll
    for (int r = 0; r < 4; ++r) {
      int m = m0 + wm + i * 16 + r0 + r;
#pragma unroll
      for (int j = 0; j < 4; ++j) {
        int n = n0 + wn + j * 16 + cc;
        size_t off = (size_t)m * N + n;
        float v = acc[i][j][r];
        if constexpr (MODE == 0) Cf[off] = v;
        else Cf[off] = v + resid[off];
      }
    }
  }
}

// ---------------- Routed MoE up-GEMM: gu[m] = y[elist[m]] @ WguT  (bf16, 128x128) ----------------
__global__ __launch_bounds__(256) void moe_gemm_up(const u16* __restrict__ A,
                                                   const u16* __restrict__ BT,
                                                   u16* __restrict__ Cb,
                                                   const int* __restrict__ elist_e,
                                                   const int* __restrict__ cnt_e,
                                                   int N, int K) {
  int count = *cnt_e;
  int m0 = blockIdx.y * 128;
  if (m0 >= count) return;                 // uniform early-exit (before any barrier)
  constexpr int LS = 40;
  __shared__ u16 As[128 * LS];
  __shared__ u16 Bs[128 * LS];
  int tid = threadIdx.x;
  int n0 = blockIdx.x * 128;
  int lane = tid & 63, w = tid >> 6;
  int wm = (w & 1) * 64, wn = (w >> 1) * 64;
  f32x4 acc[4][4];
#pragma unroll
  for (int i = 0; i < 4; ++i)
#pragma unroll
    for (int j = 0; j < 4; ++j) acc[i][j] = (f32x4){0.f, 0.f, 0.f, 0.f};

  int row = tid >> 2, col8 = (tid & 3) * 8;
  int mr0 = m0 + row, mr1 = mr0 + 64;
  int t0 = (mr0 < count) ? elist_e[mr0] : 0;   // padded rows compute garbage, never consumed
  int t1 = (mr1 < count) ? elist_e[mr1] : 0;
  const u16* gA0 = A + (size_t)t0 * K + col8;
  const u16* gA1 = A + (size_t)t1 * K + col8;
  const u16* gB0 = BT + (size_t)(n0 + row) * K + col8;
  const u16* gB1 = BT + (size_t)(n0 + row + 64) * K + col8;
  int lo0 = row * LS + col8, lo1 = (row + 64) * LS + col8;
  int afo[4], bfo[4];
#pragma unroll
  for (int i = 0; i < 4; ++i) {
    afo[i] = (wm + i * 16 + (lane & 15)) * LS + (lane >> 4) * 8;
    bfo[i] = (wn + i * 16 + (lane & 15)) * LS + (lane >> 4) * 8;
  }

  for (int kt = 0; kt < K; kt += 32) {
    short8 va0 = *(const short8*)(gA0 + kt);
    short8 va1 = *(const short8*)(gA1 + kt);
    short8 vb0 = *(const short8*)(gB0 + kt);
    short8 vb1 = *(const short8*)(gB1 + kt);
    __syncthreads();
    *(short8*)&As[lo0] = va0;
    *(short8*)&As[lo1] = va1;
    *(short8*)&Bs[lo0] = vb0;
    *(short8*)&Bs[lo1] = vb1;
    __syncthreads();
    short8 af[4], bfr[4];
#pragma unroll
    for (int i = 0; i < 4; ++i) af[i] = *(const short8*)&As[afo[i]];
#pragma unroll
    for (int j = 0; j < 4; ++j) bfr[j] = *(const short8*)&Bs[bfo[j]];
#pragma unroll
    for (int i = 0; i < 4; ++i)
#pragma unroll
      for (int j = 0; j < 4; ++j)
        acc[i][j] = __builtin_amdgcn_mfma_f32_16x16x32_bf16(af[i], bfr[j], acc[i][j], 0, 0, 0);
  }

  int r0 = (lane >> 4) * 4, cc = lane & 15;
#pragma unroll
  for (int i = 0; i < 4; ++i)
#pragma unroll
    for (int r = 0; r < 4; ++r) {
      int m = m0 + wm + i * 16 + r0 + r;
      u16* crow = Cb + (size_t)m * N;
#pragma unroll
      for (int j = 0; j < 4; ++j) crow[n0 + wn + j * 16 + cc] = f2bf(acc[i][j][r]);
    }
}

// ---------------- Routed MoE down-GEMM: out[elist[m]] += gate * (he[m] @ WdT)  (64x128) ----------------
__global__ __launch_bounds__(256) void moe_gemm_down(const u16* __restrict__ A,
                                                     const u16* __restrict__ BT,
                                                     float* __restrict__ Cf,
                                                     const float* __restrict__ gates, int e,
                                                     const int* __restrict__ elist_e,
                                                     const int* __restrict__ cnt_e,
                                                     int N, int K) {
  int count = *cnt_e;
  int m0 = blockIdx.y * 64;
  if (m0 >= count) return;
  constexpr int LS = 40;
  __shared__ u16 As[64 * LS];
  __shared__ u16 Bs[128 * LS];
  int tid = threadIdx.x;
  int n0 = blockIdx.x * 128;
  int lane = tid & 63, w = tid >> 6;
  int wm = (w & 1) * 32, wn = (w >> 1) * 64;
  int c = lane & 15, g = lane >> 4;
  f32x4 acc[2][4];
#pragma unroll
  for (int i = 0; i < 2; ++i)
#pragma unroll
    for (int j = 0; j < 4; ++j) acc[i][j] = (f32x4){0.f, 0.f, 0.f, 0.f};

  int row = tid >> 2, col8 = (tid & 3) * 8;
  const u16* gA0 = A + (size_t)(m0 + row) * K + col8;
  const u16* gB0 = BT + (size_t)(n0 + row) * K + col8;
  const u16* gB1 = BT + (size_t)(n0 + row + 64) * K + col8;
  int loA = row * LS + col8;
  int loB0 = row * LS + col8, loB1 = (row + 64) * LS + col8;
  int afo[2], bfo[4];
#pragma unroll
  for (int i = 0; i < 2; ++i) afo[i] = (wm + i * 16 + c) * LS + g * 8;
#pragma unroll
  for (int j = 0; j < 4; ++j) bfo[j] = (wn + j * 16 + c) * LS + g * 8;

  for (int kt = 0; kt < K; kt += 32) {
    short8 va = *(const short8*)(gA0 + kt);
    short8 vb0 = *(const short8*)(gB0 + kt);
    short8 vb1 = *(const short8*)(gB1 + kt);
    __syncthreads();
    *(short8*)&As[loA] = va;
    *(short8*)&Bs[loB0] = vb0;
    *(short8*)&Bs[loB1] = vb1;
    __syncthreads();
    short8 af[2], bfr[4];
#pragma unroll
    for (int i = 0; i < 2; ++i) af[i] = *(const short8*)&As[afo[i]];
#pragma unroll
    for (int j = 0; j < 4; ++j) bfr[j] = *(const short8*)&Bs[bfo[j]];
#pragma unroll
    for (int i = 0; i < 2; ++i)
#pragma unroll
      for (int j = 0; j < 4; ++j)
        acc[i][j] = __builtin_amdgcn_mfma_f32_16x16x32_bf16(af[i], bfr[j], acc[i][j], 0, 0, 0);
  }

  int r0 = g * 4;
#pragma unroll
  for (int i = 0; i < 2; ++i)
#pragma unroll
    for (int r = 0; r < 4; ++r) {
      int m = m0 + wm + i * 16 + r0 + r;
      if (m < count) {
        int tok = elist_e[m];
        float gt = gates[(size_t)tok * Ee + e];
        float* orow = Cf + (size_t)tok * N;
#pragma unroll
        for (int j = 0; j < 4; ++j) {
          int n = n0 + wn + j * 16 + c;
          orow[n] += gt * acc[i][j][r];
        }
      }
    }
}

// ---------------- RoPE on k (in place) + emit fp32 k,v outputs; zero expert counters ----------------
__global__ __launch_bounds__(256) void ropek_kv_kernel(float* __restrict__ kf,
                                                       const float* __restrict__ vf,
                                                       const float* __restrict__ cosb,
                                                       const float* __restrict__ sinb,
                                                       float* __restrict__ outk,
                                                       float* __restrict__ outv,
                                                       int* __restrict__ cnt) {
  if (blockIdx.x == 0 && threadIdx.x < Ee) cnt[threadIdx.x] = 0;
  int idx = blockIdx.x * 256 + threadIdx.x;  // Tt*KV*32
  int d = idx & 31;
  int kv = (idx >> 5) & (KVh - 1);
  int t = idx >> 7;
  int s = t & (Ss - 1);
  float c = cosb[s * HDd + d], sn = sinb[s * HDd + d];
  size_t base = (size_t)t * (KVh * HDd) + kv * HDd;
  float a = kf[base + d], b = kf[base + d + 32];
  float r1 = a * c - b * sn, r2 = b * c + a * sn;
  kf[base + d] = r1; kf[base + d + 32] = r2;
  outk[base + d] = r1; outk[base + d + 32] = r2;
  outv[base + d] = vf[base + d]; outv[base + d + 32] = vf[base + d + 32];
}

// ---------------- K/V f16 prep: kh = f16(kf) passthrough; vt[b][kv][d][Ss] = f16(vf^T) ----------------
__global__ __launch_bounds__(256) void kv16_prep(const float* __restrict__ kf,
                                                 const float* __restrict__ vf,
                                                 _Float16* __restrict__ kh,
                                                 _Float16* __restrict__ vt) {
  __shared__ float tile[64][65];
  int st = blockIdx.x;          // s-tile of 64
  int bk = blockIdx.y;          // b*KVh + kv
  int t = threadIdx.x;
  int r = t >> 2, c16 = (t & 3) * 16;
  size_t rowbase = ((size_t)(bk >> 2) * Ss + st * 64 + r) * (KVh * HDd) + (bk & 3) * HDd;
  const float* kfr = kf + rowbase;
  const float* vfr = vf + rowbase;
  _Float16* khr = kh + rowbase;
#pragma unroll
  for (int u = 0; u < 4; ++u) {
    float4 k4 = *(const float4*)(kfr + c16 + u * 4);
    h16x4 hk;
    hk[0] = (_Float16)k4.x; hk[1] = (_Float16)k4.y;
    hk[2] = (_Float16)k4.z; hk[3] = (_Float16)k4.w;
    *(h16x4*)(khr + c16 + u * 4) = hk;
    float4 v4 = *(const float4*)(vfr + c16 + u * 4);
    tile[r][c16 + u * 4 + 0] = v4.x; tile[r][c16 + u * 4 + 1] = v4.y;
    tile[r][c16 + u * 4 + 2] = v4.z; tile[r][c16 + u * 4 + 3] = v4.w;
  }
  __syncthreads();
  _Float16* vtr = vt + ((size_t)bk * 64 + r) * Ss + st * 64 + c16;
#pragma unroll
  for (int u = 0; u < 2; ++u) {
    h16x8 hv;
#pragma unroll
    for (int j = 0; j < 8; ++j) hv[j] = (_Float16)tile[c16 + u * 8 + j][r];
    *(h16x8*)(vtr + u * 8) = hv;
  }
}

// ---------------- MFMA f16 flash attention, causal-balanced q-tile pairs ----------------
// Grid = B*H*8. Block p processes q-tiles (15-p) then (p): 17 k-tile-units each, uniform.
// 4 waves x 32 q-rows. K staged from pre-converted f16 kh; V from pre-transposed f16 vt.
// RoPE applied to Q in-register at fragment load (lane holds both rotate halves).
__global__ __launch_bounds__(256) void flash_mfma(const float* __restrict__ q,
                                                  const _Float16* __restrict__ kh,
                                                  const _Float16* __restrict__ vt,
                                                  const float* __restrict__ cosb,
                                                  const float* __restrict__ sinb,
                                                  u16* __restrict__ ob) {
  constexpr int LS = 72;  // halves per row: 144B, 16B aligned, padded vs 128B
  __shared__ __align__(16) _Float16 Kt[64 * LS];
  __shared__ __align__(16) _Float16 Vt[64 * LS];       // Vt[d][key]
  __shared__ __align__(16) _Float16 Pl[4][32 * LS];    // per-wave P[q][key]
  int tid = threadIdx.x;
  int pr = blockIdx.x & 7;
  int bh = blockIdx.x >> 3;
  int b = bh >> 4, hh = bh & 15;
  int w = tid >> 6, lane = tid & 63;
  int c = lane & 15, g = lane >> 4;
  int kvh = hh >> 2;                    // H/KV = 4
  const _Float16* Kb16 = kh + (size_t)b * Ss * (KVh * HDd) + kvh * HDd;
  const _Float16* Vb16 = vt + (size_t)(b * KVh + kvh) * HDd * Ss;
  int sr = tid >> 2, sc = (tid & 3) * 16;   // stager: row sr, 16 halves at sc

  for (int pass = 0; pass < 2; ++pass) {
    int qt = pass ? pr : 15 - pr;       // heavy tile first
    int qrow0 = qt * 128 + w * 32;

    // Q fragments (A operand): fused RoPE + scale 1/sqrt(64), fp32 -> f16
    h16x8 qa[2][2];
#pragma unroll
    for (int i = 0; i < 2; ++i) {
      int srow = qrow0 + i * 16 + c;
      const float* qp = q + ((size_t)(b * Ss) + srow) * (Hh * HDd) + hh * HDd + g * 8;
      const float* cb = cosb + (size_t)srow * HDd + g * 8;   // dims g*8..g*8+7 (<32)
      const float* sb = sinb + (size_t)srow * HDd + g * 8;
      float f0[8], f1[8], cc8[8], ss8[8];
      *(float4*)&f0[0] = *(const float4*)qp;       *(float4*)&f0[4] = *(const float4*)(qp + 4);
      *(float4*)&f1[0] = *(const float4*)(qp + 32); *(float4*)&f1[4] = *(const float4*)(qp + 36);
      *(float4*)&cc8[0] = *(const float4*)cb;      *(float4*)&cc8[4] = *(const float4*)(cb + 4);
      *(float4*)&ss8[0] = *(const float4*)sb;      *(float4*)&ss8[4] = *(const float4*)(sb + 4);
#pragma unroll
      for (int j = 0; j < 8; ++j) {
        qa[i][0][j] = (_Float16)((f0[j] * cc8[j] - f1[j] * ss8[j]) * 0.125f);
        qa[i][1][j] = (_Float16)((f1[j] * cc8[j] + f0[j] * ss8[j]) * 0.125f);
      }
    }

    f32x4 occ[2][4];
#pragma unroll
    for (int i = 0; i < 2; ++i)
#pragma unroll
      for (int dt = 0; dt < 4; ++dt) occ[i][dt] = (f32x4){0.f, 0.f, 0.f, 0.f};
    float mrow[2][4], lrow[2][4];
#pragma unroll
    for (int i = 0; i < 2; ++i)
#pragma unroll
      for (int r = 0; r < 4; ++r) { mrow[i][r] = -1e30f; lrow[i][r] = 0.f; }

    int kmax = qt * 128 + 128;
    for (int j0 = 0; j0 < kmax; j0 += 64) {
      __syncthreads();
      // ---- stage K [key][d] and Vt [d][key]: pure vectorized f16 copies ----
      const _Float16* ksrc = Kb16 + (size_t)(j0 + sr) * (KVh * HDd) + sc;
      *(h16x8*)&Kt[sr * LS + sc]     = *(const h16x8*)ksrc;
      *(h16x8*)&Kt[sr * LS + sc + 8] = *(const h16x8*)(ksrc + 8);
      const _Float16* vsrc = Vb16 + (size_t)sr * Ss + j0 + sc;
      *(h16x8*)&Vt[sr * LS + sc]     = *(const h16x8*)vsrc;
      *(h16x8*)&Vt[sr * LS + sc + 8] = *(const h16x8*)(vsrc + 8);
      __syncthreads();
      // ---- S = Q K^T : per wave 32 q x 64 keys ----
      f32x4 sacc[2][4];
#pragma unroll
      for (int i = 0; i < 2; ++i)
#pragma unroll
        for (int jt = 0; jt < 4; ++jt) sacc[i][jt] = (f32x4){0.f, 0.f, 0.f, 0.f};
#pragma unroll
      for (int kk = 0; kk < 2; ++kk) {
#pragma unroll
        for (int jt = 0; jt < 4; ++jt) {
          h16x8 bf = *(const h16x8*)&Kt[(jt * 16 + c) * LS + kk * 32 + g * 8];
          sacc[0][jt] = __builtin_amdgcn_mfma_f32_16x16x32_f16(qa[0][kk], bf, sacc[0][jt], 0, 0, 0);
          sacc[1][jt] = __builtin_amdgcn_mfma_f32_16x16x32_f16(qa[1][kk], bf, sacc[1][jt], 0, 0, 0);
        }
      }
      // ---- online softmax (fp32) + emit P (f16) to per-wave LDS ----
#pragma unroll
      for (int i = 0; i < 2; ++i) {
#pragma unroll
        for (int r = 0; r < 4; ++r) {
          int iq = qrow0 + i * 16 + g * 4 + r;
          float sv[4];
#pragma unroll
          for (int jt = 0; jt < 4; ++jt) {
            int jk = j0 + jt * 16 + c;
            sv[jt] = (jk <= iq) ? sacc[i][jt][r] : -1e30f;
          }
          float rm = fmaxf(fmaxf(sv[0], sv[1]), fmaxf(sv[2], sv[3]));
#pragma unroll
          for (int off = 1; off < 16; off <<= 1) rm = fmaxf(rm, __shfl_xor(rm, off, 64));
          float mn = fmaxf(mrow[i][r], rm);
          float alpha = __expf(mrow[i][r] - mn);
          mrow[i][r] = mn;
          float ps = 0.f;
          _Float16 ph[4];
#pragma unroll
          for (int jt = 0; jt < 4; ++jt) {
            float p = __expf(sv[jt] - mn);
            ps += p;
            ph[jt] = (_Float16)p;
          }
          lrow[i][r] = lrow[i][r] * alpha + ps;   // per-lane partial sum
#pragma unroll
          for (int dt = 0; dt < 4; ++dt) occ[i][dt][r] *= alpha;
#pragma unroll
          for (int jt = 0; jt < 4; ++jt)
            Pl[w][(i * 16 + g * 4 + r) * LS + jt * 16 + c] = ph[jt];
        }
      }
      __syncthreads();  // P write -> P frag read visibility
      // ---- O += P V ----
#pragma unroll
      for (int kkey = 0; kkey < 2; ++kkey) {
        h16x8 pa0 = *(const h16x8*)&Pl[w][(0 * 16 + c) * LS + kkey * 32 + g * 8];
        h16x8 pa1 = *(const h16x8*)&Pl[w][(1 * 16 + c) * LS + kkey * 32 + g * 8];
#pragma unroll
        for (int dt = 0; dt < 4; ++dt) {
          h16x8 bv = *(const h16x8*)&Vt[(dt * 16 + c) * LS + kkey * 32 + g * 8];
          occ[0][dt] = __builtin_amdgcn_mfma_f32_16x16x32_f16(pa0, bv, occ[0][dt], 0, 0, 0);
          occ[1][dt] = __builtin_amdgcn_mfma_f32_16x16x32_f16(pa1, bv, occ[1][dt], 0, 0, 0);
        }
      }
    }
    // ---- epilogue: finish l reduction, store O f16 ----
#pragma unroll
    for (int i = 0; i < 2; ++i) {
#pragma unroll
      for (int r = 0; r < 4; ++r) {
        float ls = lrow[i][r];
#pragma unroll
        for (int off = 1; off < 16; off <<= 1) ls += __shfl_xor(ls, off, 64);
        float inv = 1.f / ls;
        u16* op = ob + ((size_t)(b * Ss) + qrow0 + i * 16 + g * 4 + r) * (Hh * HDd) +
                  hh * HDd + c;
#pragma unroll
        for (int dt = 0; dt < 4; ++dt) op[dt * 16] = f2h(occ[i][dt][r] * inv);
      }
    }
  }
}

// ---------------- Fused router: rmsnorm(h) -> logits -> top-2 gates + expert lists ----------------
__global__ __launch_bounds__(64) void router_kernel(const float* __restrict__ h,
                                                    const float* __restrict__ wm,
                                                    const float* __restrict__ rw,
                                                    float* __restrict__ gates,
                                                    int* __restrict__ cnt,
                                                    int* __restrict__ elist) {
  int t = blockIdx.x, lane = threadIdx.x;
  const float* hr = h + (size_t)t * Dd;
  float v[16]; float ss = 0.f;
#pragma unroll
  for (int j = 0; j < 16; ++j) { v[j] = hr[lane + j * 64]; ss += v[j] * v[j]; }
#pragma unroll
  for (int off = 32; off; off >>= 1) ss += __shfl_down(ss, off, 64);
  ss = __shfl(ss, 0, 64);
  float sc = rsqrtf(ss * (1.f / Dd) + EPSf);
  float acc[8] = {};
#pragma unroll
  for (int j = 0; j < 16; ++j) {
    int i = lane + j * 64;
    float yv = v[j] * sc * wm[i];
    float4 w0 = *(const float4*)(rw + (size_t)i * 8);
    float4 w1 = *(const float4*)(rw + (size_t)i * 8 + 4);
    acc[0] += yv * w0.x; acc[1] += yv * w0.y;
    acc[2] += yv * w0.z; acc[3] += yv * w0.w;
    acc[4] += yv * w1.x; acc[5] += yv * w1.y;
    acc[6] += yv * w1.z; acc[7] += yv * w1.w;
  }
#pragma unroll
  for (int off = 32; off; off >>= 1)
#pragma unroll
    for (int e = 0; e < 8; ++e) acc[e] += __shfl_down(acc[e], off, 64);
  if (lane == 0) {
    int i0 = 0; float v0 = acc[0];
#pragma unroll
    for (int e = 1; e < 8; ++e) if (acc[e] > v0) { v0 = acc[e]; i0 = e; }
    int i1 = -1; float v1 = -3.4e38f;
#pragma unroll
    for (int e = 0; e < 8; ++e) if (e != i0 && acc[e] > v1) { v1 = acc[e]; i1 = e; }
    float e1 = __expf(v1 - v0);
    float inv = 1.f / (1.f + e1);
    float* gr = gates + (size_t)t * 8;
#pragma unroll
    for (int e = 0; e < 8; ++e) gr[e] = (e == i0) ? inv : ((e == i1) ? e1 * inv : 0.f);
    int p0 = atomicAdd(&cnt[i0], 1); elist[(size_t)i0 * Tt + p0] = t;
    int p1 = atomicAdd(&cnt[i1], 1); elist[(size_t)i1 * Tt + p1] = t;
  }
}

// ---------------- silu(g)*u from fused gu [m][2048] bf16 -> he [m][1024] bf16 (routed) ----------------
__global__ __launch_bounds__(256) void silu_mul_kernel(const u16* __restrict__ gu,
                                                       u16* __restrict__ he,
                                                       const int* __restrict__ cnt_e) {
  if ((int)blockIdx.x >= *cnt_e) return;   // block <-> compact row m
  size_t idx4 = ((size_t)blockIdx.x * 256 + threadIdx.x) * 4;
  size_t m = idx4 >> 10, f = idx4 & 1023;
  const u16* gp = gu + m * 2048 + f;
  ushort4 gv = *(const ushort4*)gp;
  ushort4 uv = *(const ushort4*)(gp + 1024);
  float g[4] = {bf2f(gv.x), bf2f(gv.y), bf2f(gv.z), bf2f(gv.w)};
  float u[4] = {bf2f(uv.x), bf2f(uv.y), bf2f(uv.z), bf2f(uv.w)};
  ushort4 o;
  o.x = f2bf(g[0] / (1.f + __expf(-g[0])) * u[0]);
  o.y = f2bf(g[1] / (1.f + __expf(-g[1])) * u[1]);
  o.z = f2bf(g[2] / (1.f + __expf(-g[2])) * u[2]);
  o.w = f2bf(g[3] / (1.f + __expf(-g[3])) * u[3]);
  *(ushort4*)(he + m * 1024 + f) = o;
}

extern "C" void kernel_launch(void* const* d_in, const int* in_sizes, int n_in,
                              void* d_out, int out_size, void* d_ws, size_t ws_size,
                              hipStream_t stream) {
  const float* x      = (const float*)d_in[0];
  const float* cosb   = (const float*)d_in[1];
  const float* sinb   = (const float*)d_in[2];
  // d_in[3] = mask — causal, hard-coded in flash
  const float* w_attn = (const float*)d_in[4];
  const float* w_moe  = (const float*)d_in[5];
  const float* Wq = (const float*)d_in[6];
  const float* Wk = (const float*)d_in[7];
  const float* Wv = (const float*)d_in[8];
  const float* Wo = (const float*)d_in[9];
  const float* Wr = (const float*)d_in[10];
  const float* Wg = (const float*)d_in[11];
  const float* Wu = (const float*)d_in[12];
  const float* Wd = (const float*)d_in[13];
  float* out  = (float*)d_out;
  float* outk = out + (size_t)Tt * Dd;
  float* outv = outk + (size_t)Tt * KVh * HDd;

  // ---- workspace layout (112 MB budget) ----
  char* ws8 = (char*)d_ws;
  u16*   xnb   = (u16*)(ws8);                    // 16 MB f16 : xnb -> ob -> y
  u16*   ob    = (u16*)(ws8);
  u16*   y     = (u16*)(ws8);
  float* gates = (float*)(ws8 + 16777216);       // 256 KB
  int*   cnt   = (int*)(ws8 + 17039360);         // 32 B expert counters
  int*   elist = (int*)(ws8 + 17040384);         // 256 KB expert token lists [8][8192]
  u16*   wbuf  = (u16*)(ws8 + 17825792);         // ~5 MB shared weight region
  u16*   WqT   = wbuf;                           // f16 [1024][1024] 2 MB
  u16*   WkT   = wbuf + (size_t)1024 * 1024;     // f16 [256][1024]  0.5 MB
  u16*   WvT   = WkT + (size_t)256 * 1024;       // f16 [256][1024]  0.5 MB
  u16*   WoT   = WvT + (size_t)256 * 1024;       // f16 [1024][1024] 2 MB
  u16*   WdT   = wbuf;                           // bf16 [1024][1024] 2 MB (per-expert, loop)
  _Float16* khb = (_Float16*)(ws8 + 24117248);   // f16 K (roped) 4 MB
  _Float16* vtb = (_Float16*)(ws8 + 28311552);   // f16 V^T [b][kv][64][Ss] 4 MB
  float* q     = (float*)(ws8 + 33554432);       // 32 MB fp32 -> gu bf16 (compact)
  u16*   gu    = (u16*)q;
  float* kf    = (float*)(ws8 + 67108864);       //  8 MB
  float* vf    = (float*)(ws8 + 75497472);       //  8 MB
  u16*   he    = (u16*)kf;                       // 16 MB compact (spans kf+vf, after flash)
  float* h     = (float*)(ws8 + 83886080);       // 32 MB -> WguT_all after h dead
  u16*   WguT_all = (u16*)(ws8 + 83886080);      // bf16 [8][2048][1024] 32 MB

  // 1. xnb = rmsnorm(x, w_attn) -> f16
  rmsnorm_kernel<2><<<Tt, 256, 0, stream>>>(x, w_attn, xnb);
  // 2. transpose attention weights -> f16 [N][K]
  transpose_kernel<true><<<dim3(16, 16), 256, 0, stream>>>(Wq, WqT, 1024, 0, 0);
  transpose_kernel<true><<<dim3(4, 16), 256, 0, stream>>>(Wk, WkT, 256, 0, 0);
  transpose_kernel<true><<<dim3(4, 16), 256, 0, stream>>>(Wv, WvT, 256, 0, 0);
  transpose_kernel<true><<<dim3(16, 16), 256, 0, stream>>>(Wo, WoT, 1024, 0, 0);
  // 3. q/k/v projections (f16 MFMA, fp32 out)
  mfma_gemm<0, true><<<dim3(8, 64), 256, 0, stream>>>(xnb, WqT, q, nullptr, 1024, 1024);
  mfma_gemm<0, true><<<dim3(2, 64), 256, 0, stream>>>(xnb, WkT, kf, nullptr, 256, 1024);
  mfma_gemm<0, true><<<dim3(2, 64), 256, 0, stream>>>(xnb, WvT, vf, nullptr, 256, 1024);
  // 4. RoPE on k (emits fp32 k,v outputs; zeroes cnt); then f16 K / V^T prep
  ropek_kv_kernel<<<(Tt * KVh * 32) / 256, 256, 0, stream>>>(kf, vf, cosb, sinb, outk, outv, cnt);
  kv16_prep<<<dim3(Ss / 64, Bb * KVh), 256, 0, stream>>>(kf, vf, khb, vtb);
  // 5. causal GQA flash attention (MFMA f16, balanced q-tile pairs; RoPE-q fused) -> ob (f16)
  flash_mfma<<<Bb * Hh * 8, 256, 0, stream>>>(q, khb, vtb, cosb, sinb, ob);
  // 6. h = ob @ WoT + x (f16 MFMA, fp32 out + resid)
  mfma_gemm<1, true><<<dim3(8, 64), 256, 0, stream>>>(ob, WoT, h, x, 1024, 1024);
  // 7. y = rmsnorm(h) -> bf16; fused fp32 router -> gates + expert lists
  rmsnorm_kernel<1><<<Tt, 256, 0, stream>>>(h, w_moe, y);
  router_kernel<<<Tt, 64, 0, stream>>>(h, w_moe, Wr, gates, cnt, elist);
  // 8. out = h (h dead afterwards -> region becomes WguT_all)
  hipMemcpyAsync(out, h, (size_t)Tt * Dd * sizeof(float), hipMemcpyDeviceToDevice, stream);
  // 9. batched all-expert Wg/Wu transposes -> bf16 [e][2048][1024]
  transpose_kernel<false><<<dim3(16, 16, 8), 256, 0, stream>>>(
      Wg, WguT_all, 1024, (size_t)Dd * Ff, (size_t)2048 * 1024);
  transpose_kernel<false><<<dim3(16, 16, 8), 256, 0, stream>>>(
      Wu, WguT_all + (size_t)1024 * 1024, 1024, (size_t)Dd * Ff, (size_t)2048 * 1024);
  // 10. routed MoE: only tokens whose top-2 includes e (fixed worst-case grids, early-exit)
  for (int e = 0; e < Ee; ++e) {
    transpose_kernel<false><<<dim3(16, 16), 256, 0, stream>>>(Wd + (size_t)e * Ff * Dd, WdT, 1024, 0, 0);
    moe_gemm_up<<<dim3(16, 64), 256, 0, stream>>>(y, WguT_all + (size_t)e * 2048 * 1024, gu,
                                                  elist + (size_t)e * Tt, cnt + e, 2048, 1024);
    silu_mul_kernel<<<Tt, 256, 0, stream>>>(gu, he, cnt + e);
    moe_gemm_down<<<dim3(8, 128), 256, 0, stream>>>(he, WdT, out, gates, e,
                                                    elist + (size_t)e * Tt, cnt + e, 1024, 1024);
  }
}

// Round 6
// 940.312 us; speedup vs baseline: 3.3433x; 1.2229x over previous
//
#include <hip/hip_runtime.h>
#include <stdint.h>

// ---- problem constants ----
constexpr int Bb = 4, Ss = 2048, Dd = 1024;
constexpr int Hh = 16, KVh = 4, HDd = 64;
constexpr int Ee = 8, Ff = 1024;
constexpr int Tt = Bb * Ss;           // 8192 tokens
constexpr int QKVS = 1536;            // packed q|k|v row stride (fp32)
constexpr float EPSf = 1e-6f;

typedef unsigned short u16;
typedef __attribute__((ext_vector_type(8))) short short8;       // 8 bf16/f16 (4 VGPRs)
typedef __attribute__((ext_vector_type(4))) float f32x4;        // 4 fp32 acc
typedef __attribute__((ext_vector_type(8))) _Float16 h16x8;     // 8 f16 (4 VGPRs)
typedef __attribute__((ext_vector_type(4))) _Float16 h16x4;     // 4 f16 (8B)

__device__ __forceinline__ float bf2f(u16 u) {
  union { unsigned int i; float f; } x; x.i = ((unsigned int)u) << 16; return x.f;
}
__device__ __forceinline__ u16 f2bf(float f) {
  union { float f; unsigned int i; } x; x.f = f;
  unsigned int r = x.i + 0x7fffu + ((x.i >> 16) & 1u);
  return (u16)(r >> 16);
}
__device__ __forceinline__ u16 f2h(float f) {
  union { _Float16 h; u16 u; } x; x.h = (_Float16)f; return x.u;
}
__device__ __forceinline__ h16x8 as_h(short8 v) {
  union { short8 s; h16x8 h; } u; u.s = v; return u.h;
}

// ---------------- fp32 [1024][N] -> 16-bit [N][1024] transpose-convert ----------------
template <bool F16H>
__global__ __launch_bounds__(256) void transpose_kernel(const float* __restrict__ W,
                                                        u16* __restrict__ WT, int N,
                                                        size_t wes, size_t tes) {
  W += (size_t)blockIdx.z * wes;
  WT += (size_t)blockIdx.z * tes;
  __shared__ float tile[64][65];
  int n0 = blockIdx.x * 64, k0 = blockIdx.y * 64;
  int tid = threadIdx.x, r = tid >> 6, c = tid & 63;
#pragma unroll
  for (int p = 0; p < 16; ++p)
    tile[p * 4 + r][c] = W[(size_t)(k0 + p * 4 + r) * N + n0 + c];
  __syncthreads();
#pragma unroll
  for (int p = 0; p < 16; ++p) {
    float v = tile[c][p * 4 + r];
    WT[(size_t)(n0 + p * 4 + r) * 1024 + k0 + c] = F16H ? f2h(v) : f2bf(v);
  }
}

// ---------------- RMSNorm: fp32 in -> FMT out (0=f32, 1=bf16, 2=f16) ----------------
template <int FMT>
__global__ __launch_bounds__(256) void rmsnorm_kernel(const float* __restrict__ x,
                                                      const float* __restrict__ w,
                                                      void* __restrict__ outp) {
  int t = blockIdx.x, tid = threadIdx.x;
  __shared__ float red[4];
  const float* xr = x + (size_t)t * Dd;
  float v[4]; float ss = 0.f;
#pragma unroll
  for (int i = 0; i < 4; ++i) { v[i] = xr[tid + 256 * i]; ss += v[i] * v[i]; }
#pragma unroll
  for (int off = 32; off; off >>= 1) ss += __shfl_down(ss, off, 64);
  if ((tid & 63) == 0) red[tid >> 6] = ss;
  __syncthreads();
  float tot = red[0] + red[1] + red[2] + red[3];
  float sc = rsqrtf(tot * (1.f / Dd) + EPSf);
#pragma unroll
  for (int i = 0; i < 4; ++i) {
    size_t idx = (size_t)t * Dd + tid + 256 * i;
    float val = v[i] * sc * w[tid + 256 * i];
    if constexpr (FMT == 0) ((float*)outp)[idx] = val;
    else if constexpr (FMT == 1) ((u16*)outp)[idx] = f2bf(val);
    else ((u16*)outp)[idx] = f2h(val);
  }
}

// ---------------- MFMA 16-bit GEMM (attention path): C[M,N] = A[M,K] @ BT[N,K] ----------------
// MODE 0: Cf = C     MODE 1: Cf = C + resid     MODE 2: Cf = Cf2 = C + resid (dual write)
template <int MODE, bool F16H>
__global__ __launch_bounds__(256) void mfma_gemm(const u16* __restrict__ A,
                                                 const u16* __restrict__ BT,
                                                 float* __restrict__ Cf,
                                                 float* __restrict__ Cf2,
                                                 const float* __restrict__ resid,
                                                 int N, int K) {
  constexpr int LS = 40;                 // u16 row stride (32 + 8 pad)
  __shared__ u16 As[128 * LS];
  __shared__ u16 Bs[128 * LS];
  int tid = threadIdx.x;
  int m0 = blockIdx.y * 128, n0 = blockIdx.x * 128;
  int lane = tid & 63, w = tid >> 6;
  int wm = (w & 1) * 64, wn = (w >> 1) * 64;
  f32x4 acc[4][4];
#pragma unroll
  for (int i = 0; i < 4; ++i)
#pragma unroll
    for (int j = 0; j < 4; ++j) acc[i][j] = (f32x4){0.f, 0.f, 0.f, 0.f};

  int row = tid >> 2, col8 = (tid & 3) * 8;
  int row1 = row + 64;
  const u16* gA0 = A + (size_t)(m0 + row) * K + col8;
  const u16* gA1 = A + (size_t)(m0 + row1) * K + col8;
  const u16* gB0 = BT + (size_t)(n0 + row) * K + col8;
  const u16* gB1 = BT + (size_t)(n0 + row1) * K + col8;
  int lo0 = row * LS + col8, lo1 = row1 * LS + col8;
  int afo[4], bfo[4];
#pragma unroll
  for (int i = 0; i < 4; ++i) {
    afo[i] = (wm + i * 16 + (lane & 15)) * LS + (lane >> 4) * 8;
    bfo[i] = (wn + i * 16 + (lane & 15)) * LS + (lane >> 4) * 8;
  }

  for (int kt = 0; kt < K; kt += 32) {
    short8 va0 = *(const short8*)(gA0 + kt);
    short8 va1 = *(const short8*)(gA1 + kt);
    short8 vb0 = *(const short8*)(gB0 + kt);
    short8 vb1 = *(const short8*)(gB1 + kt);
    __syncthreads();
    *(short8*)&As[lo0] = va0;
    *(short8*)&As[lo1] = va1;
    *(short8*)&Bs[lo0] = vb0;
    *(short8*)&Bs[lo1] = vb1;
    __syncthreads();
    short8 af[4], bfr[4];
#pragma unroll
    for (int i = 0; i < 4; ++i) af[i] = *(const short8*)&As[afo[i]];
#pragma unroll
    for (int j = 0; j < 4; ++j) bfr[j] = *(const short8*)&Bs[bfo[j]];
#pragma unroll
    for (int i = 0; i < 4; ++i)
#pragma unroll
      for (int j = 0; j < 4; ++j) {
        if constexpr (F16H)
          acc[i][j] = __builtin_amdgcn_mfma_f32_16x16x32_f16(as_h(af[i]), as_h(bfr[j]),
                                                             acc[i][j], 0, 0, 0);
        else
          acc[i][j] = __builtin_amdgcn_mfma_f32_16x16x32_bf16(af[i], bfr[j],
                                                              acc[i][j], 0, 0, 0);
      }
  }

  int r0 = (lane >> 4) * 4, cc = lane & 15;   // C/D: row=(lane>>4)*4+reg, col=lane&15
#pragma unroll
  for (int i = 0; i < 4; ++i) {
#pragma unroll
    for (int r = 0; r < 4; ++r) {
      int m = m0 + wm + i * 16 + r0 + r;
#pragma unroll
      for (int j = 0; j < 4; ++j) {
        int n = n0 + wn + j * 16 + cc;
        size_t off = (size_t)m * N + n;
        float v = acc[i][j][r];
        if constexpr (MODE == 0) Cf[off] = v;
        else if constexpr (MODE == 1) Cf[off] = v + resid[off];
        else { float val = v + resid[off]; Cf[off] = val; Cf2[off] = val; }
      }
    }
  }
}

// ---------------- Routed MoE up-GEMM: gu[m] = y[elist[m]] @ WguT  (bf16, 128x128) ----------------
__global__ __launch_bounds__(256) void moe_gemm_up(const u16* __restrict__ A,
                                                   const u16* __restrict__ BT,
                                                   u16* __restrict__ Cb,
                                                   const int* __restrict__ elist_e,
                                                   const int* __restrict__ cnt_e,
                                                   int N, int K) {
  int count = *cnt_e;
  int m0 = blockIdx.y * 128;
  if (m0 >= count) return;                 // uniform early-exit (before any barrier)
  constexpr int LS = 40;
  __shared__ u16 As[128 * LS];
  __shared__ u16 Bs[128 * LS];
  int tid = threadIdx.x;
  int n0 = blockIdx.x * 128;
  int lane = tid & 63, w = tid >> 6;
  int wm = (w & 1) * 64, wn = (w >> 1) * 64;
  f32x4 acc[4][4];
#pragma unroll
  for (int i = 0; i < 4; ++i)
#pragma unroll
    for (int j = 0; j < 4; ++j) acc[i][j] = (f32x4){0.f, 0.f, 0.f, 0.f};

  int row = tid >> 2, col8 = (tid & 3) * 8;
  int mr0 = m0 + row, mr1 = mr0 + 64;
  int t0 = (mr0 < count) ? elist_e[mr0] : 0;   // padded rows compute garbage, never consumed
  int t1 = (mr1 < count) ? elist_e[mr1] : 0;
  const u16* gA0 = A + (size_t)t0 * K + col8;
  const u16* gA1 = A + (size_t)t1 * K + col8;
  const u16* gB0 = BT + (size_t)(n0 + row) * K + col8;
  const u16* gB1 = BT + (size_t)(n0 + row + 64) * K + col8;
  int lo0 = row * LS + col8, lo1 = (row + 64) * LS + col8;
  int afo[4], bfo[4];
#pragma unroll
  for (int i = 0; i < 4; ++i) {
    afo[i] = (wm + i * 16 + (lane & 15)) * LS + (lane >> 4) * 8;
    bfo[i] = (wn + i * 16 + (lane & 15)) * LS + (lane >> 4) * 8;
  }

  for (int kt = 0; kt < K; kt += 32) {
    short8 va0 = *(const short8*)(gA0 + kt);
    short8 va1 = *(const short8*)(gA1 + kt);
    short8 vb0 = *(const short8*)(gB0 + kt);
    short8 vb1 = *(const short8*)(gB1 + kt);
    __syncthreads();
    *(short8*)&As[lo0] = va0;
    *(short8*)&As[lo1] = va1;
    *(short8*)&Bs[lo0] = vb0;
    *(short8*)&Bs[lo1] = vb1;
    __syncthreads();
    short8 af[4], bfr[4];
#pragma unroll
    for (int i = 0; i < 4; ++i) af[i] = *(const short8*)&As[afo[i]];
#pragma unroll
    for (int j = 0; j < 4; ++j) bfr[j] = *(const short8*)&Bs[bfo[j]];
#pragma unroll
    for (int i = 0; i < 4; ++i)
#pragma unroll
      for (int j = 0; j < 4; ++j)
        acc[i][j] = __builtin_amdgcn_mfma_f32_16x16x32_bf16(af[i], bfr[j], acc[i][j], 0, 0, 0);
  }

  int r0 = (lane >> 4) * 4, cc = lane & 15;
#pragma unroll
  for (int i = 0; i < 4; ++i)
#pragma unroll
    for (int r = 0; r < 4; ++r) {
      int m = m0 + wm + i * 16 + r0 + r;
      u16* crow = Cb + (size_t)m * N;
#pragma unroll
      for (int j = 0; j < 4; ++j) crow[n0 + wn + j * 16 + cc] = f2bf(acc[i][j][r]);
    }
}

// ---------------- Routed MoE down-GEMM: out[elist[m]] += gate * (he[m] @ WdT)  (64x128) ----------------
__global__ __launch_bounds__(256) void moe_gemm_down(const u16* __restrict__ A,
                                                     const u16* __restrict__ BT,
                                                     float* __restrict__ Cf,
                                                     const float* __restrict__ gates, int e,
                                                     const int* __restrict__ elist_e,
                                                     const int* __restrict__ cnt_e,
                                                     int N, int K) {
  int count = *cnt_e;
  int m0 = blockIdx.y * 64;
  if (m0 >= count) return;
  constexpr int LS = 40;
  __shared__ u16 As[64 * LS];
  __shared__ u16 Bs[128 * LS];
  int tid = threadIdx.x;
  int n0 = blockIdx.x * 128;
  int lane = tid & 63, w = tid >> 6;
  int wm = (w & 1) * 32, wn = (w >> 1) * 64;
  int c = lane & 15, g = lane >> 4;
  f32x4 acc[2][4];
#pragma unroll
  for (int i = 0; i < 2; ++i)
#pragma unroll
    for (int j = 0; j < 4; ++j) acc[i][j] = (f32x4){0.f, 0.f, 0.f, 0.f};

  int row = tid >> 2, col8 = (tid & 3) * 8;
  const u16* gA0 = A + (size_t)(m0 + row) * K + col8;
  const u16* gB0 = BT + (size_t)(n0 + row) * K + col8;
  const u16* gB1 = BT + (size_t)(n0 + row + 64) * K + col8;
  int loA = row * LS + col8;
  int loB0 = row * LS + col8, loB1 = (row + 64) * LS + col8;
  int afo[2], bfo[4];
#pragma unroll
  for (int i = 0; i < 2; ++i) afo[i] = (wm + i * 16 + c) * LS + g * 8;
#pragma unroll
  for (int j = 0; j < 4; ++j) bfo[j] = (wn + j * 16 + c) * LS + g * 8;

  for (int kt = 0; kt < K; kt += 32) {
    short8 va = *(const short8*)(gA0 + kt);
    short8 vb0 = *(const short8*)(gB0 + kt);
    short8 vb1 = *(const short8*)(gB1 + kt);
    __syncthreads();
    *(short8*)&As[loA] = va;
    *(short8*)&Bs[loB0] = vb0;
    *(short8*)&Bs[loB1] = vb1;
    __syncthreads();
    short8 af[2], bfr[4];
#pragma unroll
    for (int i = 0; i < 2; ++i) af[i] = *(const short8*)&As[afo[i]];
#pragma unroll
    for (int j = 0; j < 4; ++j) bfr[j] = *(const short8*)&Bs[bfo[j]];
#pragma unroll
    for (int i = 0; i < 2; ++i)
#pragma unroll
      for (int j = 0; j < 4; ++j)
        acc[i][j] = __builtin_amdgcn_mfma_f32_16x16x32_bf16(af[i], bfr[j], acc[i][j], 0, 0, 0);
  }

  int r0 = g * 4;
#pragma unroll
  for (int i = 0; i < 2; ++i)
#pragma unroll
    for (int r = 0; r < 4; ++r) {
      int m = m0 + wm + i * 16 + r0 + r;
      if (m < count) {
        int tok = elist_e[m];
        float gt = gates[(size_t)tok * Ee + e];
        float* orow = Cf + (size_t)tok * N;
#pragma unroll
        for (int j = 0; j < 4; ++j) {
          int n = n0 + wn + j * 16 + c;
          orow[n] += gt * acc[i][j][r];
        }
      }
    }
}

// ---------------- RoPE on k from packed qkv -> outk (fp32) + kh (f16); copy v -> outv ----------------
__global__ __launch_bounds__(256) void ropek_kv_kernel(const float* __restrict__ qkv,
                                                       const float* __restrict__ cosb,
                                                       const float* __restrict__ sinb,
                                                       float* __restrict__ outk,
                                                       float* __restrict__ outv,
                                                       _Float16* __restrict__ kh) {
  int idx = blockIdx.x * 256 + threadIdx.x;  // Tt*KV*32
  int d = idx & 31;
  int kv = (idx >> 5) & (KVh - 1);
  int t = idx >> 7;
  int s = t & (Ss - 1);
  float c = cosb[s * HDd + d], sn = sinb[s * HDd + d];
  const float* src = qkv + (size_t)t * QKVS + 1024 + kv * HDd;   // k section; v at +256
  size_t dbase = (size_t)t * (KVh * HDd) + kv * HDd;
  float a = src[d], b = src[d + 32];
  float r1 = a * c - b * sn, r2 = b * c + a * sn;
  outk[dbase + d] = r1; outk[dbase + d + 32] = r2;
  kh[dbase + d] = (_Float16)r1; kh[dbase + d + 32] = (_Float16)r2;
  outv[dbase + d] = src[256 + d]; outv[dbase + d + 32] = src[256 + d + 32];
}

// ---------------- V^T prep: vt[b][kv][d][Ss] = f16(v^T) from packed qkv ----------------
__global__ __launch_bounds__(256) void vt_prep(const float* __restrict__ qkv,
                                               _Float16* __restrict__ vt) {
  __shared__ float tile[64][65];
  int st = blockIdx.x;          // s-tile of 64
  int bk = blockIdx.y;          // b*KVh + kv
  int t = threadIdx.x;
  int r = t >> 2, c16 = (t & 3) * 16;
  const float* vfr = qkv + ((size_t)(bk >> 2) * Ss + st * 64 + r) * QKVS + 1280 + (bk & 3) * HDd;
#pragma unroll
  for (int u = 0; u < 4; ++u) {
    float4 v4 = *(const float4*)(vfr + c16 + u * 4);
    tile[r][c16 + u * 4 + 0] = v4.x; tile[r][c16 + u * 4 + 1] = v4.y;
    tile[r][c16 + u * 4 + 2] = v4.z; tile[r][c16 + u * 4 + 3] = v4.w;
  }
  __syncthreads();
  _Float16* vtr = vt + ((size_t)bk * 64 + r) * Ss + st * 64 + c16;
#pragma unroll
  for (int u = 0; u < 2; ++u) {
    h16x8 hv;
#pragma unroll
    for (int j = 0; j < 8; ++j) hv[j] = (_Float16)tile[c16 + u * 8 + j][r];
    *(h16x8*)(vtr + u * 8) = hv;
  }
}

// ---------------- MFMA f16 flash attention, causal-balanced q-tile pairs ----------------
// Grid = B*H*8. Block p processes q-tiles (15-p) then (p): 17 k-tile-units each, uniform.
// Q read from packed qkv (stride QKVS) with fused RoPE; K from f16 kh; V from f16 vt.
__global__ __launch_bounds__(256) void flash_mfma(const float* __restrict__ qkv,
                                                  const _Float16* __restrict__ kh,
                                                  const _Float16* __restrict__ vt,
                                                  const float* __restrict__ cosb,
                                                  const float* __restrict__ sinb,
                                                  u16* __restrict__ ob) {
  constexpr int LS = 72;  // halves per row: 144B, 16B aligned, padded vs 128B
  __shared__ __align__(16) _Float16 Kt[64 * LS];
  __shared__ __align__(16) _Float16 Vt[64 * LS];       // Vt[d][key]
  __shared__ __align__(16) _Float16 Pl[4][32 * LS];    // per-wave P[q][key]
  int tid = threadIdx.x;
  int pr = blockIdx.x & 7;
  int bh = blockIdx.x >> 3;
  int b = bh >> 4, hh = bh & 15;
  int w = tid >> 6, lane = tid & 63;
  int c = lane & 15, g = lane >> 4;
  int kvh = hh >> 2;                    // H/KV = 4
  const _Float16* Kb16 = kh + (size_t)b * Ss * (KVh * HDd) + kvh * HDd;
  const _Float16* Vb16 = vt + (size_t)(b * KVh + kvh) * HDd * Ss;
  int sr = tid >> 2, sc = (tid & 3) * 16;   // stager: row sr, 16 halves at sc

  for (int pass = 0; pass < 2; ++pass) {
    int qt = pass ? pr : 15 - pr;       // heavy tile first
    int qrow0 = qt * 128 + w * 32;

    // Q fragments (A operand): fused RoPE + scale 1/sqrt(64), fp32 -> f16
    h16x8 qa[2][2];
#pragma unroll
    for (int i = 0; i < 2; ++i) {
      int srow = qrow0 + i * 16 + c;
      const float* qp = qkv + ((size_t)(b * Ss) + srow) * QKVS + hh * HDd + g * 8;
      const float* cb = cosb + (size_t)srow * HDd + g * 8;   // dims g*8..g*8+7 (<32)
      const float* sb = sinb + (size_t)srow * HDd + g * 8;
      float f0[8], f1[8], cc8[8], ss8[8];
      *(float4*)&f0[0] = *(const float4*)qp;       *(float4*)&f0[4] = *(const float4*)(qp + 4);
      *(float4*)&f1[0] = *(const float4*)(qp + 32); *(float4*)&f1[4] = *(const float4*)(qp + 36);
      *(float4*)&cc8[0] = *(const float4*)cb;      *(float4*)&cc8[4] = *(const float4*)(cb + 4);
      *(float4*)&ss8[0] = *(const float4*)sb;      *(float4*)&ss8[4] = *(const float4*)(sb + 4);
#pragma unroll
      for (int j = 0; j < 8; ++j) {
        qa[i][0][j] = (_Float16)((f0[j] * cc8[j] - f1[j] * ss8[j]) * 0.125f);
        qa[i][1][j] = (_Float16)((f1[j] * cc8[j] + f0[j] * ss8[j]) * 0.125f);
      }
    }

    f32x4 occ[2][4];
#pragma unroll
    for (int i = 0; i < 2; ++i)
#pragma unroll
      for (int dt = 0; dt < 4; ++dt) occ[i][dt] = (f32x4){0.f, 0.f, 0.f, 0.f};
    float mrow[2][4], lrow[2][4];
#pragma unroll
    for (int i = 0; i < 2; ++i)
#pragma unroll
      for (int r = 0; r < 4; ++r) { mrow[i][r] = -1e30f; lrow[i][r] = 0.f; }

    int kmax = qt * 128 + 128;
    for (int j0 = 0; j0 < kmax; j0 += 64) {
      __syncthreads();
      // ---- stage K [key][d] and Vt [d][key]: pure vectorized f16 copies ----
      const _Float16* ksrc = Kb16 + (size_t)(j0 + sr) * (KVh * HDd) + sc;
      *(h16x8*)&Kt[sr * LS + sc]     = *(const h16x8*)ksrc;
      *(h16x8*)&Kt[sr * LS + sc + 8] = *(const h16x8*)(ksrc + 8);
      const _Float16* vsrc = Vb16 + (size_t)sr * Ss + j0 + sc;
      *(h16x8*)&Vt[sr * LS + sc]     = *(const h16x8*)vsrc;
      *(h16x8*)&Vt[sr * LS + sc + 8] = *(const h16x8*)(vsrc + 8);
      __syncthreads();
      // ---- S = Q K^T : per wave 32 q x 64 keys ----
      f32x4 sacc[2][4];
#pragma unroll
      for (int i = 0; i < 2; ++i)
#pragma unroll
        for (int jt = 0; jt < 4; ++jt) sacc[i][jt] = (f32x4){0.f, 0.f, 0.f, 0.f};
#pragma unroll
      for (int kk = 0; kk < 2; ++kk) {
#pragma unroll
        for (int jt = 0; jt < 4; ++jt) {
          h16x8 bf = *(const h16x8*)&Kt[(jt * 16 + c) * LS + kk * 32 + g * 8];
          sacc[0][jt] = __builtin_amdgcn_mfma_f32_16x16x32_f16(qa[0][kk], bf, sacc[0][jt], 0, 0, 0);
          sacc[1][jt] = __builtin_amdgcn_mfma_f32_16x16x32_f16(qa[1][kk], bf, sacc[1][jt], 0, 0, 0);
        }
      }
      // ---- online softmax (fp32) + emit P (f16) to per-wave LDS ----
#pragma unroll
      for (int i = 0; i < 2; ++i) {
#pragma unroll
        for (int r = 0; r < 4; ++r) {
          int iq = qrow0 + i * 16 + g * 4 + r;
          float sv[4];
#pragma unroll
          for (int jt = 0; jt < 4; ++jt) {
            int jk = j0 + jt * 16 + c;
            sv[jt] = (jk <= iq) ? sacc[i][jt][r] : -1e30f;
          }
          float rm = fmaxf(fmaxf(sv[0], sv[1]), fmaxf(sv[2], sv[3]));
#pragma unroll
          for (int off = 1; off < 16; off <<= 1) rm = fmaxf(rm, __shfl_xor(rm, off, 64));
          float mn = fmaxf(mrow[i][r], rm);
          float alpha = __expf(mrow[i][r] - mn);
          mrow[i][r] = mn;
          float ps = 0.f;
          _Float16 ph[4];
#pragma unroll
          for (int jt = 0; jt < 4; ++jt) {
            float p = __expf(sv[jt] - mn);
            ps += p;
            ph[jt] = (_Float16)p;
          }
          lrow[i][r] = lrow[i][r] * alpha + ps;   // per-lane partial sum
#pragma unroll
          for (int dt = 0; dt < 4; ++dt) occ[i][dt][r] *= alpha;
#pragma unroll
          for (int jt = 0; jt < 4; ++jt)
            Pl[w][(i * 16 + g * 4 + r) * LS + jt * 16 + c] = ph[jt];
        }
      }
      __syncthreads();  // P write -> P frag read visibility
      // ---- O += P V ----
#pragma unroll
      for (int kkey = 0; kkey < 2; ++kkey) {
        h16x8 pa0 = *(const h16x8*)&Pl[w][(0 * 16 + c) * LS + kkey * 32 + g * 8];
        h16x8 pa1 = *(const h16x8*)&Pl[w][(1 * 16 + c) * LS + kkey * 32 + g * 8];
#pragma unroll
        for (int dt = 0; dt < 4; ++dt) {
          h16x8 bv = *(const h16x8*)&Vt[(dt * 16 + c) * LS + kkey * 32 + g * 8];
          occ[0][dt] = __builtin_amdgcn_mfma_f32_16x16x32_f16(pa0, bv, occ[0][dt], 0, 0, 0);
          occ[1][dt] = __builtin_amdgcn_mfma_f32_16x16x32_f16(pa1, bv, occ[1][dt], 0, 0, 0);
        }
      }
    }
    // ---- epilogue: finish l reduction, store O f16 ----
#pragma unroll
    for (int i = 0; i < 2; ++i) {
#pragma unroll
      for (int r = 0; r < 4; ++r) {
        float ls = lrow[i][r];
#pragma unroll
        for (int off = 1; off < 16; off <<= 1) ls += __shfl_xor(ls, off, 64);
        float inv = 1.f / ls;
        u16* op = ob + ((size_t)(b * Ss) + qrow0 + i * 16 + g * 4 + r) * (Hh * HDd) +
                  hh * HDd + c;
#pragma unroll
        for (int dt = 0; dt < 4; ++dt) op[dt * 16] = f2h(occ[i][dt][r] * inv);
      }
    }
  }
}

// ---------------- Fused router: rmsnorm(h) -> logits -> top-2 gates + packed top2 (NO atomics) ----------------
__global__ __launch_bounds__(64) void router_kernel(const float* __restrict__ h,
                                                    const float* __restrict__ wm,
                                                    const float* __restrict__ rw,
                                                    float* __restrict__ gates,
                                                    int* __restrict__ top2) {
  int t = blockIdx.x, lane = threadIdx.x;
  const float* hr = h + (size_t)t * Dd;
  float v[16]; float ss = 0.f;
#pragma unroll
  for (int j = 0; j < 16; ++j) { v[j] = hr[lane + j * 64]; ss += v[j] * v[j]; }
#pragma unroll
  for (int off = 32; off; off >>= 1) ss += __shfl_down(ss, off, 64);
  ss = __shfl(ss, 0, 64);
  float sc = rsqrtf(ss * (1.f / Dd) + EPSf);
  float acc[8] = {};
#pragma unroll
  for (int j = 0; j < 16; ++j) {
    int i = lane + j * 64;
    float yv = v[j] * sc * wm[i];
    float4 w0 = *(const float4*)(rw + (size_t)i * 8);
    float4 w1 = *(const float4*)(rw + (size_t)i * 8 + 4);
    acc[0] += yv * w0.x; acc[1] += yv * w0.y;
    acc[2] += yv * w0.z; acc[3] += yv * w0.w;
    acc[4] += yv * w1.x; acc[5] += yv * w1.y;
    acc[6] += yv * w1.z; acc[7] += yv * w1.w;
  }
#pragma unroll
  for (int off = 32; off; off >>= 1)
#pragma unroll
    for (int e = 0; e < 8; ++e) acc[e] += __shfl_down(acc[e], off, 64);
  if (lane == 0) {
    int i0 = 0; float v0 = acc[0];
#pragma unroll
    for (int e = 1; e < 8; ++e) if (acc[e] > v0) { v0 = acc[e]; i0 = e; }
    int i1 = -1; float v1 = -3.4e38f;
#pragma unroll
    for (int e = 0; e < 8; ++e) if (e != i0 && acc[e] > v1) { v1 = acc[e]; i1 = e; }
    float e1 = __expf(v1 - v0);
    float inv = 1.f / (1.f + e1);
    float* gr = gates + (size_t)t * 8;
#pragma unroll
    for (int e = 0; e < 8; ++e) gr[e] = (e == i0) ? inv : ((e == i1) ? e1 * inv : 0.f);
    top2[t] = i0 | (i1 << 4);
  }
}

// ---------------- Build ordered expert lists from top2 (ballot compaction, no atomics) ----------------
__global__ __launch_bounds__(64) void build_lists(const int* __restrict__ top2,
                                                  int* __restrict__ cnt,
                                                  int* __restrict__ elist) {
  int e = blockIdx.x, lane = threadIdx.x;
  int* el = elist + (size_t)e * Tt;
  int base = 0;
  for (int t0 = 0; t0 < Tt; t0 += 256) {
    int pr[4];
#pragma unroll
    for (int u = 0; u < 4; ++u) pr[u] = top2[t0 + u * 64 + lane];
#pragma unroll
    for (int u = 0; u < 4; ++u) {
      bool match = ((pr[u] & 15) == e) || (((pr[u] >> 4) & 15) == e);
      unsigned long long mask = __ballot(match);
      int prefix = __popcll(mask & ((1ull << lane) - 1ull));
      if (match) el[base + prefix] = t0 + u * 64 + lane;
      base += __popcll(mask);
    }
  }
  if (lane == 0) cnt[e] = base;
}

// ---------------- silu(g)*u from fused gu [m][2048] bf16 -> he [m][1024] bf16 (routed) ----------------
__global__ __launch_bounds__(256) void silu_mul_kernel(const u16* __restrict__ gu,
                                                       u16* __restrict__ he,
                                                       const int* __restrict__ cnt_e) {
  if ((int)blockIdx.x >= *cnt_e) return;   // block <-> compact row m
  size_t idx4 = ((size_t)blockIdx.x * 256 + threadIdx.x) * 4;
  size_t m = idx4 >> 10, f = idx4 & 1023;
  const u16* gp = gu + m * 2048 + f;
  ushort4 gv = *(const ushort4*)gp;
  ushort4 uv = *(const ushort4*)(gp + 1024);
  float g[4] = {bf2f(gv.x), bf2f(gv.y), bf2f(gv.z), bf2f(gv.w)};
  float u[4] = {bf2f(uv.x), bf2f(uv.y), bf2f(uv.z), bf2f(uv.w)};
  ushort4 o;
  o.x = f2bf(g[0] / (1.f + __expf(-g[0])) * u[0]);
  o.y = f2bf(g[1] / (1.f + __expf(-g[1])) * u[1]);
  o.z = f2bf(g[2] / (1.f + __expf(-g[2])) * u[2]);
  o.w = f2bf(g[3] / (1.f + __expf(-g[3])) * u[3]);
  *(ushort4*)(he + m * 1024 + f) = o;
}

extern "C" void kernel_launch(void* const* d_in, const int* in_sizes, int n_in,
                              void* d_out, int out_size, void* d_ws, size_t ws_size,
                              hipStream_t stream) {
  const float* x      = (const float*)d_in[0];
  const float* cosb   = (const float*)d_in[1];
  const float* sinb   = (const float*)d_in[2];
  // d_in[3] = mask — causal, hard-coded in flash
  const float* w_attn = (const float*)d_in[4];
  const float* w_moe  = (const float*)d_in[5];
  const float* Wq = (const float*)d_in[6];
  const float* Wk = (const float*)d_in[7];
  const float* Wv = (const float*)d_in[8];
  const float* Wo = (const float*)d_in[9];
  const float* Wr = (const float*)d_in[10];
  const float* Wg = (const float*)d_in[11];
  const float* Wu = (const float*)d_in[12];
  const float* Wd = (const float*)d_in[13];
  float* out  = (float*)d_out;
  float* outk = out + (size_t)Tt * Dd;
  float* outv = outk + (size_t)Tt * KVh * HDd;

  // ---- workspace layout (112 MB budget) ----
  char* ws8 = (char*)d_ws;
  u16*   xnb   = (u16*)(ws8);                    // 16 MB f16 : xnb -> ob -> y
  u16*   ob    = (u16*)(ws8);
  u16*   y     = (u16*)(ws8);
  float* gates = (float*)(ws8 + 16777216);       // 256 KB
  int*   cnt   = (int*)(ws8 + 17039360);         // 32 B expert counters
  int*   elist = (int*)(ws8 + 17040384);         // 256 KB expert token lists [8][8192]
  int*   top2  = (int*)(ws8 + 17302528);         // 32 KB packed top-2 per token
  u16*   wbuf  = (u16*)(ws8 + 17825792);         // 5 MB: WqT|WkT|WvT|WoT contiguous (f16)
  u16*   WqT   = wbuf;                           // f16 [1024][1024] 2 MB   (qkv BT base)
  u16*   WkT   = wbuf + (size_t)1024 * 1024;     // f16 [256][1024]  0.5 MB
  u16*   WvT   = WkT + (size_t)256 * 1024;       // f16 [256][1024]  0.5 MB
  u16*   WoT   = WvT + (size_t)256 * 1024;       // f16 [1024][1024] 2 MB
  u16*   WdT   = wbuf;                           // bf16 [1024][1024] 2 MB (per-expert, loop)
  _Float16* khb = (_Float16*)(ws8 + 24117248);   // f16 K (roped) [Tt][256] 4 MB
  _Float16* vtb = (_Float16*)(ws8 + 28311552);   // f16 V^T [b][kv][64][Ss] 4 MB
  float* qkv   = (float*)(ws8 + 33554432);       // fp32 [Tt][1536] 48 MB (q|k|v packed)
  u16*   gu    = (u16*)(ws8 + 33554432);         // 32 MB (qkv dead after flash)
  u16*   he    = (u16*)(ws8 + 67108864);         // 16 MB
  float* h     = (float*)(ws8 + 83886080);       // 32 MB -> WguT_all after h dead
  u16*   WguT_all = (u16*)(ws8 + 83886080);      // bf16 [8][2048][1024] 32 MB

  // 1. xnb = rmsnorm(x, w_attn) -> f16
  rmsnorm_kernel<2><<<Tt, 256, 0, stream>>>(x, w_attn, xnb);
  // 2. transpose attention weights -> f16 [N][K] (contiguous: forms [1536][1024] for QKV)
  transpose_kernel<true><<<dim3(16, 16), 256, 0, stream>>>(Wq, WqT, 1024, 0, 0);
  transpose_kernel<true><<<dim3(4, 16), 256, 0, stream>>>(Wk, WkT, 256, 0, 0);
  transpose_kernel<true><<<dim3(4, 16), 256, 0, stream>>>(Wv, WvT, 256, 0, 0);
  transpose_kernel<true><<<dim3(16, 16), 256, 0, stream>>>(Wo, WoT, 1024, 0, 0);
  // 3. fused q|k|v projection (f16 MFMA, fp32 out, N=1536)
  mfma_gemm<0, true><<<dim3(12, 64), 256, 0, stream>>>(xnb, WqT, qkv, nullptr, nullptr, QKVS, 1024);
  // 4. RoPE on k -> outk + f16 khb; copy v -> outv; then V^T f16 prep
  ropek_kv_kernel<<<(Tt * KVh * 32) / 256, 256, 0, stream>>>(qkv, cosb, sinb, outk, outv, khb);
  vt_prep<<<dim3(Ss / 64, Bb * KVh), 256, 0, stream>>>(qkv, vtb);
  // 5. causal GQA flash attention (MFMA f16, balanced q-tile pairs; RoPE-q fused) -> ob (f16)
  flash_mfma<<<Bb * Hh * 8, 256, 0, stream>>>(qkv, khb, vtb, cosb, sinb, ob);
  // 6. h = ob @ WoT + x; dual-write into out (replaces D2D memcpy)
  mfma_gemm<2, true><<<dim3(8, 64), 256, 0, stream>>>(ob, WoT, h, out, x, 1024, 1024);
  // 7. y = rmsnorm(h) -> bf16; router -> gates + top2; ordered expert lists
  rmsnorm_kernel<1><<<Tt, 256, 0, stream>>>(h, w_moe, y);
  router_kernel<<<Tt, 64, 0, stream>>>(h, w_moe, Wr, gates, top2);
  build_lists<<<Ee, 64, 0, stream>>>(top2, cnt, elist);
  // 8. batched all-expert Wg/Wu transposes -> bf16 [e][2048][1024] (h dead now)
  transpose_kernel<false><<<dim3(16, 16, 8), 256, 0, stream>>>(
      Wg, WguT_all, 1024, (size_t)Dd * Ff, (size_t)2048 * 1024);
  transpose_kernel<false><<<dim3(16, 16, 8), 256, 0, stream>>>(
      Wu, WguT_all + (size_t)1024 * 1024, 1024, (size_t)Dd * Ff, (size_t)2048 * 1024);
  // 9. routed MoE: only tokens whose top-2 includes e (fixed worst-case grids, early-exit)
  for (int e = 0; e < Ee; ++e) {
    transpose_kernel<false><<<dim3(16, 16), 256, 0, stream>>>(Wd + (size_t)e * Ff * Dd, WdT, 1024, 0, 0);
    moe_gemm_up<<<dim3(16, 64), 256, 0, stream>>>(y, WguT_all + (size_t)e * 2048 * 1024, gu,
                                                  elist + (size_t)e * Tt, cnt + e, 2048, 1024);
    silu_mul_kernel<<<Tt, 256, 0, stream>>>(gu, he, cnt + e);
    moe_gemm_down<<<dim3(8, 128), 256, 0, stream>>>(he, WdT, out, gates, e,
                                                    elist + (size_t)e * Tt, cnt + e, 1024, 1024);
  }
}

// Round 7
// 666.319 us; speedup vs baseline: 4.7181x; 1.4112x over previous
//
#include <hip/hip_runtime.h>
#include <stdint.h>

// ---- problem constants ----
constexpr int Bb = 4, Ss = 2048, Dd = 1024;
constexpr int Hh = 16, KVh = 4, HDd = 64;
constexpr int Ee = 8, Ff = 1024;
constexpr int Tt = Bb * Ss;           // 8192 tokens
constexpr int QKVS = 1536;            // packed q|k|v row stride (fp32)
constexpr float EPSf = 1e-6f;

typedef unsigned short u16;
typedef __attribute__((ext_vector_type(8))) short short8;       // 8 bf16/f16 (4 VGPRs)
typedef __attribute__((ext_vector_type(4))) float f32x4;        // 4 fp32 acc
typedef __attribute__((ext_vector_type(8))) _Float16 h16x8;     // 8 f16 (4 VGPRs)
typedef __attribute__((ext_vector_type(4))) _Float16 h16x4;     // 4 f16 (8B)

__device__ __forceinline__ float bf2f(u16 u) {
  union { unsigned int i; float f; } x; x.i = ((unsigned int)u) << 16; return x.f;
}
__device__ __forceinline__ u16 f2bf(float f) {
  union { float f; unsigned int i; } x; x.f = f;
  unsigned int r = x.i + 0x7fffu + ((x.i >> 16) & 1u);
  return (u16)(r >> 16);
}
__device__ __forceinline__ u16 f2h(float f) {
  union { _Float16 h; u16 u; } x; x.h = (_Float16)f; return x.u;
}
__device__ __forceinline__ float h2f(u16 u) {
  union { _Float16 h; u16 u; } x; x.u = u; return (float)x.h;
}
__device__ __forceinline__ h16x8 as_h(short8 v) {
  union { short8 s; h16x8 h; } u; u.s = v; return u.h;
}

// ---------------- fp32 [1024][N] -> 16-bit [N][1024] transpose-convert ----------------
template <bool F16H>
__global__ __launch_bounds__(256) void transpose_kernel(const float* __restrict__ W,
                                                        u16* __restrict__ WT, int N,
                                                        size_t wes, size_t tes) {
  W += (size_t)blockIdx.z * wes;
  WT += (size_t)blockIdx.z * tes;
  __shared__ float tile[64][65];
  int n0 = blockIdx.x * 64, k0 = blockIdx.y * 64;
  int tid = threadIdx.x, r = tid >> 6, c = tid & 63;
#pragma unroll
  for (int p = 0; p < 16; ++p)
    tile[p * 4 + r][c] = W[(size_t)(k0 + p * 4 + r) * N + n0 + c];
  __syncthreads();
#pragma unroll
  for (int p = 0; p < 16; ++p) {
    float v = tile[c][p * 4 + r];
    WT[(size_t)(n0 + p * 4 + r) * 1024 + k0 + c] = F16H ? f2h(v) : f2bf(v);
  }
}

// ---------------- RMSNorm: fp32 in -> FMT out (0=f32, 1=bf16, 2=f16) ----------------
template <int FMT>
__global__ __launch_bounds__(256) void rmsnorm_kernel(const float* __restrict__ x,
                                                      const float* __restrict__ w,
                                                      void* __restrict__ outp) {
  int t = blockIdx.x, tid = threadIdx.x;
  __shared__ float red[4];
  const float* xr = x + (size_t)t * Dd;
  float v[4]; float ss = 0.f;
#pragma unroll
  for (int i = 0; i < 4; ++i) { v[i] = xr[tid + 256 * i]; ss += v[i] * v[i]; }
#pragma unroll
  for (int off = 32; off; off >>= 1) ss += __shfl_down(ss, off, 64);
  if ((tid & 63) == 0) red[tid >> 6] = ss;
  __syncthreads();
  float tot = red[0] + red[1] + red[2] + red[3];
  float sc = rsqrtf(tot * (1.f / Dd) + EPSf);
#pragma unroll
  for (int i = 0; i < 4; ++i) {
    size_t idx = (size_t)t * Dd + tid + 256 * i;
    float val = v[i] * sc * w[tid + 256 * i];
    if constexpr (FMT == 0) ((float*)outp)[idx] = val;
    else if constexpr (FMT == 1) ((u16*)outp)[idx] = f2bf(val);
    else ((u16*)outp)[idx] = f2h(val);
  }
}

// ---------------- MFMA 16-bit GEMM (attention path): C[M,N] = A[M,K] @ BT[N,K] ----------------
// MODE 0: Cf = C     MODE 1: Cf = C + resid     MODE 2: Cf = Cf2 = C + resid (dual write)
template <int MODE, bool F16H>
__global__ __launch_bounds__(256) void mfma_gemm(const u16* __restrict__ A,
                                                 const u16* __restrict__ BT,
                                                 float* __restrict__ Cf,
                                                 float* __restrict__ Cf2,
                                                 const float* __restrict__ resid,
                                                 int N, int K) {
  constexpr int LS = 40;                 // u16 row stride (32 + 8 pad)
  __shared__ u16 As[128 * LS];
  __shared__ u16 Bs[128 * LS];
  int tid = threadIdx.x;
  int m0 = blockIdx.y * 128, n0 = blockIdx.x * 128;
  int lane = tid & 63, w = tid >> 6;
  int wm = (w & 1) * 64, wn = (w >> 1) * 64;
  f32x4 acc[4][4];
#pragma unroll
  for (int i = 0; i < 4; ++i)
#pragma unroll
    for (int j = 0; j < 4; ++j) acc[i][j] = (f32x4){0.f, 0.f, 0.f, 0.f};

  int row = tid >> 2, col8 = (tid & 3) * 8;
  int row1 = row + 64;
  const u16* gA0 = A + (size_t)(m0 + row) * K + col8;
  const u16* gA1 = A + (size_t)(m0 + row1) * K + col8;
  const u16* gB0 = BT + (size_t)(n0 + row) * K + col8;
  const u16* gB1 = BT + (size_t)(n0 + row1) * K + col8;
  int lo0 = row * LS + col8, lo1 = row1 * LS + col8;
  int afo[4], bfo[4];
#pragma unroll
  for (int i = 0; i < 4; ++i) {
    afo[i] = (wm + i * 16 + (lane & 15)) * LS + (lane >> 4) * 8;
    bfo[i] = (wn + i * 16 + (lane & 15)) * LS + (lane >> 4) * 8;
  }

  for (int kt = 0; kt < K; kt += 32) {
    short8 va0 = *(const short8*)(gA0 + kt);
    short8 va1 = *(const short8*)(gA1 + kt);
    short8 vb0 = *(const short8*)(gB0 + kt);
    short8 vb1 = *(const short8*)(gB1 + kt);
    __syncthreads();
    *(short8*)&As[lo0] = va0;
    *(short8*)&As[lo1] = va1;
    *(short8*)&Bs[lo0] = vb0;
    *(short8*)&Bs[lo1] = vb1;
    __syncthreads();
    short8 af[4], bfr[4];
#pragma unroll
    for (int i = 0; i < 4; ++i) af[i] = *(const short8*)&As[afo[i]];
#pragma unroll
    for (int j = 0; j < 4; ++j) bfr[j] = *(const short8*)&Bs[bfo[j]];
#pragma unroll
    for (int i = 0; i < 4; ++i)
#pragma unroll
      for (int j = 0; j < 4; ++j) {
        if constexpr (F16H)
          acc[i][j] = __builtin_amdgcn_mfma_f32_16x16x32_f16(as_h(af[i]), as_h(bfr[j]),
                                                             acc[i][j], 0, 0, 0);
        else
          acc[i][j] = __builtin_amdgcn_mfma_f32_16x16x32_bf16(af[i], bfr[j],
                                                              acc[i][j], 0, 0, 0);
      }
  }

  int r0 = (lane >> 4) * 4, cc = lane & 15;   // C/D: row=(lane>>4)*4+reg, col=lane&15
#pragma unroll
  for (int i = 0; i < 4; ++i) {
#pragma unroll
    for (int r = 0; r < 4; ++r) {
      int m = m0 + wm + i * 16 + r0 + r;
#pragma unroll
      for (int j = 0; j < 4; ++j) {
        int n = n0 + wn + j * 16 + cc;
        size_t off = (size_t)m * N + n;
        float v = acc[i][j][r];
        if constexpr (MODE == 0) Cf[off] = v;
        else if constexpr (MODE == 1) Cf[off] = v + resid[off];
        else { float val = v + resid[off]; Cf[off] = val; Cf2[off] = val; }
      }
    }
  }
}

// ---------------- Fused routed MoE up+gate GEMM with SiLU (bf16, 128x64, z=expert) ----------------
// he[off[e]+m][n] = silu(y[elist] @ Wg^T) * (y[elist] @ Wu^T)
__global__ __launch_bounds__(256) void moe_up_silu(const u16* __restrict__ y,
                                                   const u16* __restrict__ WguT,  // [e][2048][1024]
                                                   u16* __restrict__ he,
                                                   const int* __restrict__ elist,
                                                   const int* __restrict__ cnt,
                                                   const int* __restrict__ off) {
  constexpr int LS = 40, K = 1024;
  int e = blockIdx.z;
  int count = cnt[e];
  int m0 = blockIdx.y * 128;
  if (m0 >= count) return;                 // uniform early-exit (before any barrier)
  int base = off[e];
  const u16* Bg = WguT + (size_t)e * 2048 * 1024;
  const u16* Bu = Bg + (size_t)1024 * 1024;
  __shared__ u16 As[128 * LS];
  __shared__ u16 Bgs[64 * LS];
  __shared__ u16 Bus[64 * LS];
  int tid = threadIdx.x;
  int n0 = blockIdx.x * 64;
  int lane = tid & 63, w = tid >> 6;
  int wm = (w & 1) * 64, wn = (w >> 1) * 32;
  f32x4 ag[4][2], au[4][2];
#pragma unroll
  for (int i = 0; i < 4; ++i)
#pragma unroll
    for (int j = 0; j < 2; ++j) {
      ag[i][j] = (f32x4){0.f, 0.f, 0.f, 0.f};
      au[i][j] = (f32x4){0.f, 0.f, 0.f, 0.f};
    }

  int row = tid >> 2, col8 = (tid & 3) * 8;
  int mr0 = m0 + row, mr1 = mr0 + 64;
  int t0 = (mr0 < count) ? elist[base + mr0] : elist[base];  // padded rows: garbage, never written
  int t1 = (mr1 < count) ? elist[base + mr1] : elist[base];
  const u16* gA0 = y + (size_t)t0 * K + col8;
  const u16* gA1 = y + (size_t)t1 * K + col8;
  const u16* gBg = Bg + (size_t)(n0 + row) * K + col8;
  const u16* gBu = Bu + (size_t)(n0 + row) * K + col8;
  int lo0 = row * LS + col8, lo1 = (row + 64) * LS + col8;
  int afo[4], bfo[2];
#pragma unroll
  for (int i = 0; i < 4; ++i) afo[i] = (wm + i * 16 + (lane & 15)) * LS + (lane >> 4) * 8;
#pragma unroll
  for (int j = 0; j < 2; ++j) bfo[j] = (wn + j * 16 + (lane & 15)) * LS + (lane >> 4) * 8;

  for (int kt = 0; kt < K; kt += 32) {
    short8 va0 = *(const short8*)(gA0 + kt);
    short8 va1 = *(const short8*)(gA1 + kt);
    short8 vbg = *(const short8*)(gBg + kt);
    short8 vbu = *(const short8*)(gBu + kt);
    __syncthreads();
    *(short8*)&As[lo0] = va0;
    *(short8*)&As[lo1] = va1;
    *(short8*)&Bgs[lo0] = vbg;
    *(short8*)&Bus[lo0] = vbu;
    __syncthreads();
    short8 af[4], bgf[2], buf_[2];
#pragma unroll
    for (int i = 0; i < 4; ++i) af[i] = *(const short8*)&As[afo[i]];
#pragma unroll
    for (int j = 0; j < 2; ++j) {
      bgf[j] = *(const short8*)&Bgs[bfo[j]];
      buf_[j] = *(const short8*)&Bus[bfo[j]];
    }
#pragma unroll
    for (int i = 0; i < 4; ++i)
#pragma unroll
      for (int j = 0; j < 2; ++j) {
        ag[i][j] = __builtin_amdgcn_mfma_f32_16x16x32_bf16(af[i], bgf[j], ag[i][j], 0, 0, 0);
        au[i][j] = __builtin_amdgcn_mfma_f32_16x16x32_bf16(af[i], buf_[j], au[i][j], 0, 0, 0);
      }
  }

  int r0 = (lane >> 4) * 4, cc = lane & 15;
#pragma unroll
  for (int i = 0; i < 4; ++i)
#pragma unroll
    for (int r = 0; r < 4; ++r) {
      int m = m0 + wm + i * 16 + r0 + r;
      if (m < count) {
        u16* hrow = he + (size_t)(base + m) * 1024 + n0;
#pragma unroll
        for (int j = 0; j < 2; ++j) {
          float g = ag[i][j][r], u = au[i][j][r];
          hrow[wn + j * 16 + cc] = f2bf(g / (1.f + __expf(-g)) * u);
        }
      }
    }
}

// ---------------- Routed MoE down-GEMM: dout[off[e]+m] = f16(he[off[e]+m] @ WdT[e]) (z=expert) ----------------
__global__ __launch_bounds__(256) void moe_down(const u16* __restrict__ he,
                                                const u16* __restrict__ WdT_all,  // [e][1024][1024]
                                                u16* __restrict__ dout,
                                                const int* __restrict__ cnt,
                                                const int* __restrict__ off) {
  constexpr int LS = 40, K = 1024, N = 1024;
  int e = blockIdx.z;
  int count = cnt[e];
  int m0 = blockIdx.y * 128;
  if (m0 >= count) return;
  int base = off[e];
  const u16* BT = WdT_all + (size_t)e * 1024 * 1024;
  __shared__ u16 As[128 * LS];
  __shared__ u16 Bs[128 * LS];
  int tid = threadIdx.x;
  int n0 = blockIdx.x * 128;
  int lane = tid & 63, w = tid >> 6;
  int wm = (w & 1) * 64, wn = (w >> 1) * 64;
  f32x4 acc[4][4];
#pragma unroll
  for (int i = 0; i < 4; ++i)
#pragma unroll
    for (int j = 0; j < 4; ++j) acc[i][j] = (f32x4){0.f, 0.f, 0.f, 0.f};

  int row = tid >> 2, col8 = (tid & 3) * 8;
  int mr0 = m0 + row, mr1 = mr0 + 64;
  int ar0 = (mr0 < count) ? mr0 : count - 1;   // clamp: stay in this expert's compact rows
  int ar1 = (mr1 < count) ? mr1 : count - 1;
  const u16* gA0 = he + (size_t)(base + ar0) * K + col8;
  const u16* gA1 = he + (size_t)(base + ar1) * K + col8;
  const u16* gB0 = BT + (size_t)(n0 + row) * K + col8;
  const u16* gB1 = BT + (size_t)(n0 + row + 64) * K + col8;
  int lo0 = row * LS + col8, lo1 = (row + 64) * LS + col8;
  int afo[4], bfo[4];
#pragma unroll
  for (int i = 0; i < 4; ++i) {
    afo[i] = (wm + i * 16 + (lane & 15)) * LS + (lane >> 4) * 8;
    bfo[i] = (wn + i * 16 + (lane & 15)) * LS + (lane >> 4) * 8;
  }

  for (int kt = 0; kt < K; kt += 32) {
    short8 va0 = *(const short8*)(gA0 + kt);
    short8 va1 = *(const short8*)(gA1 + kt);
    short8 vb0 = *(const short8*)(gB0 + kt);
    short8 vb1 = *(const short8*)(gB1 + kt);
    __syncthreads();
    *(short8*)&As[lo0] = va0;
    *(short8*)&As[lo1] = va1;
    *(short8*)&Bs[lo0] = vb0;
    *(short8*)&Bs[lo1] = vb1;
    __syncthreads();
    short8 af[4], bfr[4];
#pragma unroll
    for (int i = 0; i < 4; ++i) af[i] = *(const short8*)&As[afo[i]];
#pragma unroll
    for (int j = 0; j < 4; ++j) bfr[j] = *(const short8*)&Bs[bfo[j]];
#pragma unroll
    for (int i = 0; i < 4; ++i)
#pragma unroll
      for (int j = 0; j < 4; ++j)
        acc[i][j] = __builtin_amdgcn_mfma_f32_16x16x32_bf16(af[i], bfr[j], acc[i][j], 0, 0, 0);
  }

  int r0 = (lane >> 4) * 4, cc = lane & 15;
#pragma unroll
  for (int i = 0; i < 4; ++i)
#pragma unroll
    for (int r = 0; r < 4; ++r) {
      int m = m0 + wm + i * 16 + r0 + r;
      if (m < count) {
        u16* drow = dout + (size_t)(base + m) * N;
#pragma unroll
        for (int j = 0; j < 4; ++j) drow[n0 + wn + j * 16 + cc] = f2h(acc[i][j][r]);
      }
    }
}

// ---------------- out[t] += g0*dout[pos0] + g1*dout[pos1] ----------------
__global__ __launch_bounds__(256) void gather_add(const u16* __restrict__ dout,
                                                  const int* __restrict__ top2,
                                                  const int* __restrict__ pos,
                                                  const float* __restrict__ gates,
                                                  float* __restrict__ out) {
  int t = blockIdx.x, tid = threadIdx.x;
  int p2 = top2[t];
  int e0 = p2 & 15, e1 = (p2 >> 4) & 15;
  float g0 = gates[(size_t)t * Ee + e0], g1 = gates[(size_t)t * Ee + e1];
  int r0 = pos[t * 2], r1 = pos[t * 2 + 1];
  ushort4 a = *(const ushort4*)(dout + (size_t)r0 * 1024 + tid * 4);
  ushort4 b = *(const ushort4*)(dout + (size_t)r1 * 1024 + tid * 4);
  float* o = out + (size_t)t * 1024 + tid * 4;
  float4 ov = *(float4*)o;
  ov.x += g0 * h2f(a.x) + g1 * h2f(b.x);
  ov.y += g0 * h2f(a.y) + g1 * h2f(b.y);
  ov.z += g0 * h2f(a.z) + g1 * h2f(b.z);
  ov.w += g0 * h2f(a.w) + g1 * h2f(b.w);
  *(float4*)o = ov;
}

// ---------------- RoPE on k from packed qkv -> outk (fp32) + kh (f16); copy v -> outv ----------------
__global__ __launch_bounds__(256) void ropek_kv_kernel(const float* __restrict__ qkv,
                                                       const float* __restrict__ cosb,
                                                       const float* __restrict__ sinb,
                                                       float* __restrict__ outk,
                                                       float* __restrict__ outv,
                                                       _Float16* __restrict__ kh) {
  int idx = blockIdx.x * 256 + threadIdx.x;  // Tt*KV*32
  int d = idx & 31;
  int kv = (idx >> 5) & (KVh - 1);
  int t = idx >> 7;
  int s = t & (Ss - 1);
  float c = cosb[s * HDd + d], sn = sinb[s * HDd + d];
  const float* src = qkv + (size_t)t * QKVS + 1024 + kv * HDd;   // k section; v at +256
  size_t dbase = (size_t)t * (KVh * HDd) + kv * HDd;
  float a = src[d], b = src[d + 32];
  float r1 = a * c - b * sn, r2 = b * c + a * sn;
  outk[dbase + d] = r1; outk[dbase + d + 32] = r2;
  kh[dbase + d] = (_Float16)r1; kh[dbase + d + 32] = (_Float16)r2;
  outv[dbase + d] = src[256 + d]; outv[dbase + d + 32] = src[256 + d + 32];
}

// ---------------- V^T prep: vt[b][kv][d][Ss] = f16(v^T) from packed qkv ----------------
__global__ __launch_bounds__(256) void vt_prep(const float* __restrict__ qkv,
                                               _Float16* __restrict__ vt) {
  __shared__ float tile[64][65];
  int st = blockIdx.x;          // s-tile of 64
  int bk = blockIdx.y;          // b*KVh + kv
  int t = threadIdx.x;
  int r = t >> 2, c16 = (t & 3) * 16;
  const float* vfr = qkv + ((size_t)(bk >> 2) * Ss + st * 64 + r) * QKVS + 1280 + (bk & 3) * HDd;
#pragma unroll
  for (int u = 0; u < 4; ++u) {
    float4 v4 = *(const float4*)(vfr + c16 + u * 4);
    tile[r][c16 + u * 4 + 0] = v4.x; tile[r][c16 + u * 4 + 1] = v4.y;
    tile[r][c16 + u * 4 + 2] = v4.z; tile[r][c16 + u * 4 + 3] = v4.w;
  }
  __syncthreads();
  _Float16* vtr = vt + ((size_t)bk * 64 + r) * Ss + st * 64 + c16;
#pragma unroll
  for (int u = 0; u < 2; ++u) {
    h16x8 hv;
#pragma unroll
    for (int j = 0; j < 8; ++j) hv[j] = (_Float16)tile[c16 + u * 8 + j][r];
    *(h16x8*)(vtr + u * 8) = hv;
  }
}

// ---------------- MFMA f16 flash attention, causal-balanced q-tile pairs ----------------
// Grid = B*H*8. Block p processes q-tiles (15-p) then (p): 17 k-tile-units each, uniform.
__global__ __launch_bounds__(256) void flash_mfma(const float* __restrict__ qkv,
                                                  const _Float16* __restrict__ kh,
                                                  const _Float16* __restrict__ vt,
                                                  const float* __restrict__ cosb,
                                                  const float* __restrict__ sinb,
                                                  u16* __restrict__ ob) {
  constexpr int LS = 72;  // halves per row: 144B, 16B aligned, padded vs 128B
  __shared__ __align__(16) _Float16 Kt[64 * LS];
  __shared__ __align__(16) _Float16 Vt[64 * LS];       // Vt[d][key]
  __shared__ __align__(16) _Float16 Pl[4][32 * LS];    // per-wave P[q][key]
  int tid = threadIdx.x;
  int pr = blockIdx.x & 7;
  int bh = blockIdx.x >> 3;
  int b = bh >> 4, hh = bh & 15;
  int w = tid >> 6, lane = tid & 63;
  int c = lane & 15, g = lane >> 4;
  int kvh = hh >> 2;                    // H/KV = 4
  const _Float16* Kb16 = kh + (size_t)b * Ss * (KVh * HDd) + kvh * HDd;
  const _Float16* Vb16 = vt + (size_t)(b * KVh + kvh) * HDd * Ss;
  int sr = tid >> 2, sc = (tid & 3) * 16;   // stager: row sr, 16 halves at sc

  for (int pass = 0; pass < 2; ++pass) {
    int qt = pass ? pr : 15 - pr;       // heavy tile first
    int qrow0 = qt * 128 + w * 32;

    // Q fragments (A operand): fused RoPE + scale 1/sqrt(64), fp32 -> f16
    h16x8 qa[2][2];
#pragma unroll
    for (int i = 0; i < 2; ++i) {
      int srow = qrow0 + i * 16 + c;
      const float* qp = qkv + ((size_t)(b * Ss) + srow) * QKVS + hh * HDd + g * 8;
      const float* cb = cosb + (size_t)srow * HDd + g * 8;   // dims g*8..g*8+7 (<32)
      const float* sb = sinb + (size_t)srow * HDd + g * 8;
      float f0[8], f1[8], cc8[8], ss8[8];
      *(float4*)&f0[0] = *(const float4*)qp;       *(float4*)&f0[4] = *(const float4*)(qp + 4);
      *(float4*)&f1[0] = *(const float4*)(qp + 32); *(float4*)&f1[4] = *(const float4*)(qp + 36);
      *(float4*)&cc8[0] = *(const float4*)cb;      *(float4*)&cc8[4] = *(const float4*)(cb + 4);
      *(float4*)&ss8[0] = *(const float4*)sb;      *(float4*)&ss8[4] = *(const float4*)(sb + 4);
#pragma unroll
      for (int j = 0; j < 8; ++j) {
        qa[i][0][j] = (_Float16)((f0[j] * cc8[j] - f1[j] * ss8[j]) * 0.125f);
        qa[i][1][j] = (_Float16)((f1[j] * cc8[j] + f0[j] * ss8[j]) * 0.125f);
      }
    }

    f32x4 occ[2][4];
#pragma unroll
    for (int i = 0; i < 2; ++i)
#pragma unroll
      for (int dt = 0; dt < 4; ++dt) occ[i][dt] = (f32x4){0.f, 0.f, 0.f, 0.f};
    float mrow[2][4], lrow[2][4];
#pragma unroll
    for (int i = 0; i < 2; ++i)
#pragma unroll
      for (int r = 0; r < 4; ++r) { mrow[i][r] = -1e30f; lrow[i][r] = 0.f; }

    int kmax = qt * 128 + 128;
    for (int j0 = 0; j0 < kmax; j0 += 64) {
      __syncthreads();
      // ---- stage K [key][d] and Vt [d][key]: pure vectorized f16 copies ----
      const _Float16* ksrc = Kb16 + (size_t)(j0 + sr) * (KVh * HDd) + sc;
      *(h16x8*)&Kt[sr * LS + sc]     = *(const h16x8*)ksrc;
      *(h16x8*)&Kt[sr * LS + sc + 8] = *(const h16x8*)(ksrc + 8);
      const _Float16* vsrc = Vb16 + (size_t)sr * Ss + j0 + sc;
      *(h16x8*)&Vt[sr * LS + sc]     = *(const h16x8*)vsrc;
      *(h16x8*)&Vt[sr * LS + sc + 8] = *(const h16x8*)(vsrc + 8);
      __syncthreads();
      // ---- S = Q K^T : per wave 32 q x 64 keys ----
      f32x4 sacc[2][4];
#pragma unroll
      for (int i = 0; i < 2; ++i)
#pragma unroll
        for (int jt = 0; jt < 4; ++jt) sacc[i][jt] = (f32x4){0.f, 0.f, 0.f, 0.f};
#pragma unroll
      for (int kk = 0; kk < 2; ++kk) {
#pragma unroll
        for (int jt = 0; jt < 4; ++jt) {
          h16x8 bf = *(const h16x8*)&Kt[(jt * 16 + c) * LS + kk * 32 + g * 8];
          sacc[0][jt] = __builtin_amdgcn_mfma_f32_16x16x32_f16(qa[0][kk], bf, sacc[0][jt], 0, 0, 0);
          sacc[1][jt] = __builtin_amdgcn_mfma_f32_16x16x32_f16(qa[1][kk], bf, sacc[1][jt], 0, 0, 0);
        }
      }
      // ---- online softmax (fp32) + emit P (f16) to per-wave LDS ----
#pragma unroll
      for (int i = 0; i < 2; ++i) {
#pragma unroll
        for (int r = 0; r < 4; ++r) {
          int iq = qrow0 + i * 16 + g * 4 + r;
          float sv[4];
#pragma unroll
          for (int jt = 0; jt < 4; ++jt) {
            int jk = j0 + jt * 16 + c;
            sv[jt] = (jk <= iq) ? sacc[i][jt][r] : -1e30f;
          }
          float rm = fmaxf(fmaxf(sv[0], sv[1]), fmaxf(sv[2], sv[3]));
#pragma unroll
          for (int off = 1; off < 16; off <<= 1) rm = fmaxf(rm, __shfl_xor(rm, off, 64));
          float mn = fmaxf(mrow[i][r], rm);
          float alpha = __expf(mrow[i][r] - mn);
          mrow[i][r] = mn;
          float ps = 0.f;
          _Float16 ph[4];
#pragma unroll
          for (int jt = 0; jt < 4; ++jt) {
            float p = __expf(sv[jt] - mn);
            ps += p;
            ph[jt] = (_Float16)p;
          }
          lrow[i][r] = lrow[i][r] * alpha + ps;   // per-lane partial sum
#pragma unroll
          for (int dt = 0; dt < 4; ++dt) occ[i][dt][r] *= alpha;
#pragma unroll
          for (int jt = 0; jt < 4; ++jt)
            Pl[w][(i * 16 + g * 4 + r) * LS + jt * 16 + c] = ph[jt];
        }
      }
      __syncthreads();  // P write -> P frag read visibility
      // ---- O += P V ----
#pragma unroll
      for (int kkey = 0; kkey < 2; ++kkey) {
        h16x8 pa0 = *(const h16x8*)&Pl[w][(0 * 16 + c) * LS + kkey * 32 + g * 8];
        h16x8 pa1 = *(const h16x8*)&Pl[w][(1 * 16 + c) * LS + kkey * 32 + g * 8];
#pragma unroll
        for (int dt = 0; dt < 4; ++dt) {
          h16x8 bv = *(const h16x8*)&Vt[(dt * 16 + c) * LS + kkey * 32 + g * 8];
          occ[0][dt] = __builtin_amdgcn_mfma_f32_16x16x32_f16(pa0, bv, occ[0][dt], 0, 0, 0);
          occ[1][dt] = __builtin_amdgcn_mfma_f32_16x16x32_f16(pa1, bv, occ[1][dt], 0, 0, 0);
        }
      }
    }
    // ---- epilogue: finish l reduction, store O f16 ----
#pragma unroll
    for (int i = 0; i < 2; ++i) {
#pragma unroll
      for (int r = 0; r < 4; ++r) {
        float ls = lrow[i][r];
#pragma unroll
        for (int off = 1; off < 16; off <<= 1) ls += __shfl_xor(ls, off, 64);
        float inv = 1.f / ls;
        u16* op = ob + ((size_t)(b * Ss) + qrow0 + i * 16 + g * 4 + r) * (Hh * HDd) +
                  hh * HDd + c;
#pragma unroll
        for (int dt = 0; dt < 4; ++dt) op[dt * 16] = f2h(occ[i][dt][r] * inv);
      }
    }
  }
}

// ---------------- Fused router: rmsnorm(h) -> logits -> top-2 gates + packed top2 (NO atomics) ----------------
__global__ __launch_bounds__(64) void router_kernel(const float* __restrict__ h,
                                                    const float* __restrict__ wm,
                                                    const float* __restrict__ rw,
                                                    float* __restrict__ gates,
                                                    int* __restrict__ top2) {
  int t = blockIdx.x, lane = threadIdx.x;
  const float* hr = h + (size_t)t * Dd;
  float v[16]; float ss = 0.f;
#pragma unroll
  for (int j = 0; j < 16; ++j) { v[j] = hr[lane + j * 64]; ss += v[j] * v[j]; }
#pragma unroll
  for (int off = 32; off; off >>= 1) ss += __shfl_down(ss, off, 64);
  ss = __shfl(ss, 0, 64);
  float sc = rsqrtf(ss * (1.f / Dd) + EPSf);
  float acc[8] = {};
#pragma unroll
  for (int j = 0; j < 16; ++j) {
    int i = lane + j * 64;
    float yv = v[j] * sc * wm[i];
    float4 w0 = *(const float4*)(rw + (size_t)i * 8);
    float4 w1 = *(const float4*)(rw + (size_t)i * 8 + 4);
    acc[0] += yv * w0.x; acc[1] += yv * w0.y;
    acc[2] += yv * w0.z; acc[3] += yv * w0.w;
    acc[4] += yv * w1.x; acc[5] += yv * w1.y;
    acc[6] += yv * w1.z; acc[7] += yv * w1.w;
  }
#pragma unroll
  for (int off = 32; off; off >>= 1)
#pragma unroll
    for (int e = 0; e < 8; ++e) acc[e] += __shfl_down(acc[e], off, 64);
  if (lane == 0) {
    int i0 = 0; float v0 = acc[0];
#pragma unroll
    for (int e = 1; e < 8; ++e) if (acc[e] > v0) { v0 = acc[e]; i0 = e; }
    int i1 = -1; float v1 = -3.4e38f;
#pragma unroll
    for (int e = 0; e < 8; ++e) if (e != i0 && acc[e] > v1) { v1 = acc[e]; i1 = e; }
    float e1 = __expf(v1 - v0);
    float inv = 1.f / (1.f + e1);
    float* gr = gates + (size_t)t * 8;
#pragma unroll
    for (int e = 0; e < 8; ++e) gr[e] = (e == i0) ? inv : ((e == i1) ? e1 * inv : 0.f);
    top2[t] = i0 | (i1 << 4);
  }
}

// ---------------- Build compact expert lists + prefix offsets + per-token positions ----------------
// 1 block, 8 waves: wave e handles expert e. Two passes (count -> prefix -> assign).
__global__ __launch_bounds__(512) void build_lists(const int* __restrict__ top2,
                                                   int* __restrict__ cnt,
                                                   int* __restrict__ off,
                                                   int* __restrict__ elist,
                                                   int* __restrict__ pos) {
  int w = threadIdx.x >> 6, lane = threadIdx.x & 63;
  __shared__ int scnt[8], soff[8];
  int cl = 0;
  for (int t0 = 0; t0 < Tt; t0 += 64) {
    int p2 = top2[t0 + lane];
    bool match = ((p2 & 15) == w) || (((p2 >> 4) & 15) == w);
    cl += __popcll(__ballot(match));
  }
  if (lane == 0) scnt[w] = cl;
  __syncthreads();
  if (threadIdx.x == 0) {
    int s = 0;
    for (int e = 0; e < 8; ++e) { soff[e] = s; s += scnt[e]; }
  }
  __syncthreads();
  int base = soff[w];
  if (lane == 0) { cnt[w] = scnt[w]; off[w] = base; }
  for (int t0 = 0; t0 < Tt; t0 += 64) {
    int t = t0 + lane;
    int p2 = top2[t];
    bool m0 = (p2 & 15) == w;
    bool m1 = ((p2 >> 4) & 15) == w;
    bool match = m0 || m1;
    unsigned long long mask = __ballot(match);
    int prefix = __popcll(mask & ((1ull << lane) - 1ull));
    if (match) {
      int row = base + prefix;
      elist[row] = t;
      pos[t * 2 + (m0 ? 0 : 1)] = row;
    }
    base += __popcll(mask);
  }
}

extern "C" void kernel_launch(void* const* d_in, const int* in_sizes, int n_in,
                              void* d_out, int out_size, void* d_ws, size_t ws_size,
                              hipStream_t stream) {
  const float* x      = (const float*)d_in[0];
  const float* cosb   = (const float*)d_in[1];
  const float* sinb   = (const float*)d_in[2];
  // d_in[3] = mask — causal, hard-coded in flash
  const float* w_attn = (const float*)d_in[4];
  const float* w_moe  = (const float*)d_in[5];
  const float* Wq = (const float*)d_in[6];
  const float* Wk = (const float*)d_in[7];
  const float* Wv = (const float*)d_in[8];
  const float* Wo = (const float*)d_in[9];
  const float* Wr = (const float*)d_in[10];
  const float* Wg = (const float*)d_in[11];
  const float* Wu = (const float*)d_in[12];
  const float* Wd = (const float*)d_in[13];
  float* out  = (float*)d_out;
  float* outk = out + (size_t)Tt * Dd;
  float* outv = outk + (size_t)Tt * KVh * HDd;

  // ---- workspace layout (112 MB budget) ----
  char* ws8 = (char*)d_ws;
  u16*   xnb   = (u16*)(ws8);                    // 16 MB f16 : xnb -> ob -> y
  u16*   ob    = (u16*)(ws8);
  u16*   y     = (u16*)(ws8);
  float* gates = (float*)(ws8 + 16777216);       // 256 KB
  int*   cnt   = (int*)(ws8 + 17039360);         // 32 B expert counters
  int*   off   = (int*)(ws8 + 17039488);         // 32 B expert offsets (prefix)
  int*   elist = (int*)(ws8 + 17040384);         // 64 KB compact token list [16384]
  int*   top2  = (int*)(ws8 + 17302528);         // 32 KB packed top-2 per token
  int*   pos   = (int*)(ws8 + 17335296);         // 64 KB per-token compact rows [8192][2]
  u16*   wbuf  = (u16*)(ws8 + 17825792);         // 5 MB: WqT|WkT|WvT|WoT contiguous (f16)
  u16*   WqT   = wbuf;                           // f16 [1024][1024] 2 MB   (qkv BT base)
  u16*   WkT   = wbuf + (size_t)1024 * 1024;     // f16 [256][1024]  0.5 MB
  u16*   WvT   = WkT + (size_t)256 * 1024;       // f16 [256][1024]  0.5 MB
  u16*   WoT   = WvT + (size_t)256 * 1024;       // f16 [1024][1024] 2 MB
  _Float16* khb = (_Float16*)(ws8 + 24117248);   // f16 K (roped) [Tt][256] 4 MB
  _Float16* vtb = (_Float16*)(ws8 + 28311552);   // f16 V^T [b][kv][64][Ss] 4 MB
  float* qkv   = (float*)(ws8 + 33554432);       // fp32 [Tt][1536] 48 MB (dead after flash)
  u16*   he    = (u16*)(ws8 + 33554432);         // bf16 [16384][1024] 32 MB (post-flash)
  u16*   WdT_all = (u16*)(ws8 + 67108864);       // bf16 [8][1024][1024] 16 MB (post-flash)
  float* h     = (float*)(ws8 + 83886080);       // 32 MB
  u16*   WguT_all = (u16*)(ws8 + 83886080);      // bf16 [8][2048][1024] 32 MB (h dead)
  u16*   dout  = (u16*)(ws8 + 83886080);         // f16 [16384][1024] 32 MB (WguT_all dead)

  // 1. xnb = rmsnorm(x, w_attn) -> f16
  rmsnorm_kernel<2><<<Tt, 256, 0, stream>>>(x, w_attn, xnb);
  // 2. transpose attention weights -> f16 [N][K] (contiguous: forms [1536][1024] for QKV)
  transpose_kernel<true><<<dim3(16, 16), 256, 0, stream>>>(Wq, WqT, 1024, 0, 0);
  transpose_kernel<true><<<dim3(4, 16), 256, 0, stream>>>(Wk, WkT, 256, 0, 0);
  transpose_kernel<true><<<dim3(4, 16), 256, 0, stream>>>(Wv, WvT, 256, 0, 0);
  transpose_kernel<true><<<dim3(16, 16), 256, 0, stream>>>(Wo, WoT, 1024, 0, 0);
  // 3. fused q|k|v projection (f16 MFMA, fp32 out, N=1536)
  mfma_gemm<0, true><<<dim3(12, 64), 256, 0, stream>>>(xnb, WqT, qkv, nullptr, nullptr, QKVS, 1024);
  // 4. RoPE on k -> outk + f16 khb; copy v -> outv; then V^T f16 prep
  ropek_kv_kernel<<<(Tt * KVh * 32) / 256, 256, 0, stream>>>(qkv, cosb, sinb, outk, outv, khb);
  vt_prep<<<dim3(Ss / 64, Bb * KVh), 256, 0, stream>>>(qkv, vtb);
  // 5. causal GQA flash attention (MFMA f16, balanced q-tile pairs; RoPE-q fused) -> ob (f16)
  flash_mfma<<<Bb * Hh * 8, 256, 0, stream>>>(qkv, khb, vtb, cosb, sinb, ob);
  // 6. h = ob @ WoT + x; dual-write into out
  mfma_gemm<2, true><<<dim3(8, 64), 256, 0, stream>>>(ob, WoT, h, out, x, 1024, 1024);
  // 7. y = rmsnorm(h) -> bf16; router -> gates + top2; compact lists + offsets + positions
  rmsnorm_kernel<1><<<Tt, 256, 0, stream>>>(h, w_moe, y);
  router_kernel<<<Tt, 64, 0, stream>>>(h, w_moe, Wr, gates, top2);
  build_lists<<<1, 512, 0, stream>>>(top2, cnt, off, elist, pos);
  // 8. batched all-expert weight transposes (h and qkv dead now)
  transpose_kernel<false><<<dim3(16, 16, 8), 256, 0, stream>>>(
      Wg, WguT_all, 1024, (size_t)Dd * Ff, (size_t)2048 * 1024);
  transpose_kernel<false><<<dim3(16, 16, 8), 256, 0, stream>>>(
      Wu, WguT_all + (size_t)1024 * 1024, 1024, (size_t)Dd * Ff, (size_t)2048 * 1024);
  transpose_kernel<false><<<dim3(16, 16, 8), 256, 0, stream>>>(
      Wd, WdT_all, 1024, (size_t)Ff * Dd, (size_t)1024 * 1024);
  // 9. routed MoE, 3 batched dispatches: fused up+silu -> he; down -> dout; gather-add -> out
  moe_up_silu<<<dim3(16, 64, 8), 256, 0, stream>>>(y, WguT_all, he, elist, cnt, off);
  moe_down<<<dim3(8, 64, 8), 256, 0, stream>>>(he, WdT_all, dout, cnt, off);
  gather_add<<<Tt, 256, 0, stream>>>(dout, top2, pos, gates, out);
}